// Round 11
// baseline (260.809 us; speedup 1.0000x reference)
//
#include <hip/hip_runtime.h>
#include <hip/hip_bf16.h>
#include <math.h>

#define NB 16384

typedef __bf16 bf16x8 __attribute__((ext_vector_type(8)));
typedef __fp16 f16x8  __attribute__((ext_vector_type(8)));
typedef float  f32x4  __attribute__((ext_vector_type(4)));
typedef unsigned short ushort8 __attribute__((ext_vector_type(8)));
typedef unsigned int   uint4v  __attribute__((ext_vector_type(4)));

__device__ __forceinline__ float selu_f(float x) {
    const float kScale = 1.0507009873554805f;
    const float kAlphaScale = 1.7580993408473766f;   // scale*alpha
    return x > 0.0f ? kScale * x : kAlphaScale * (__expf(x) - 1.0f);
}

__device__ __forceinline__ unsigned short f2bf(float x) {   // RNE
    unsigned int u = __float_as_uint(x);
    unsigned int r = (u + 0x7FFFu + ((u >> 16) & 1u)) >> 16;
    return (unsigned short)r;
}

// split v into fp16 hi + fp16 lo, packed into one u32 (lo16=hi, hi16=lo)
__device__ __forceinline__ unsigned int packsplit(float v) {
    const __fp16 h = (__fp16)v;
    const __fp16 l = (__fp16)(v - (float)h);
    const unsigned int hb = (unsigned int)__builtin_bit_cast(unsigned short, h);
    const unsigned int lb = (unsigned int)__builtin_bit_cast(unsigned short, l);
    return hb | (lb << 16);
}

// extract packed pairs: AH u32 = hi fp16s, AL u32 = lo fp16s
#define PERM_AH 0x05040100u
#define PERM_AL 0x07060302u

union F16x8Cast { uint4v u; f16x8 f; };

#define CH1 145          // x1 channel stride (u32)
#define X1SZ (CH1 * 10)  // 1450 u32 per image

// ---------------------------------------------------------------------------
// Kernel P (prep): builds all weight-derived tables in ws.
//  1. dec2_w  -> bf16 wbf                               (125440)
//  2. lin1_w  -> lin1_wp permuted for x2 [b][q*20+oc]   (16000)
//  3. woff[k] -> x1P u32-offset of conv2 k-elem, stride CH1 (256)
//  4. conv2_w -> whi/wlo fp16 split, B-fragment order   (2 x 8192)
//  5. koff1[k]-> GLOBAL image offset of conv1 k-elem, stride 28 (32)
//  6. conv1_w -> whi1/wlo1 fp16 split, B-fragment order (2 x 512)
// ---------------------------------------------------------------------------
__global__ __launch_bounds__(256) void k_prep(
    const float* __restrict__ dec2_w,  unsigned short* __restrict__ wbf,
    const float* __restrict__ lin1_w,  float* __restrict__ lin1_wp,
    const float* __restrict__ conv2_w, unsigned short* __restrict__ woff,
    __fp16* __restrict__ whi, __fp16* __restrict__ wlo,
    const float* __restrict__ conv1_w, unsigned short* __restrict__ koff1,
    __fp16* __restrict__ whi1, __fp16* __restrict__ wlo1)
{
    int i = blockIdx.x * 256 + threadIdx.x;
    if (i < 125440) { wbf[i] = f2bf(dec2_w[i]); return; }
    i -= 125440;
    if (i < 16000) {                       // lin1 permute
        const int row = i / 320, cn = i - row * 320;
        const int q = cn / 20, oc = cn - q * 20;
        lin1_wp[row * 320 + cn] = lin1_w[row * 320 + oc * 16 + q];
        return;
    }
    i -= 16000;
    if (i < 256) {                         // conv2 A-gather offsets (stride CH1)
        unsigned short off = 0;
        if (i < 250) {
            const int ic = i / 25, r = i - ic * 25, ky = r / 5, kx = r - ky * 5;
            off = (unsigned short)(ic * CH1 + ky * 12 + kx);
        }
        woff[i] = off;
        return;
    }
    i -= 256;
    if (i < 16384) {                       // conv2 weight split tables
        const int v = i >> 13;             // 0 = hi, 1 = lo
        const int r = i & 8191;
        const int j = r & 7, lane = (r >> 3) & 63, s = (r >> 9) & 7, nt = r >> 12;
        const int k  = s * 32 + (lane >> 4) * 8 + j;
        const int oc = nt * 16 + (lane & 15);
        float w = 0.f;
        if (k < 250 && oc < 20) {
            const int ic = k / 25, rr = k - ic * 25;
            w = conv2_w[(oc * 10 + ic) * 25 + rr];
        }
        const __fp16 hi = (__fp16)w;
        if (v == 0) whi[r] = hi;
        else        wlo[r] = (__fp16)(w - (float)hi);
        return;
    }
    i -= 16384;
    if (i < 32) {                          // conv1 A-gather offsets (stride 28)
        unsigned short off = 0;
        if (i < 25) off = (unsigned short)((i / 5) * 28 + (i % 5));
        koff1[i] = off;
        return;
    }
    i -= 32;
    if (i < 1024) {                        // conv1 weight split tables
        const int v = i >> 9;
        const int r = i & 511;
        const int j = r & 7, lane = r >> 3;
        const int c = lane & 15, g = lane >> 4;
        const int k = g * 8 + j;
        float w = 0.f;
        if (k < 25 && c < 10) w = conv1_w[c * 25 + k];
        const __fp16 hi = (__fp16)w;
        if (v == 0) whi1[r] = hi;
        else        wlo1[r] = (__fp16)(w - (float)hi);
    }
}

// ---------------------------------------------------------------------------
// Kernel A: conv1+conv2 split-fp16 MFMA, wave-private slabs, NO barriers.
//  phase 1: conv1 GEMM; 8-tap patches gathered from GLOBAL fp32 (images are
//           L1-resident, 12.5KB/block) + inline fp16 split (r9-proven);
//           pool+bias+selu -> split-packed x1P (stride CH1) in LDS
//  phase 2: conv2 GEMM, gather+v_perm extraction, B-frag double-buffer
//           (r7/r8/r10-proven, byte-identical to r10)
// LDS = sX1P only = 23.2KB -> 7 blocks/CU (vs 4 at r10's 40.4KB) — occupancy
// was the binding constraint (r10: no pipe >55%, occ 39%).
// launch_bounds(256,4): do NOT raise (r4 spill). Small live sets, unroll-1
// outer loops (r6 spill). NO K-padding of conv2 (r9: 1.7x regression).
// ---------------------------------------------------------------------------
__global__ __launch_bounds__(256, 4) void k_conv_fused(
    const float* __restrict__ images,
    const float* __restrict__ conv1_b, const float* __restrict__ conv2_b,
    const unsigned short* __restrict__ woff,
    const __fp16* __restrict__ whi,  const __fp16* __restrict__ wlo,
    const unsigned short* __restrict__ koff1,
    const __fp16* __restrict__ whi1, const __fp16* __restrict__ wlo1,
    float* __restrict__ x2)
{
    __shared__ unsigned int sX1P[4 * X1SZ];    // 23.2 KB

    const int t  = threadIdx.x;
    const int b0 = blockIdx.x * 4;

    const int lane = t & 63;
    const int wv   = t >> 6;
    const int g    = lane >> 4;          // k-group
    const int c0   = lane & 15;          // A-row (phase1/2) / D-col

    // ---- phase 1: conv1 via MFMA, patch gather from GLOBAL ----
    {
        const float* imgG = images + (size_t)(b0 + wv) * 784;
        unsigned int* x1P = sX1P + wv * X1SZ;

        // per-lane A base: row r=c0 -> quad r>>2, sub r&3 (global stride 28)
        const int sub = c0 & 3, qq = c0 >> 2;
        const int base_lane = (sub >> 1) * 28 + 2 * qq + (sub & 1);
        const ushort8 kof = *reinterpret_cast<const ushort8*>(koff1 + g * 8);
        int addr8[8];
        #pragma unroll
        for (int j = 0; j < 8; ++j) addr8[j] = base_lane + (int)kof[j];

        const f16x8 bh1 = *reinterpret_cast<const f16x8*>(whi1 + lane * 8);
        const f16x8 bl1 = *reinterpret_cast<const f16x8*>(wlo1 + lane * 8);
        const float bias = (c0 < 10) ? conv1_b[c0] : 0.f;

        #pragma unroll 1
        for (int a = 0; a < 12; ++a) {
            const int abase = a * 56;
            #pragma unroll
            for (int b = 0; b < 3; ++b) {
                f16x8 ah, al;
                #pragma unroll
                for (int j = 0; j < 8; ++j) {
                    const float v = imgG[addr8[j] + abase + b * 8];
                    const __fp16 h = (__fp16)v;
                    ah[j] = h;
                    al[j] = (__fp16)(v - (float)h);
                }
                f32x4 acc = {0.f, 0.f, 0.f, 0.f};
                acc = __builtin_amdgcn_mfma_f32_16x16x32_f16(ah, bh1, acc, 0, 0, 0);
                acc = __builtin_amdgcn_mfma_f32_16x16x32_f16(al, bh1, acc, 0, 0, 0);
                acc = __builtin_amdgcn_mfma_f32_16x16x32_f16(ah, bl1, acc, 0, 0, 0);
                // D: col=c0 (channel), rows g*4+0..3 = subs of quad q=12a+4b+g
                const float m = fmaxf(fmaxf(acc[0], acc[1]), fmaxf(acc[2], acc[3]));
                if (c0 < 10)
                    x1P[c0 * CH1 + 12 * a + 4 * b + g] = packsplit(selu_f(m + bias));
            }
        }
    }
    // no barrier: phase 2 reads only this wave's own slab (lgkmcnt orders)

    // ---- phase 2: conv2 via MFMA (r10 structure, perm extraction) ----
    {
        const unsigned int* x1P = sX1P + wv * X1SZ;

        int rowbase[4];
        #pragma unroll
        for (int mi = 0; mi < 4; ++mi) {
            const int r64 = mi * 16 + c0;
            const int qi  = r64 >> 2;
            const int sb  = r64 & 3;
            rowbase[mi] = (2 * (qi >> 2) + (sb >> 1)) * 12
                        + 2 * (qi & 3) + (sb & 1);
        }

        f32x4 acc[4][2];
        #pragma unroll
        for (int mi = 0; mi < 4; ++mi) {
            acc[mi][0] = (f32x4){0.f, 0.f, 0.f, 0.f};
            acc[mi][1] = (f32x4){0.f, 0.f, 0.f, 0.f};
        }

        // double-buffered per-s data (named regs; no runtime indexing)
        ushort8 off = *reinterpret_cast<const ushort8*>(woff + g * 8);
        f16x8 bh0 = *reinterpret_cast<const f16x8*>(whi + (size_t)(0 * 64 + lane) * 8);
        f16x8 bl0 = *reinterpret_cast<const f16x8*>(wlo + (size_t)(0 * 64 + lane) * 8);
        f16x8 bh1 = *reinterpret_cast<const f16x8*>(whi + (size_t)(8 * 64 + lane) * 8);
        f16x8 bl1 = *reinterpret_cast<const f16x8*>(wlo + (size_t)(8 * 64 + lane) * 8);

        #pragma unroll 1
        for (int s = 0; s < 8; ++s) {
            const int sn = (s + 1) & 7;    // wraps harmlessly at s=7
            const ushort8 offn = *reinterpret_cast<const ushort8*>(woff + sn * 32 + g * 8);
            const f16x8 nbh0 = *reinterpret_cast<const f16x8*>(whi + (size_t)((0 + sn) * 64 + lane) * 8);
            const f16x8 nbl0 = *reinterpret_cast<const f16x8*>(wlo + (size_t)((0 + sn) * 64 + lane) * 8);
            const f16x8 nbh1 = *reinterpret_cast<const f16x8*>(whi + (size_t)((8 + sn) * 64 + lane) * 8);
            const f16x8 nbl1 = *reinterpret_cast<const f16x8*>(wlo + (size_t)((8 + sn) * 64 + lane) * 8);

            #pragma unroll
            for (int mi = 0; mi < 4; ++mi) {
                unsigned int w[8];
                #pragma unroll
                for (int j = 0; j < 8; ++j)
                    w[j] = x1P[rowbase[mi] + (int)off[j]];
                F16x8Cast AH, AL;
                AH.u = (uint4v){ __builtin_amdgcn_perm(w[1], w[0], PERM_AH),
                                 __builtin_amdgcn_perm(w[3], w[2], PERM_AH),
                                 __builtin_amdgcn_perm(w[5], w[4], PERM_AH),
                                 __builtin_amdgcn_perm(w[7], w[6], PERM_AH) };
                AL.u = (uint4v){ __builtin_amdgcn_perm(w[1], w[0], PERM_AL),
                                 __builtin_amdgcn_perm(w[3], w[2], PERM_AL),
                                 __builtin_amdgcn_perm(w[5], w[4], PERM_AL),
                                 __builtin_amdgcn_perm(w[7], w[6], PERM_AL) };
                acc[mi][0] = __builtin_amdgcn_mfma_f32_16x16x32_f16(AH.f, bh0, acc[mi][0], 0, 0, 0);
                acc[mi][0] = __builtin_amdgcn_mfma_f32_16x16x32_f16(AL.f, bh0, acc[mi][0], 0, 0, 0);
                acc[mi][0] = __builtin_amdgcn_mfma_f32_16x16x32_f16(AH.f, bl0, acc[mi][0], 0, 0, 0);
                acc[mi][1] = __builtin_amdgcn_mfma_f32_16x16x32_f16(AH.f, bh1, acc[mi][1], 0, 0, 0);
                acc[mi][1] = __builtin_amdgcn_mfma_f32_16x16x32_f16(AL.f, bh1, acc[mi][1], 0, 0, 0);
                acc[mi][1] = __builtin_amdgcn_mfma_f32_16x16x32_f16(AH.f, bl1, acc[mi][1], 0, 0, 0);
            }
            off = offn; bh0 = nbh0; bl0 = nbl0; bh1 = nbh1; bl1 = nbl1;
        }

        // epilogue: the 4 D-regs are one pool quad; qq = pooled pos
        const float bias0 = conv2_b[c0];
        const float bias1 = (c0 < 4) ? conv2_b[16 + c0] : 0.f;
        #pragma unroll
        for (int mi = 0; mi < 4; ++mi) {
            const int qq = mi * 4 + g;
            float* orow = x2 + (size_t)(b0 + wv) * 320 + qq * 20;
            const float v0 = fmaxf(fmaxf(acc[mi][0][0], acc[mi][0][1]),
                                   fmaxf(acc[mi][0][2], acc[mi][0][3]));
            orow[c0] = selu_f(v0 + bias0);
            if (c0 < 4) {
                const float v1 = fmaxf(fmaxf(acc[mi][1][0], acc[mi][1][1]),
                                       fmaxf(acc[mi][1][2], acc[mi][1][3]));
                orow[16 + c0] = selu_f(v1 + bias1);
            }
        }
    }
}

// ---------------------------------------------------------------------------
// Kernel B: lin1 (320->50, permuted weights) + selu, lin2 (50->25) -> code
// ---------------------------------------------------------------------------
__global__ __launch_bounds__(256) void k_lin12(
    const float* __restrict__ x2,
    const float* __restrict__ lin1_wp, const float* __restrict__ lin1_b,
    const float* __restrict__ lin2_w,  const float* __restrict__ lin2_b,
    float* __restrict__ code)
{
    __shared__ float sIn[32][324];
    __shared__ float sH[32][51];
    const int t  = threadIdx.x;
    const int b0 = blockIdx.x * 32;
    {
        const float* g = x2 + (size_t)b0 * 320;
        for (int k = t; k < 2560; k += 256) {      // float4-vectorized staging
            const int r  = k / 80;
            const int c4 = k - r * 80;
            reinterpret_cast<float4*>(&sIn[r][0])[c4] =
                reinterpret_cast<const float4*>(g + r * 320)[c4];
        }
    }
    __syncthreads();

    for (int idx = t; idx < 1600; idx += 256) {        // 32 x 50
        const int bi = idx & 31;
        const int j  = idx >> 5;
        float s = lin1_b[j];
        const float4* w  = reinterpret_cast<const float4*>(lin1_wp + j * 320);
        const float4* xi = reinterpret_cast<const float4*>(&sIn[bi][0]);
        #pragma unroll 4
        for (int k4 = 0; k4 < 80; ++k4) {
            const float4 a = xi[k4];
            const float4 wq = w[k4];
            s = fmaf(a.x, wq.x, s); s = fmaf(a.y, wq.y, s);
            s = fmaf(a.z, wq.z, s); s = fmaf(a.w, wq.w, s);
        }
        sH[bi][j] = selu_f(s);
    }
    __syncthreads();
    for (int idx = t; idx < 800; idx += 256) {         // 32 x 25
        const int bi = idx & 31;
        const int j  = idx >> 5;
        float s = lin2_b[j];
        const float* w = lin2_w + j * 50;
        #pragma unroll
        for (int k = 0; k < 50; ++k) s = fmaf(sH[bi][k], w[k], s);
        code[(size_t)(b0 + bi) * 25 + j] = s;
    }
}

// ---------------------------------------------------------------------------
// Kernel C: per-sample 5x5: A = M*M^T, double Jacobi eigensolver (6 sweeps,
//           quadratic convergence: off-diag << fp64 eps by sweep 5),
//           P = sum of outer products of top-2 eigenvectors -> proj[B][25]
// ---------------------------------------------------------------------------
__global__ __launch_bounds__(64) void k_svdproj(
    const float* __restrict__ code, float* __restrict__ proj)
{
    const int b = blockIdx.x * 64 + threadIdx.x;
    if (b >= NB) return;
    const float* c = code + (size_t)b * 25;

    double M[5][5];
    #pragma unroll
    for (int i = 0; i < 5; ++i) {
        #pragma unroll
        for (int j = 0; j < 5; ++j) M[i][j] = (double)c[i * 5 + j];
    }
    double A[5][5], V[5][5];
    #pragma unroll
    for (int i = 0; i < 5; ++i) {
        #pragma unroll
        for (int j = 0; j < 5; ++j) {
            double s = 0.0;
            #pragma unroll
            for (int k = 0; k < 5; ++k) s += M[i][k] * M[j][k];
            A[i][j] = s;
            V[i][j] = (i == j) ? 1.0 : 0.0;
        }
    }
    for (int sweep = 0; sweep < 6; ++sweep) {
        #pragma unroll
        for (int p = 0; p < 4; ++p) {
            #pragma unroll
            for (int q = p + 1; q < 5; ++q) {
                const double apq = A[p][q];
                if (fabs(apq) > 1e-60) {
                    const double app = A[p][p], aqq = A[q][q];
                    const double tau = (aqq - app) / (2.0 * apq);
                    const double tt  = (tau >= 0.0 ? 1.0 : -1.0) /
                                       (fabs(tau) + sqrt(1.0 + tau * tau));
                    const double cc  = 1.0 / sqrt(1.0 + tt * tt);
                    const double ss  = tt * cc;
                    #pragma unroll
                    for (int i = 0; i < 5; ++i) {
                        if (i == p || i == q) continue;
                        const double aip = A[i][p], aiq = A[i][q];
                        A[i][p] = A[p][i] = cc * aip - ss * aiq;
                        A[i][q] = A[q][i] = ss * aip + cc * aiq;
                    }
                    A[p][p] = app - tt * apq;
                    A[q][q] = aqq + tt * apq;
                    A[p][q] = A[q][p] = 0.0;
                    #pragma unroll
                    for (int i = 0; i < 5; ++i) {
                        const double vip = V[i][p], viq = V[i][q];
                        V[i][p] = cc * vip - ss * viq;
                        V[i][q] = ss * vip + cc * viq;
                    }
                }
            }
        }
    }
    double d[5];
    #pragma unroll
    for (int i = 0; i < 5; ++i) d[i] = A[i][i];
    double sel[5];
    #pragma unroll
    for (int c1 = 0; c1 < 5; ++c1) {
        int cnt = 0;
        #pragma unroll
        for (int c2 = 0; c2 < 5; ++c2) {
            if (c2 == c1) continue;
            if (d[c2] > d[c1] || (d[c2] == d[c1] && c2 < c1)) ++cnt;
        }
        sel[c1] = (cnt < 2) ? 1.0 : 0.0;
    }
    #pragma unroll
    for (int i = 0; i < 5; ++i) {
        #pragma unroll
        for (int j = 0; j < 5; ++j) {
            double s = 0.0;
            #pragma unroll
            for (int k = 0; k < 5; ++k) s += sel[k] * V[i][k] * V[j][k];
            proj[(size_t)b * 25 + i * 5 + j] = (float)s;
        }
    }
}

// ---------------------------------------------------------------------------
// Kernel D: dec1 (25->160) + selu  ->  bf16 h in LDS  ->  dec2 (160->784)
//           via mfma_f32_16x16x32_bf16 + bias + sigmoid -> out[B][784]
// ---------------------------------------------------------------------------
#define HS 168   // padded h row stride in ushorts

__global__ __launch_bounds__(256) void k_decoder(
    const float* __restrict__ proj,
    const float* __restrict__ dec1_w, const float* __restrict__ dec1_b,
    const unsigned short* __restrict__ dec2_wb, const float* __restrict__ dec2_b,
    float* __restrict__ out)
{
    __shared__ unsigned short sH[32 * HS];
    const int t  = threadIdx.x;
    const int b0 = blockIdx.x * 32;
    const int bi = t & 31;     // sample row owned by this thread (phase 1)
    const int j0 = t >> 5;     // 0..7

    // ---- phase 1: h[bi][j] = selu(dec1), j = j0 + 8*i ----
    float p[25];
    {
        const float* pr = proj + (size_t)(b0 + bi) * 25;
        #pragma unroll
        for (int k = 0; k < 25; ++k) p[k] = pr[k];
    }
    #pragma unroll 4
    for (int i = 0; i < 20; ++i) {
        const int j = j0 + i * 8;
        const float* w = dec1_w + j * 25;
        float s = dec1_b[j];
        #pragma unroll
        for (int k = 0; k < 25; ++k) s = fmaf(p[k], w[k], s);
        sH[bi * HS + j] = f2bf(selu_f(s));
    }
    __syncthreads();

    // ---- phase 2: out[32][784] = sigmoid(h @ W^T + b) via MFMA ----
    const int wv   = t >> 6;      // 0..3
    const int lane = t & 63;
    const int arow = lane & 15;   // A row / B col within tile
    const int kgrp = lane >> 4;   // 0..3

    bf16x8 afr[2][5];             // hoisted A fragments: 2 row-tiles x 5 k-steps
    #pragma unroll
    for (int rt = 0; rt < 2; ++rt)
        #pragma unroll
        for (int ks = 0; ks < 5; ++ks)
            afr[rt][ks] = *reinterpret_cast<const bf16x8*>(
                &sH[(rt * 16 + arow) * HS + ks * 32 + kgrp * 8]);

    for (int ct = wv; ct < 49; ct += 4) {
        const int col = ct * 16 + arow;
        bf16x8 bfr[5];
        const unsigned short* wp = dec2_wb + (size_t)col * 160 + kgrp * 8;
        #pragma unroll
        for (int ks = 0; ks < 5; ++ks)
            bfr[ks] = *reinterpret_cast<const bf16x8*>(wp + ks * 32);

        f32x4 acc0 = {0.f, 0.f, 0.f, 0.f};
        f32x4 acc1 = {0.f, 0.f, 0.f, 0.f};
        #pragma unroll
        for (int ks = 0; ks < 5; ++ks) {
            acc0 = __builtin_amdgcn_mfma_f32_16x16x32_bf16(afr[0][ks], bfr[ks], acc0, 0, 0, 0);
            acc1 = __builtin_amdgcn_mfma_f32_16x16x32_bf16(afr[1][ks], bfr[ks], acc1, 0, 0, 0);
        }
        const float bb = dec2_b[col];
        #pragma unroll
        for (int r = 0; r < 4; ++r) {
            const int row = kgrp * 4 + r;          // D: row=(lane>>4)*4+reg
            const float v0 = acc0[r] + bb;
            const float v1 = acc1[r] + bb;
            out[(size_t)(b0 + row) * 784 + col]      = 1.0f / (1.0f + __expf(-v0));
            out[(size_t)(b0 + 16 + row) * 784 + col] = 1.0f / (1.0f + __expf(-v1));
        }
    }
}

// ---------------------------------------------------------------------------
extern "C" void kernel_launch(void* const* d_in, const int* in_sizes, int n_in,
                              void* d_out, int out_size, void* d_ws, size_t ws_size,
                              hipStream_t stream) {
    const float* images  = (const float*)d_in[0];
    const float* conv1_w = (const float*)d_in[1];
    const float* conv1_b = (const float*)d_in[2];
    const float* conv2_w = (const float*)d_in[3];
    const float* conv2_b = (const float*)d_in[4];
    const float* lin1_w  = (const float*)d_in[5];
    const float* lin1_b  = (const float*)d_in[6];
    const float* lin2_w  = (const float*)d_in[7];
    const float* lin2_b  = (const float*)d_in[8];
    const float* dec1_w  = (const float*)d_in[9];
    const float* dec1_b  = (const float*)d_in[10];
    const float* dec2_w  = (const float*)d_in[11];
    const float* dec2_b  = (const float*)d_in[12];

    float* out_img = (float*)d_out;                    // NB*784 fp32
    float* code    = (float*)d_out + (size_t)NB * 784; // NB*25  fp32

    // workspace layout (bytes, all 16-aligned):
    char* ws = (char*)d_ws;
    float*          x2      = (float*)ws;                                  // NB*320 f
    float*          proj    = (float*)(ws + (size_t)NB * 320 * 4);         // NB*25 f
    unsigned short* wbf     = (unsigned short*)(ws + (size_t)NB * 345 * 4);// 125440 us
    char*           pB      = ws + (size_t)NB * 345 * 4 + 250880;
    float*          lin1_wp = (float*)pB;                                  // 16000 f
    unsigned short* woff    = (unsigned short*)(pB + 64000);               // 256 us
    __fp16*         whi     = (__fp16*)(pB + 64512);                       // 8192 h
    __fp16*         wlo     = (__fp16*)(pB + 80896);                       // 8192 h
    unsigned short* koff1   = (unsigned short*)(pB + 97280);               // 32 us
    __fp16*         whi1    = (__fp16*)(pB + 97344);                       // 512 h
    __fp16*         wlo1    = (__fp16*)(pB + 98368);                       // 512 h

    k_prep     <<<622,      256, 0, stream>>>(dec2_w, wbf, lin1_w, lin1_wp,
                                              conv2_w, woff, whi, wlo,
                                              conv1_w, koff1, whi1, wlo1);
    k_conv_fused<<<NB / 4,  256, 0, stream>>>(images, conv1_b, conv2_b,
                                              woff, whi, wlo,
                                              koff1, whi1, wlo1, x2);
    k_lin12    <<<NB / 32, 256, 0, stream>>>(x2, lin1_wp, lin1_b,
                                             lin2_w, lin2_b, code);
    k_svdproj  <<<NB / 64, 64, 0, stream>>>(code, proj);
    k_decoder  <<<NB / 32, 256, 0, stream>>>(proj, dec1_w, dec1_b,
                                             wbf, dec2_b, out_img);
}

// Round 12
// 189.562 us; speedup vs baseline: 1.3758x; 1.3758x over previous
//
#include <hip/hip_runtime.h>
#include <hip/hip_bf16.h>
#include <math.h>

#define NB 16384

typedef __bf16 bf16x8 __attribute__((ext_vector_type(8)));
typedef __fp16 f16x8  __attribute__((ext_vector_type(8)));
typedef float  f32x4  __attribute__((ext_vector_type(4)));
typedef unsigned short ushort8 __attribute__((ext_vector_type(8)));
typedef unsigned int   uint4v  __attribute__((ext_vector_type(4)));

__device__ __forceinline__ float selu_f(float x) {
    const float kScale = 1.0507009873554805f;
    const float kAlphaScale = 1.7580993408473766f;   // scale*alpha
    return x > 0.0f ? kScale * x : kAlphaScale * (__expf(x) - 1.0f);
}

__device__ __forceinline__ unsigned short f2bf(float x) {   // RNE
    unsigned int u = __float_as_uint(x);
    unsigned int r = (u + 0x7FFFu + ((u >> 16) & 1u)) >> 16;
    return (unsigned short)r;
}

// split v into fp16 hi + fp16 lo, packed into one u32 (lo16=hi, hi16=lo)
__device__ __forceinline__ unsigned int packsplit(float v) {
    const __fp16 h = (__fp16)v;
    const __fp16 l = (__fp16)(v - (float)h);
    const unsigned int hb = (unsigned int)__builtin_bit_cast(unsigned short, h);
    const unsigned int lb = (unsigned int)__builtin_bit_cast(unsigned short, l);
    return hb | (lb << 16);
}

// extract packed pairs: AH u32 = hi fp16s, AL u32 = lo fp16s
#define PERM_AH 0x05040100u
#define PERM_AL 0x07060302u

union F16x8Cast { uint4v u; f16x8 f; };

#define CH1 145          // x1 channel stride (u32)
#define X1SZ (CH1 * 10)  // 1450 u32 per image
#define IMS 37           // sImgP row stride (pad 28->37)
#define IMSZ 1064        // per image (max read 1026)

// ---------------------------------------------------------------------------
// Kernel P (prep): builds all weight-derived tables in ws. (r10, unchanged)
// ---------------------------------------------------------------------------
__global__ __launch_bounds__(256) void k_prep(
    const float* __restrict__ dec2_w,  unsigned short* __restrict__ wbf,
    const float* __restrict__ lin1_w,  float* __restrict__ lin1_wp,
    const float* __restrict__ conv2_w, unsigned short* __restrict__ woff,
    __fp16* __restrict__ whi, __fp16* __restrict__ wlo,
    const float* __restrict__ conv1_w, unsigned short* __restrict__ koff1,
    __fp16* __restrict__ whi1, __fp16* __restrict__ wlo1)
{
    int i = blockIdx.x * 256 + threadIdx.x;
    if (i < 125440) { wbf[i] = f2bf(dec2_w[i]); return; }
    i -= 125440;
    if (i < 16000) {                       // lin1 permute
        const int row = i / 320, cn = i - row * 320;
        const int q = cn / 20, oc = cn - q * 20;
        lin1_wp[row * 320 + cn] = lin1_w[row * 320 + oc * 16 + q];
        return;
    }
    i -= 16000;
    if (i < 256) {                         // conv2 A-gather offsets (stride CH1)
        unsigned short off = 0;
        if (i < 250) {
            const int ic = i / 25, r = i - ic * 25, ky = r / 5, kx = r - ky * 5;
            off = (unsigned short)(ic * CH1 + ky * 12 + kx);
        }
        woff[i] = off;
        return;
    }
    i -= 256;
    if (i < 16384) {                       // conv2 weight split tables
        const int v = i >> 13;             // 0 = hi, 1 = lo
        const int r = i & 8191;
        const int j = r & 7, lane = (r >> 3) & 63, s = (r >> 9) & 7, nt = r >> 12;
        const int k  = s * 32 + (lane >> 4) * 8 + j;
        const int oc = nt * 16 + (lane & 15);
        float w = 0.f;
        if (k < 250 && oc < 20) {
            const int ic = k / 25, rr = k - ic * 25;
            w = conv2_w[(oc * 10 + ic) * 25 + rr];
        }
        const __fp16 hi = (__fp16)w;
        if (v == 0) whi[r] = hi;
        else        wlo[r] = (__fp16)(w - (float)hi);
        return;
    }
    i -= 16384;
    if (i < 32) {                          // conv1 A-gather offsets (stride IMS)
        unsigned short off = 0;
        if (i < 25) off = (unsigned short)((i / 5) * IMS + (i % 5));
        koff1[i] = off;
        return;
    }
    i -= 32;
    if (i < 1024) {                        // conv1 weight split tables
        const int v = i >> 9;
        const int r = i & 511;
        const int j = r & 7, lane = r >> 3;
        const int c = lane & 15, g = lane >> 4;
        const int k = g * 8 + j;
        float w = 0.f;
        if (k < 25 && c < 10) w = conv1_w[c * 25 + k];
        const __fp16 hi = (__fp16)w;
        if (v == 0) whi1[r] = hi;
        else        wlo1[r] = (__fp16)(w - (float)hi);
    }
}

// ---------------------------------------------------------------------------
// Kernel A (exact r10, proven 111-122us): conv1+conv2 split-fp16 MFMA.
// phase 0: images -> split-packed LDS (row stride 37); phase 1: conv1 GEMM;
// phase 2: conv2 GEMM with gather+v_perm. Lessons pinned: (256,4) only (r4),
// unroll-1 outer + small live sets (r6), no conv2 K-padding (r9), phase-1
// patches from LDS not global (r11: global scatter = latency collapse).
// ---------------------------------------------------------------------------
__global__ __launch_bounds__(256, 4) void k_conv_fused(
    const float* __restrict__ images,
    const float* __restrict__ conv1_b, const float* __restrict__ conv2_b,
    const unsigned short* __restrict__ woff,
    const __fp16* __restrict__ whi,  const __fp16* __restrict__ wlo,
    const unsigned short* __restrict__ koff1,
    const __fp16* __restrict__ whi1, const __fp16* __restrict__ wlo1,
    float* __restrict__ x2)
{
    __shared__ unsigned int sImgP[4 * IMSZ];   // 17.0 KB
    __shared__ unsigned int sX1P[4 * X1SZ];    // 23.2 KB

    const int t  = threadIdx.x;
    const int b0 = blockIdx.x * 4;

    // ---- phase 0: images -> split-packed LDS (padded rows) ----
    for (int i = t; i < 4 * 784; i += 256) {
        const int img = i / 784;
        const int pix = i - img * 784;
        const int row = pix / 28;
        const int col = pix - row * 28;
        sImgP[img * IMSZ + row * IMS + col] = packsplit(images[(size_t)b0 * 784 + i]);
    }
    __syncthreads();

    const int lane = t & 63;
    const int wv   = t >> 6;
    const int g    = lane >> 4;          // k-group
    const int c0   = lane & 15;          // A-row (phase1/2) / D-col

    // ---- phase 1: conv1 via MFMA -> sX1P[wv][c*CH1 + q] ----
    {
        const unsigned int* imgP = sImgP + wv * IMSZ;
        unsigned int* x1P = sX1P + wv * X1SZ;

        const int sub = c0 & 3, qq = c0 >> 2;
        const int base_lane = (sub >> 1) * IMS + 2 * qq + (sub & 1);
        const ushort8 kof = *reinterpret_cast<const ushort8*>(koff1 + g * 8);
        int addr8[8];
        #pragma unroll
        for (int j = 0; j < 8; ++j) addr8[j] = base_lane + (int)kof[j];

        const f16x8 bh1 = *reinterpret_cast<const f16x8*>(whi1 + lane * 8);
        const f16x8 bl1 = *reinterpret_cast<const f16x8*>(wlo1 + lane * 8);
        const float bias = (c0 < 10) ? conv1_b[c0] : 0.f;

        #pragma unroll 1
        for (int a = 0; a < 12; ++a) {
            const int abase = a * (2 * IMS);
            #pragma unroll
            for (int b = 0; b < 3; ++b) {
                unsigned int w[8];
                #pragma unroll
                for (int j = 0; j < 8; ++j)
                    w[j] = imgP[addr8[j] + abase + b * 8];
                F16x8Cast AH, AL;
                AH.u = (uint4v){ __builtin_amdgcn_perm(w[1], w[0], PERM_AH),
                                 __builtin_amdgcn_perm(w[3], w[2], PERM_AH),
                                 __builtin_amdgcn_perm(w[5], w[4], PERM_AH),
                                 __builtin_amdgcn_perm(w[7], w[6], PERM_AH) };
                AL.u = (uint4v){ __builtin_amdgcn_perm(w[1], w[0], PERM_AL),
                                 __builtin_amdgcn_perm(w[3], w[2], PERM_AL),
                                 __builtin_amdgcn_perm(w[5], w[4], PERM_AL),
                                 __builtin_amdgcn_perm(w[7], w[6], PERM_AL) };
                f32x4 acc = {0.f, 0.f, 0.f, 0.f};
                acc = __builtin_amdgcn_mfma_f32_16x16x32_f16(AH.f, bh1, acc, 0, 0, 0);
                acc = __builtin_amdgcn_mfma_f32_16x16x32_f16(AL.f, bh1, acc, 0, 0, 0);
                acc = __builtin_amdgcn_mfma_f32_16x16x32_f16(AH.f, bl1, acc, 0, 0, 0);
                const float m = fmaxf(fmaxf(acc[0], acc[1]), fmaxf(acc[2], acc[3]));
                if (c0 < 10)
                    x1P[c0 * CH1 + 12 * a + 4 * b + g] = packsplit(selu_f(m + bias));
            }
        }
    }
    __syncthreads();

    // ---- phase 2: conv2 via MFMA (perm extraction) ----
    {
        const unsigned int* x1P = sX1P + wv * X1SZ;

        int rowbase[4];
        #pragma unroll
        for (int mi = 0; mi < 4; ++mi) {
            const int r64 = mi * 16 + c0;
            const int qi  = r64 >> 2;
            const int sb  = r64 & 3;
            rowbase[mi] = (2 * (qi >> 2) + (sb >> 1)) * 12
                        + 2 * (qi & 3) + (sb & 1);
        }

        f32x4 acc[4][2];
        #pragma unroll
        for (int mi = 0; mi < 4; ++mi) {
            acc[mi][0] = (f32x4){0.f, 0.f, 0.f, 0.f};
            acc[mi][1] = (f32x4){0.f, 0.f, 0.f, 0.f};
        }

        // double-buffered per-s data (named regs; no runtime indexing)
        ushort8 off = *reinterpret_cast<const ushort8*>(woff + g * 8);
        f16x8 bh0 = *reinterpret_cast<const f16x8*>(whi + (size_t)(0 * 64 + lane) * 8);
        f16x8 bl0 = *reinterpret_cast<const f16x8*>(wlo + (size_t)(0 * 64 + lane) * 8);
        f16x8 bh1 = *reinterpret_cast<const f16x8*>(whi + (size_t)(8 * 64 + lane) * 8);
        f16x8 bl1 = *reinterpret_cast<const f16x8*>(wlo + (size_t)(8 * 64 + lane) * 8);

        #pragma unroll 1
        for (int s = 0; s < 8; ++s) {
            const int sn = (s + 1) & 7;    // wraps harmlessly at s=7
            const ushort8 offn = *reinterpret_cast<const ushort8*>(woff + sn * 32 + g * 8);
            const f16x8 nbh0 = *reinterpret_cast<const f16x8*>(whi + (size_t)((0 + sn) * 64 + lane) * 8);
            const f16x8 nbl0 = *reinterpret_cast<const f16x8*>(wlo + (size_t)((0 + sn) * 64 + lane) * 8);
            const f16x8 nbh1 = *reinterpret_cast<const f16x8*>(whi + (size_t)((8 + sn) * 64 + lane) * 8);
            const f16x8 nbl1 = *reinterpret_cast<const f16x8*>(wlo + (size_t)((8 + sn) * 64 + lane) * 8);

            #pragma unroll
            for (int mi = 0; mi < 4; ++mi) {
                unsigned int w[8];
                #pragma unroll
                for (int j = 0; j < 8; ++j)
                    w[j] = x1P[rowbase[mi] + (int)off[j]];
                F16x8Cast AH, AL;
                AH.u = (uint4v){ __builtin_amdgcn_perm(w[1], w[0], PERM_AH),
                                 __builtin_amdgcn_perm(w[3], w[2], PERM_AH),
                                 __builtin_amdgcn_perm(w[5], w[4], PERM_AH),
                                 __builtin_amdgcn_perm(w[7], w[6], PERM_AH) };
                AL.u = (uint4v){ __builtin_amdgcn_perm(w[1], w[0], PERM_AL),
                                 __builtin_amdgcn_perm(w[3], w[2], PERM_AL),
                                 __builtin_amdgcn_perm(w[5], w[4], PERM_AL),
                                 __builtin_amdgcn_perm(w[7], w[6], PERM_AL) };
                acc[mi][0] = __builtin_amdgcn_mfma_f32_16x16x32_f16(AH.f, bh0, acc[mi][0], 0, 0, 0);
                acc[mi][0] = __builtin_amdgcn_mfma_f32_16x16x32_f16(AL.f, bh0, acc[mi][0], 0, 0, 0);
                acc[mi][0] = __builtin_amdgcn_mfma_f32_16x16x32_f16(AH.f, bl0, acc[mi][0], 0, 0, 0);
                acc[mi][1] = __builtin_amdgcn_mfma_f32_16x16x32_f16(AH.f, bh1, acc[mi][1], 0, 0, 0);
                acc[mi][1] = __builtin_amdgcn_mfma_f32_16x16x32_f16(AL.f, bh1, acc[mi][1], 0, 0, 0);
                acc[mi][1] = __builtin_amdgcn_mfma_f32_16x16x32_f16(AH.f, bl1, acc[mi][1], 0, 0, 0);
            }
            off = offn; bh0 = nbh0; bl0 = nbl0; bh1 = nbh1; bl1 = nbl1;
        }

        // epilogue: the 4 D-regs are one pool quad; qq = pooled pos
        const float bias0 = conv2_b[c0];
        const float bias1 = (c0 < 4) ? conv2_b[16 + c0] : 0.f;
        #pragma unroll
        for (int mi = 0; mi < 4; ++mi) {
            const int qq = mi * 4 + g;
            float* orow = x2 + (size_t)(b0 + wv) * 320 + qq * 20;
            const float v0 = fmaxf(fmaxf(acc[mi][0][0], acc[mi][0][1]),
                                   fmaxf(acc[mi][0][2], acc[mi][0][3]));
            orow[c0] = selu_f(v0 + bias0);
            if (c0 < 4) {
                const float v1 = fmaxf(fmaxf(acc[mi][1][0], acc[mi][1][1]),
                                       fmaxf(acc[mi][1][2], acc[mi][1][3]));
                orow[16 + c0] = selu_f(v1 + bias1);
            }
        }
    }
}

// ---------------------------------------------------------------------------
// Kernel B: lin1 (320->50, permuted weights) + selu, lin2 (50->25) -> code,
// THEN fused per-sample SVD-projector (fp32 Jacobi, threads 0..31, code rows
// already in LDS) -> proj. Replaces the standalone 1-wave/CU svdproj kernel
// (saves a launch + code round-trip + exposed serial latency).
// ---------------------------------------------------------------------------
__global__ __launch_bounds__(256) void k_lin12_svd(
    const float* __restrict__ x2,
    const float* __restrict__ lin1_wp, const float* __restrict__ lin1_b,
    const float* __restrict__ lin2_w,  const float* __restrict__ lin2_b,
    float* __restrict__ code, float* __restrict__ proj)
{
    __shared__ float sIn[32][324];
    __shared__ float sH[32][51];
    __shared__ float sC[32][28];
    const int t  = threadIdx.x;
    const int b0 = blockIdx.x * 32;
    {
        const float* g = x2 + (size_t)b0 * 320;
        for (int k = t; k < 2560; k += 256) {      // float4-vectorized staging
            const int r  = k / 80;
            const int c4 = k - r * 80;
            reinterpret_cast<float4*>(&sIn[r][0])[c4] =
                reinterpret_cast<const float4*>(g + r * 320)[c4];
        }
    }
    __syncthreads();

    for (int idx = t; idx < 1600; idx += 256) {        // 32 x 50
        const int bi = idx & 31;
        const int j  = idx >> 5;
        float s = lin1_b[j];
        const float4* w  = reinterpret_cast<const float4*>(lin1_wp + j * 320);
        const float4* xi = reinterpret_cast<const float4*>(&sIn[bi][0]);
        #pragma unroll 4
        for (int k4 = 0; k4 < 80; ++k4) {
            const float4 a = xi[k4];
            const float4 wq = w[k4];
            s = fmaf(a.x, wq.x, s); s = fmaf(a.y, wq.y, s);
            s = fmaf(a.z, wq.z, s); s = fmaf(a.w, wq.w, s);
        }
        sH[bi][j] = selu_f(s);
    }
    __syncthreads();
    for (int idx = t; idx < 800; idx += 256) {         // 32 x 25
        const int bi = idx & 31;
        const int j  = idx >> 5;
        float s = lin2_b[j];
        const float* w = lin2_w + j * 50;
        #pragma unroll
        for (int k = 0; k < 50; ++k) s = fmaf(sH[bi][k], w[k], s);
        code[(size_t)(b0 + bi) * 25 + j] = s;
        sC[bi][j] = s;
    }
    __syncthreads();

    // ---- fused SVD projector: thread t<32 handles sample b0+t ----
    if (t < 32) {
        float M[5][5];
        #pragma unroll
        for (int i = 0; i < 5; ++i)
            #pragma unroll
            for (int j = 0; j < 5; ++j) M[i][j] = sC[t][i * 5 + j];

        float A[5][5], V[5][5];
        #pragma unroll
        for (int i = 0; i < 5; ++i) {
            #pragma unroll
            for (int j = 0; j < 5; ++j) {
                float s = 0.f;
                #pragma unroll
                for (int k = 0; k < 5; ++k) s = fmaf(M[i][k], M[j][k], s);
                A[i][j] = s;
                V[i][j] = (i == j) ? 1.f : 0.f;
            }
        }
        for (int sweep = 0; sweep < 6; ++sweep) {
            #pragma unroll
            for (int p = 0; p < 4; ++p) {
                #pragma unroll
                for (int q = p + 1; q < 5; ++q) {
                    const float apq = A[p][q];
                    if (fabsf(apq) > 1e-30f) {
                        const float app = A[p][p], aqq = A[q][q];
                        const float tau = (aqq - app) / (2.f * apq);
                        const float tt  = (tau >= 0.f ? 1.f : -1.f) /
                                          (fabsf(tau) + sqrtf(1.f + tau * tau));
                        const float cc  = 1.f / sqrtf(1.f + tt * tt);
                        const float ss  = tt * cc;
                        #pragma unroll
                        for (int i = 0; i < 5; ++i) {
                            if (i == p || i == q) continue;
                            const float aip = A[i][p], aiq = A[i][q];
                            A[i][p] = A[p][i] = cc * aip - ss * aiq;
                            A[i][q] = A[q][i] = ss * aip + cc * aiq;
                        }
                        A[p][p] = app - tt * apq;
                        A[q][q] = aqq + tt * apq;
                        A[p][q] = A[q][p] = 0.f;
                        #pragma unroll
                        for (int i = 0; i < 5; ++i) {
                            const float vip = V[i][p], viq = V[i][q];
                            V[i][p] = cc * vip - ss * viq;
                            V[i][q] = ss * vip + cc * viq;
                        }
                    }
                }
            }
        }
        float d[5];
        #pragma unroll
        for (int i = 0; i < 5; ++i) d[i] = A[i][i];
        float sel[5];
        #pragma unroll
        for (int c1 = 0; c1 < 5; ++c1) {
            int cnt = 0;
            #pragma unroll
            for (int c2 = 0; c2 < 5; ++c2) {
                if (c2 == c1) continue;
                if (d[c2] > d[c1] || (d[c2] == d[c1] && c2 < c1)) ++cnt;
            }
            sel[c1] = (cnt < 2) ? 1.f : 0.f;
        }
        float* pr = proj + (size_t)(b0 + t) * 25;
        #pragma unroll
        for (int i = 0; i < 5; ++i) {
            #pragma unroll
            for (int j = 0; j < 5; ++j) {
                float s = 0.f;
                #pragma unroll
                for (int k = 0; k < 5; ++k) s = fmaf(sel[k] * V[i][k], V[j][k], s);
                pr[i * 5 + j] = s;
            }
        }
    }
}

// ---------------------------------------------------------------------------
// Kernel D: dec1 (25->160) + selu  ->  bf16 h in LDS  ->  dec2 (160->784)
//           via mfma_f32_16x16x32_bf16 + bias + sigmoid -> out[B][784]
// ---------------------------------------------------------------------------
#define HS 168   // padded h row stride in ushorts

__global__ __launch_bounds__(256) void k_decoder(
    const float* __restrict__ proj,
    const float* __restrict__ dec1_w, const float* __restrict__ dec1_b,
    const unsigned short* __restrict__ dec2_wb, const float* __restrict__ dec2_b,
    float* __restrict__ out)
{
    __shared__ unsigned short sH[32 * HS];
    const int t  = threadIdx.x;
    const int b0 = blockIdx.x * 32;
    const int bi = t & 31;     // sample row owned by this thread (phase 1)
    const int j0 = t >> 5;     // 0..7

    // ---- phase 1: h[bi][j] = selu(dec1), j = j0 + 8*i ----
    float p[25];
    {
        const float* pr = proj + (size_t)(b0 + bi) * 25;
        #pragma unroll
        for (int k = 0; k < 25; ++k) p[k] = pr[k];
    }
    #pragma unroll 4
    for (int i = 0; i < 20; ++i) {
        const int j = j0 + i * 8;
        const float* w = dec1_w + j * 25;
        float s = dec1_b[j];
        #pragma unroll
        for (int k = 0; k < 25; ++k) s = fmaf(p[k], w[k], s);
        sH[bi * HS + j] = f2bf(selu_f(s));
    }
    __syncthreads();

    // ---- phase 2: out[32][784] = sigmoid(h @ W^T + b) via MFMA ----
    const int wv   = t >> 6;      // 0..3
    const int lane = t & 63;
    const int arow = lane & 15;   // A row / B col within tile
    const int kgrp = lane >> 4;   // 0..3

    bf16x8 afr[2][5];             // hoisted A fragments: 2 row-tiles x 5 k-steps
    #pragma unroll
    for (int rt = 0; rt < 2; ++rt)
        #pragma unroll
        for (int ks = 0; ks < 5; ++ks)
            afr[rt][ks] = *reinterpret_cast<const bf16x8*>(
                &sH[(rt * 16 + arow) * HS + ks * 32 + kgrp * 8]);

    for (int ct = wv; ct < 49; ct += 4) {
        const int col = ct * 16 + arow;
        bf16x8 bfr[5];
        const unsigned short* wp = dec2_wb + (size_t)col * 160 + kgrp * 8;
        #pragma unroll
        for (int ks = 0; ks < 5; ++ks)
            bfr[ks] = *reinterpret_cast<const bf16x8*>(wp + ks * 32);

        f32x4 acc0 = {0.f, 0.f, 0.f, 0.f};
        f32x4 acc1 = {0.f, 0.f, 0.f, 0.f};
        #pragma unroll
        for (int ks = 0; ks < 5; ++ks) {
            acc0 = __builtin_amdgcn_mfma_f32_16x16x32_bf16(afr[0][ks], bfr[ks], acc0, 0, 0, 0);
            acc1 = __builtin_amdgcn_mfma_f32_16x16x32_bf16(afr[1][ks], bfr[ks], acc1, 0, 0, 0);
        }
        const float bb = dec2_b[col];
        #pragma unroll
        for (int r = 0; r < 4; ++r) {
            const int row = kgrp * 4 + r;          // D: row=(lane>>4)*4+reg
            const float v0 = acc0[r] + bb;
            const float v1 = acc1[r] + bb;
            out[(size_t)(b0 + row) * 784 + col]      = 1.0f / (1.0f + __expf(-v0));
            out[(size_t)(b0 + 16 + row) * 784 + col] = 1.0f / (1.0f + __expf(-v1));
        }
    }
}

// ---------------------------------------------------------------------------
extern "C" void kernel_launch(void* const* d_in, const int* in_sizes, int n_in,
                              void* d_out, int out_size, void* d_ws, size_t ws_size,
                              hipStream_t stream) {
    const float* images  = (const float*)d_in[0];
    const float* conv1_w = (const float*)d_in[1];
    const float* conv1_b = (const float*)d_in[2];
    const float* conv2_w = (const float*)d_in[3];
    const float* conv2_b = (const float*)d_in[4];
    const float* lin1_w  = (const float*)d_in[5];
    const float* lin1_b  = (const float*)d_in[6];
    const float* lin2_w  = (const float*)d_in[7];
    const float* lin2_b  = (const float*)d_in[8];
    const float* dec1_w  = (const float*)d_in[9];
    const float* dec1_b  = (const float*)d_in[10];
    const float* dec2_w  = (const float*)d_in[11];
    const float* dec2_b  = (const float*)d_in[12];

    float* out_img = (float*)d_out;                    // NB*784 fp32
    float* code    = (float*)d_out + (size_t)NB * 784; // NB*25  fp32

    // workspace layout (bytes, all 16-aligned):
    char* ws = (char*)d_ws;
    float*          x2      = (float*)ws;                                  // NB*320 f
    float*          proj    = (float*)(ws + (size_t)NB * 320 * 4);         // NB*25 f
    unsigned short* wbf     = (unsigned short*)(ws + (size_t)NB * 345 * 4);// 125440 us
    char*           pB      = ws + (size_t)NB * 345 * 4 + 250880;
    float*          lin1_wp = (float*)pB;                                  // 16000 f
    unsigned short* woff    = (unsigned short*)(pB + 64000);               // 256 us
    __fp16*         whi     = (__fp16*)(pB + 64512);                       // 8192 h
    __fp16*         wlo     = (__fp16*)(pB + 80896);                       // 8192 h
    unsigned short* koff1   = (unsigned short*)(pB + 97280);               // 32 us
    __fp16*         whi1    = (__fp16*)(pB + 97344);                       // 512 h
    __fp16*         wlo1    = (__fp16*)(pB + 98368);                       // 512 h

    k_prep     <<<622,      256, 0, stream>>>(dec2_w, wbf, lin1_w, lin1_wp,
                                              conv2_w, woff, whi, wlo,
                                              conv1_w, koff1, whi1, wlo1);
    k_conv_fused<<<NB / 4,  256, 0, stream>>>(images, conv1_b, conv2_b,
                                              woff, whi, wlo,
                                              koff1, whi1, wlo1, x2);
    k_lin12_svd<<<NB / 32, 256, 0, stream>>>(x2, lin1_wp, lin1_b,
                                             lin2_w, lin2_b, code, proj);
    k_decoder  <<<NB / 32, 256, 0, stream>>>(proj, dec1_w, dec1_b,
                                             wbf, dec2_b, out_img);
}

// Round 13
// 188.248 us; speedup vs baseline: 1.3855x; 1.0070x over previous
//
#include <hip/hip_runtime.h>
#include <hip/hip_bf16.h>
#include <math.h>

#define NB 16384

typedef __bf16 bf16x8 __attribute__((ext_vector_type(8)));
typedef __fp16 f16x8  __attribute__((ext_vector_type(8)));
typedef float  f32x4  __attribute__((ext_vector_type(4)));
typedef unsigned short ushort4v __attribute__((ext_vector_type(4)));
typedef unsigned int   uint4v  __attribute__((ext_vector_type(4)));

__device__ __forceinline__ float selu_f(float x) {
    const float kScale = 1.0507009873554805f;
    const float kAlphaScale = 1.7580993408473766f;   // scale*alpha
    return x > 0.0f ? kScale * x : kAlphaScale * (__expf(x) - 1.0f);
}

__device__ __forceinline__ unsigned short f2bf(float x) {   // RNE
    unsigned int u = __float_as_uint(x);
    unsigned int r = (u + 0x7FFFu + ((u >> 16) & 1u)) >> 16;
    return (unsigned short)r;
}

// split v into fp16 hi + fp16 lo, packed into one u32 (lo16=hi, hi16=lo)
__device__ __forceinline__ unsigned int packsplit(float v) {
    const __fp16 h = (__fp16)v;
    const __fp16 l = (__fp16)(v - (float)h);
    const unsigned int hb = (unsigned int)__builtin_bit_cast(unsigned short, h);
    const unsigned int lb = (unsigned int)__builtin_bit_cast(unsigned short, l);
    return hb | (lb << 16);
}

// extract packed pairs: AH u32 = hi fp16s, AL u32 = lo fp16s
#define PERM_AH 0x05040100u
#define PERM_AL 0x07060302u

union F16x8Cast { uint4v u; f16x8 f; };

#define CH1 145          // x1 channel stride (u32)
#define X1SZ (CH1 * 10)  // 1450 u32 per image
#define IMS 37           // sImgP row stride
#define IMSZ 1064        // per image

// ---------------------------------------------------------------------------
// K-permutations for pairwise (ds_read2-mergeable) A-gathers. The SAME elem
// function generates the A-offset table and the B-weight table, so A/B always
// agree. Invariants (hand-verified): each real element appears exactly once;
// partner deltas are j-pair-uniform: conv1 all +1; conv2 jp0-2 +1, jp3 +145.
// ---------------------------------------------------------------------------
// conv2: slot (s,g,j) -> element ic*25+tap, or -1 (B=0 dummy).
//  jp<3 (H-region, 96 pairs): ch0-5: 10 H-pairs each (taps except col-4);
//    ch6-9: 9 H-pairs each (taps except {2,3} and col-4).
//  jp==3 (C-region, 32 pairs): q<15: ch-pairs (0,1),(2,3),(4,5) x col-4 taps;
//    q in 15..28: ch-pairs (6,7),(8,9) x {2,3,4,9,14,19,24}; q>=29 dummy.
__device__ __forceinline__ int c2_elem(int s, int g, int j) {
    const int o = s * 4 + g, jp = j >> 1, hl = j & 1;
    if (jp < 3) {
        const int p = o * 3 + jp;
        int ch, idx;
        if (p < 60) { ch = p / 10; idx = p - ch * 10; }
        else        { ch = 6 + (p - 60) / 9; idx = (p - 60) % 9; }
        int tap;
        if (ch < 6)        tap = 5 * (idx >> 1) + 2 * (idx & 1);
        else if (idx == 0) tap = 0;
        else { const int r = ((idx - 1) >> 1) + 1; tap = 5 * r + 2 * ((idx - 1) & 1); }
        return ch * 25 + tap + hl;
    } else {
        const int q = o;
        if (q >= 29) return -1;
        int chp, tap;
        if (q < 15) { chp = q / 5; const int ts = q - chp * 5; tap = 5 * ts + 4; }
        else { const int q2 = q - 15; chp = 3 + q2 / 7; const int ts = q2 % 7;
               tap = (ts < 2) ? (2 + ts) : (5 * (ts - 2) + 4); }
        return (2 * chp + hl) * 25 + tap;
    }
}
// conv1: slot (g,j) -> tap, or -1. p<10: H-pairs; p 10..14: col-4 singles
// (partner dummy); p==15 dummy.
__device__ __forceinline__ int c1_elem(int g, int j) {
    const int p = g * 4 + (j >> 1), hl = j & 1;
    if (p < 10) return 5 * (p >> 1) + 2 * (p & 1) + hl;
    if (p < 15) return hl ? -1 : (5 * (p - 10) + 4);
    return -1;
}

// ---------------------------------------------------------------------------
// Kernel P (prep): builds all weight-derived tables in ws.
// ---------------------------------------------------------------------------
__global__ __launch_bounds__(256) void k_prep(
    const float* __restrict__ dec2_w,  unsigned short* __restrict__ wbf,
    const float* __restrict__ lin1_w,  float* __restrict__ lin1_wp,
    const float* __restrict__ conv2_w, unsigned short* __restrict__ woff4,
    __fp16* __restrict__ whi, __fp16* __restrict__ wlo,
    const float* __restrict__ conv1_w, unsigned short* __restrict__ koff4,
    __fp16* __restrict__ whi1, __fp16* __restrict__ wlo1)
{
    int i = blockIdx.x * 256 + threadIdx.x;
    if (i < 125440) { wbf[i] = f2bf(dec2_w[i]); return; }
    i -= 125440;
    if (i < 16000) {                       // lin1 permute
        const int row = i / 320, cn = i - row * 320;
        const int q = cn / 20, oc = cn - q * 20;
        lin1_wp[row * 320 + cn] = lin1_w[row * 320 + oc * 16 + q];
        return;
    }
    i -= 16000;
    if (i < 128) {                         // conv2 pair-base offsets
        const int s = i >> 4, g = (i >> 2) & 3, jp = i & 3;
        const int e = c2_elem(s, g, jp * 2);
        unsigned short off = 0;
        if (e >= 0) {
            const int ic = e / 25, tap = e - ic * 25;
            off = (unsigned short)(ic * CH1 + (tap / 5) * 12 + tap % 5);
        }
        woff4[i] = off;
        return;
    }
    i -= 128;
    if (i < 16384) {                       // conv2 weight split tables
        const int v = i >> 13;             // 0 = hi, 1 = lo
        const int r = i & 8191;
        const int j = r & 7, lane = (r >> 3) & 63, s = (r >> 9) & 7, nt = r >> 12;
        const int oc = nt * 16 + (lane & 15);
        const int e = c2_elem(s, lane >> 4, j);
        float w = 0.f;
        if (e >= 0 && oc < 20) {
            const int ic = e / 25, tap = e - ic * 25;
            w = conv2_w[(oc * 10 + ic) * 25 + tap];
        }
        const __fp16 hi = (__fp16)w;
        if (v == 0) whi[r] = hi;
        else        wlo[r] = (__fp16)(w - (float)hi);
        return;
    }
    i -= 16384;
    if (i < 16) {                          // conv1 pair-base offsets
        const int e = c1_elem(i >> 2, (i & 3) * 2);
        koff4[i] = (unsigned short)(e < 0 ? 0 : (e / 5) * IMS + e % 5);
        return;
    }
    i -= 16;
    if (i < 1024) {                        // conv1 weight split tables
        const int v = i >> 9;
        const int r = i & 511;
        const int j = r & 7, lane = r >> 3;
        const int c = lane & 15, g = lane >> 4;
        const int e = c1_elem(g, j);
        const float w = (e >= 0 && c < 10) ? conv1_w[c * 25 + e] : 0.f;
        const __fp16 hi = (__fp16)w;
        if (v == 0) whi1[r] = hi;
        else        wlo1[r] = (__fp16)(w - (float)hi);
    }
}

// ---------------------------------------------------------------------------
// Kernel A: conv1+conv2 split-fp16 MFMA (r10 structure) with PAIRED LDS
// gathers: j-pairs share a base address + compile-time delta (+1 / +145 u32)
// so the backend merges each pair into ds_read2_b32 (halves LDS issue count;
// m134: ds_read_b32 is issue-bound at 5.8cyc). Lessons pinned: (256,4) only
// (r4), unroll-1 outer + small live sets (r6), no conv2 K-padding (r9),
// phase-1 patches from LDS not global (r11).
// ---------------------------------------------------------------------------
__global__ __launch_bounds__(256, 4) void k_conv_fused(
    const float* __restrict__ images,
    const float* __restrict__ conv1_b, const float* __restrict__ conv2_b,
    const unsigned short* __restrict__ woff4,
    const __fp16* __restrict__ whi,  const __fp16* __restrict__ wlo,
    const unsigned short* __restrict__ koff4,
    const __fp16* __restrict__ whi1, const __fp16* __restrict__ wlo1,
    float* __restrict__ x2)
{
    __shared__ unsigned int sImgP[4 * IMSZ];   // 17.0 KB
    __shared__ unsigned int sX1P[4 * X1SZ];    // 23.2 KB

    const int t  = threadIdx.x;
    const int b0 = blockIdx.x * 4;

    // ---- phase 0: images -> split-packed LDS (padded rows) ----
    for (int i = t; i < 4 * 784; i += 256) {
        const int img = i / 784;
        const int pix = i - img * 784;
        const int row = pix / 28;
        const int col = pix - row * 28;
        sImgP[img * IMSZ + row * IMS + col] = packsplit(images[(size_t)b0 * 784 + i]);
    }
    // zero col 28 (read by dummy pair-partners of col-4 taps; must be finite)
    for (int i = t; i < 112; i += 256) {
        const int img = i / 28, row = i - img * 28;
        sImgP[img * IMSZ + row * IMS + 28] = 0u;
    }
    __syncthreads();

    const int lane = t & 63;
    const int wv   = t >> 6;
    const int g    = lane >> 4;          // k-group
    const int c0   = lane & 15;          // A-row (phase1/2) / D-col

    // ---- phase 1: conv1 via MFMA -> sX1P[wv][c*CH1 + q] ----
    {
        const unsigned int* imgP = sImgP + wv * IMSZ;
        unsigned int* x1P = sX1P + wv * X1SZ;

        const int sub = c0 & 3, qq = c0 >> 2;
        const int base_lane = (sub >> 1) * IMS + 2 * qq + (sub & 1);
        const ushort4v k4 = *reinterpret_cast<const ushort4v*>(koff4 + g * 4);
        int ab[4];
        #pragma unroll
        for (int jp = 0; jp < 4; ++jp) ab[jp] = base_lane + (int)k4[jp];

        const f16x8 bh1 = *reinterpret_cast<const f16x8*>(whi1 + lane * 8);
        const f16x8 bl1 = *reinterpret_cast<const f16x8*>(wlo1 + lane * 8);
        const float bias = (c0 < 10) ? conv1_b[c0] : 0.f;

        #pragma unroll 1
        for (int a = 0; a < 12; ++a) {
            const int abase = a * (2 * IMS);
            #pragma unroll
            for (int b = 0; b < 3; ++b) {
                const unsigned int* pb_ = imgP + abase + b * 8;
                unsigned int w[8];
                const unsigned int* r0 = pb_ + ab[0]; w[0] = r0[0]; w[1] = r0[1];
                const unsigned int* r1 = pb_ + ab[1]; w[2] = r1[0]; w[3] = r1[1];
                const unsigned int* r2 = pb_ + ab[2]; w[4] = r2[0]; w[5] = r2[1];
                const unsigned int* r3 = pb_ + ab[3]; w[6] = r3[0]; w[7] = r3[1];
                F16x8Cast AH, AL;
                AH.u = (uint4v){ __builtin_amdgcn_perm(w[1], w[0], PERM_AH),
                                 __builtin_amdgcn_perm(w[3], w[2], PERM_AH),
                                 __builtin_amdgcn_perm(w[5], w[4], PERM_AH),
                                 __builtin_amdgcn_perm(w[7], w[6], PERM_AH) };
                AL.u = (uint4v){ __builtin_amdgcn_perm(w[1], w[0], PERM_AL),
                                 __builtin_amdgcn_perm(w[3], w[2], PERM_AL),
                                 __builtin_amdgcn_perm(w[5], w[4], PERM_AL),
                                 __builtin_amdgcn_perm(w[7], w[6], PERM_AL) };
                f32x4 acc = {0.f, 0.f, 0.f, 0.f};
                acc = __builtin_amdgcn_mfma_f32_16x16x32_f16(AH.f, bh1, acc, 0, 0, 0);
                acc = __builtin_amdgcn_mfma_f32_16x16x32_f16(AL.f, bh1, acc, 0, 0, 0);
                acc = __builtin_amdgcn_mfma_f32_16x16x32_f16(AH.f, bl1, acc, 0, 0, 0);
                const float m = fmaxf(fmaxf(acc[0], acc[1]), fmaxf(acc[2], acc[3]));
                if (c0 < 10)
                    x1P[c0 * CH1 + 12 * a + 4 * b + g] = packsplit(selu_f(m + bias));
            }
        }
    }
    __syncthreads();

    // ---- phase 2: conv2 via MFMA (perm extraction, paired gathers) ----
    {
        const unsigned int* x1P = sX1P + wv * X1SZ;

        int rowbase[4];
        #pragma unroll
        for (int mi = 0; mi < 4; ++mi) {
            const int r64 = mi * 16 + c0;
            const int qi  = r64 >> 2;
            const int sb  = r64 & 3;
            rowbase[mi] = (2 * (qi >> 2) + (sb >> 1)) * 12
                        + 2 * (qi & 3) + (sb & 1);
        }

        f32x4 acc[4][2];
        #pragma unroll
        for (int mi = 0; mi < 4; ++mi) {
            acc[mi][0] = (f32x4){0.f, 0.f, 0.f, 0.f};
            acc[mi][1] = (f32x4){0.f, 0.f, 0.f, 0.f};
        }

        // double-buffered per-s data (named regs; no runtime indexing)
        ushort4v of = *reinterpret_cast<const ushort4v*>(woff4 + g * 4);
        f16x8 bh0 = *reinterpret_cast<const f16x8*>(whi + (size_t)(0 * 64 + lane) * 8);
        f16x8 bl0 = *reinterpret_cast<const f16x8*>(wlo + (size_t)(0 * 64 + lane) * 8);
        f16x8 bh1 = *reinterpret_cast<const f16x8*>(whi + (size_t)(8 * 64 + lane) * 8);
        f16x8 bl1 = *reinterpret_cast<const f16x8*>(wlo + (size_t)(8 * 64 + lane) * 8);

        #pragma unroll 1
        for (int s = 0; s < 8; ++s) {
            const int sn = (s + 1) & 7;    // wraps harmlessly at s=7
            const ushort4v ofn = *reinterpret_cast<const ushort4v*>(woff4 + sn * 16 + g * 4);
            const f16x8 nbh0 = *reinterpret_cast<const f16x8*>(whi + (size_t)((0 + sn) * 64 + lane) * 8);
            const f16x8 nbl0 = *reinterpret_cast<const f16x8*>(wlo + (size_t)((0 + sn) * 64 + lane) * 8);
            const f16x8 nbh1 = *reinterpret_cast<const f16x8*>(whi + (size_t)((8 + sn) * 64 + lane) * 8);
            const f16x8 nbl1 = *reinterpret_cast<const f16x8*>(wlo + (size_t)((8 + sn) * 64 + lane) * 8);

            #pragma unroll
            for (int mi = 0; mi < 4; ++mi) {
                const unsigned int* pp = x1P + rowbase[mi];
                unsigned int w[8];
                const unsigned int* q0 = pp + (int)of[0]; w[0] = q0[0]; w[1] = q0[1];
                const unsigned int* q1 = pp + (int)of[1]; w[2] = q1[0]; w[3] = q1[1];
                const unsigned int* q2 = pp + (int)of[2]; w[4] = q2[0]; w[5] = q2[1];
                const unsigned int* q3 = pp + (int)of[3]; w[6] = q3[0]; w[7] = q3[145];
                F16x8Cast AH, AL;
                AH.u = (uint4v){ __builtin_amdgcn_perm(w[1], w[0], PERM_AH),
                                 __builtin_amdgcn_perm(w[3], w[2], PERM_AH),
                                 __builtin_amdgcn_perm(w[5], w[4], PERM_AH),
                                 __builtin_amdgcn_perm(w[7], w[6], PERM_AH) };
                AL.u = (uint4v){ __builtin_amdgcn_perm(w[1], w[0], PERM_AL),
                                 __builtin_amdgcn_perm(w[3], w[2], PERM_AL),
                                 __builtin_amdgcn_perm(w[5], w[4], PERM_AL),
                                 __builtin_amdgcn_perm(w[7], w[6], PERM_AL) };
                acc[mi][0] = __builtin_amdgcn_mfma_f32_16x16x32_f16(AH.f, bh0, acc[mi][0], 0, 0, 0);
                acc[mi][0] = __builtin_amdgcn_mfma_f32_16x16x32_f16(AL.f, bh0, acc[mi][0], 0, 0, 0);
                acc[mi][0] = __builtin_amdgcn_mfma_f32_16x16x32_f16(AH.f, bl0, acc[mi][0], 0, 0, 0);
                acc[mi][1] = __builtin_amdgcn_mfma_f32_16x16x32_f16(AH.f, bh1, acc[mi][1], 0, 0, 0);
                acc[mi][1] = __builtin_amdgcn_mfma_f32_16x16x32_f16(AL.f, bh1, acc[mi][1], 0, 0, 0);
                acc[mi][1] = __builtin_amdgcn_mfma_f32_16x16x32_f16(AH.f, bl1, acc[mi][1], 0, 0, 0);
            }
            of = ofn; bh0 = nbh0; bl0 = nbl0; bh1 = nbh1; bl1 = nbl1;
        }

        // epilogue: the 4 D-regs are one pool quad; qq = pooled pos
        const float bias0 = conv2_b[c0];
        const float bias1 = (c0 < 4) ? conv2_b[16 + c0] : 0.f;
        #pragma unroll
        for (int mi = 0; mi < 4; ++mi) {
            const int qq = mi * 4 + g;
            float* orow = x2 + (size_t)(b0 + wv) * 320 + qq * 20;
            const float v0 = fmaxf(fmaxf(acc[mi][0][0], acc[mi][0][1]),
                                   fmaxf(acc[mi][0][2], acc[mi][0][3]));
            orow[c0] = selu_f(v0 + bias0);
            if (c0 < 4) {
                const float v1 = fmaxf(fmaxf(acc[mi][1][0], acc[mi][1][1]),
                                       fmaxf(acc[mi][1][2], acc[mi][1][3]));
                orow[16 + c0] = selu_f(v1 + bias1);
            }
        }
    }
}

// ---------------------------------------------------------------------------
// Kernel B: lin1 + selu, lin2 -> code, then fused fp32-Jacobi SVD projector
// (threads 0..31, code rows already in LDS) -> proj.  (r12, unchanged)
// ---------------------------------------------------------------------------
__global__ __launch_bounds__(256) void k_lin12_svd(
    const float* __restrict__ x2,
    const float* __restrict__ lin1_wp, const float* __restrict__ lin1_b,
    const float* __restrict__ lin2_w,  const float* __restrict__ lin2_b,
    float* __restrict__ code, float* __restrict__ proj)
{
    __shared__ float sIn[32][324];
    __shared__ float sH[32][51];
    __shared__ float sC[32][28];
    const int t  = threadIdx.x;
    const int b0 = blockIdx.x * 32;
    {
        const float* g = x2 + (size_t)b0 * 320;
        for (int k = t; k < 2560; k += 256) {
            const int r  = k / 80;
            const int c4 = k - r * 80;
            reinterpret_cast<float4*>(&sIn[r][0])[c4] =
                reinterpret_cast<const float4*>(g + r * 320)[c4];
        }
    }
    __syncthreads();

    for (int idx = t; idx < 1600; idx += 256) {        // 32 x 50
        const int bi = idx & 31;
        const int j  = idx >> 5;
        float s = lin1_b[j];
        const float4* w  = reinterpret_cast<const float4*>(lin1_wp + j * 320);
        const float4* xi = reinterpret_cast<const float4*>(&sIn[bi][0]);
        #pragma unroll 4
        for (int k4 = 0; k4 < 80; ++k4) {
            const float4 a = xi[k4];
            const float4 wq = w[k4];
            s = fmaf(a.x, wq.x, s); s = fmaf(a.y, wq.y, s);
            s = fmaf(a.z, wq.z, s); s = fmaf(a.w, wq.w, s);
        }
        sH[bi][j] = selu_f(s);
    }
    __syncthreads();
    for (int idx = t; idx < 800; idx += 256) {         // 32 x 25
        const int bi = idx & 31;
        const int j  = idx >> 5;
        float s = lin2_b[j];
        const float* w = lin2_w + j * 50;
        #pragma unroll
        for (int k = 0; k < 50; ++k) s = fmaf(sH[bi][k], w[k], s);
        code[(size_t)(b0 + bi) * 25 + j] = s;
        sC[bi][j] = s;
    }
    __syncthreads();

    if (t < 32) {
        float M[5][5];
        #pragma unroll
        for (int i = 0; i < 5; ++i)
            #pragma unroll
            for (int j = 0; j < 5; ++j) M[i][j] = sC[t][i * 5 + j];

        float A[5][5], V[5][5];
        #pragma unroll
        for (int i = 0; i < 5; ++i) {
            #pragma unroll
            for (int j = 0; j < 5; ++j) {
                float s = 0.f;
                #pragma unroll
                for (int k = 0; k < 5; ++k) s = fmaf(M[i][k], M[j][k], s);
                A[i][j] = s;
                V[i][j] = (i == j) ? 1.f : 0.f;
            }
        }
        for (int sweep = 0; sweep < 6; ++sweep) {
            #pragma unroll
            for (int p = 0; p < 4; ++p) {
                #pragma unroll
                for (int q = p + 1; q < 5; ++q) {
                    const float apq = A[p][q];
                    if (fabsf(apq) > 1e-30f) {
                        const float app = A[p][p], aqq = A[q][q];
                        const float tau = (aqq - app) / (2.f * apq);
                        const float tt  = (tau >= 0.f ? 1.f : -1.f) /
                                          (fabsf(tau) + sqrtf(1.f + tau * tau));
                        const float cc  = 1.f / sqrtf(1.f + tt * tt);
                        const float ss  = tt * cc;
                        #pragma unroll
                        for (int i = 0; i < 5; ++i) {
                            if (i == p || i == q) continue;
                            const float aip = A[i][p], aiq = A[i][q];
                            A[i][p] = A[p][i] = cc * aip - ss * aiq;
                            A[i][q] = A[q][i] = ss * aip + cc * aiq;
                        }
                        A[p][p] = app - tt * apq;
                        A[q][q] = aqq + tt * apq;
                        A[p][q] = A[q][p] = 0.f;
                        #pragma unroll
                        for (int i = 0; i < 5; ++i) {
                            const float vip = V[i][p], viq = V[i][q];
                            V[i][p] = cc * vip - ss * viq;
                            V[i][q] = ss * vip + cc * viq;
                        }
                    }
                }
            }
        }
        float d[5];
        #pragma unroll
        for (int i = 0; i < 5; ++i) d[i] = A[i][i];
        float sel[5];
        #pragma unroll
        for (int c1 = 0; c1 < 5; ++c1) {
            int cnt = 0;
            #pragma unroll
            for (int c2 = 0; c2 < 5; ++c2) {
                if (c2 == c1) continue;
                if (d[c2] > d[c1] || (d[c2] == d[c1] && c2 < c1)) ++cnt;
            }
            sel[c1] = (cnt < 2) ? 1.f : 0.f;
        }
        float* pr = proj + (size_t)(b0 + t) * 25;
        #pragma unroll
        for (int i = 0; i < 5; ++i) {
            #pragma unroll
            for (int j = 0; j < 5; ++j) {
                float s = 0.f;
                #pragma unroll
                for (int k = 0; k < 5; ++k) s = fmaf(sel[k] * V[i][k], V[j][k], s);
                pr[i * 5 + j] = s;
            }
        }
    }
}

// ---------------------------------------------------------------------------
// Kernel D: dec1 (25->160) + selu  ->  bf16 h in LDS  ->  dec2 (160->784)
//           via mfma_f32_16x16x32_bf16 + bias + sigmoid -> out[B][784]
// ---------------------------------------------------------------------------
#define HS 168   // padded h row stride in ushorts

__global__ __launch_bounds__(256) void k_decoder(
    const float* __restrict__ proj,
    const float* __restrict__ dec1_w, const float* __restrict__ dec1_b,
    const unsigned short* __restrict__ dec2_wb, const float* __restrict__ dec2_b,
    float* __restrict__ out)
{
    __shared__ unsigned short sH[32 * HS];
    const int t  = threadIdx.x;
    const int b0 = blockIdx.x * 32;
    const int bi = t & 31;     // sample row owned by this thread (phase 1)
    const int j0 = t >> 5;     // 0..7

    // ---- phase 1: h[bi][j] = selu(dec1), j = j0 + 8*i ----
    float p[25];
    {
        const float* pr = proj + (size_t)(b0 + bi) * 25;
        #pragma unroll
        for (int k = 0; k < 25; ++k) p[k] = pr[k];
    }
    #pragma unroll 4
    for (int i = 0; i < 20; ++i) {
        const int j = j0 + i * 8;
        const float* w = dec1_w + j * 25;
        float s = dec1_b[j];
        #pragma unroll
        for (int k = 0; k < 25; ++k) s = fmaf(p[k], w[k], s);
        sH[bi * HS + j] = f2bf(selu_f(s));
    }
    __syncthreads();

    // ---- phase 2: out[32][784] = sigmoid(h @ W^T + b) via MFMA ----
    const int wv   = t >> 6;      // 0..3
    const int lane = t & 63;
    const int arow = lane & 15;   // A row / B col within tile
    const int kgrp = lane >> 4;   // 0..3

    bf16x8 afr[2][5];             // hoisted A fragments: 2 row-tiles x 5 k-steps
    #pragma unroll
    for (int rt = 0; rt < 2; ++rt)
        #pragma unroll
        for (int ks = 0; ks < 5; ++ks)
            afr[rt][ks] = *reinterpret_cast<const bf16x8*>(
                &sH[(rt * 16 + arow) * HS + ks * 32 + kgrp * 8]);

    for (int ct = wv; ct < 49; ct += 4) {
        const int col = ct * 16 + arow;
        bf16x8 bfr[5];
        const unsigned short* wp = dec2_wb + (size_t)col * 160 + kgrp * 8;
        #pragma unroll
        for (int ks = 0; ks < 5; ++ks)
            bfr[ks] = *reinterpret_cast<const bf16x8*>(wp + ks * 32);

        f32x4 acc0 = {0.f, 0.f, 0.f, 0.f};
        f32x4 acc1 = {0.f, 0.f, 0.f, 0.f};
        #pragma unroll
        for (int ks = 0; ks < 5; ++ks) {
            acc0 = __builtin_amdgcn_mfma_f32_16x16x32_bf16(afr[0][ks], bfr[ks], acc0, 0, 0, 0);
            acc1 = __builtin_amdgcn_mfma_f32_16x16x32_bf16(afr[1][ks], bfr[ks], acc1, 0, 0, 0);
        }
        const float bb = dec2_b[col];
        #pragma unroll
        for (int r = 0; r < 4; ++r) {
            const int row = kgrp * 4 + r;          // D: row=(lane>>4)*4+reg
            const float v0 = acc0[r] + bb;
            const float v1 = acc1[r] + bb;
            out[(size_t)(b0 + row) * 784 + col]      = 1.0f / (1.0f + __expf(-v0));
            out[(size_t)(b0 + 16 + row) * 784 + col] = 1.0f / (1.0f + __expf(-v1));
        }
    }
}

// ---------------------------------------------------------------------------
extern "C" void kernel_launch(void* const* d_in, const int* in_sizes, int n_in,
                              void* d_out, int out_size, void* d_ws, size_t ws_size,
                              hipStream_t stream) {
    const float* images  = (const float*)d_in[0];
    const float* conv1_w = (const float*)d_in[1];
    const float* conv1_b = (const float*)d_in[2];
    const float* conv2_w = (const float*)d_in[3];
    const float* conv2_b = (const float*)d_in[4];
    const float* lin1_w  = (const float*)d_in[5];
    const float* lin1_b  = (const float*)d_in[6];
    const float* lin2_w  = (const float*)d_in[7];
    const float* lin2_b  = (const float*)d_in[8];
    const float* dec1_w  = (const float*)d_in[9];
    const float* dec1_b  = (const float*)d_in[10];
    const float* dec2_w  = (const float*)d_in[11];
    const float* dec2_b  = (const float*)d_in[12];

    float* out_img = (float*)d_out;                    // NB*784 fp32
    float* code    = (float*)d_out + (size_t)NB * 784; // NB*25  fp32

    // workspace layout (bytes, all 16-aligned):
    char* ws = (char*)d_ws;
    float*          x2      = (float*)ws;                                  // NB*320 f
    float*          proj    = (float*)(ws + (size_t)NB * 320 * 4);         // NB*25 f
    unsigned short* wbf     = (unsigned short*)(ws + (size_t)NB * 345 * 4);// 125440 us
    char*           pB      = ws + (size_t)NB * 345 * 4 + 250880;
    float*          lin1_wp = (float*)pB;                                  // 16000 f
    unsigned short* woff4   = (unsigned short*)(pB + 64000);               // 128 us
    __fp16*         whi     = (__fp16*)(pB + 64512);                       // 8192 h
    __fp16*         wlo     = (__fp16*)(pB + 80896);                       // 8192 h
    unsigned short* koff4   = (unsigned short*)(pB + 97280);               // 16 us
    __fp16*         whi1    = (__fp16*)(pB + 97344);                       // 512 h
    __fp16*         wlo1    = (__fp16*)(pB + 98368);                       // 512 h

    k_prep     <<<622,      256, 0, stream>>>(dec2_w, wbf, lin1_w, lin1_wp,
                                              conv2_w, woff4, whi, wlo,
                                              conv1_w, koff4, whi1, wlo1);
    k_conv_fused<<<NB / 4,  256, 0, stream>>>(images, conv1_b, conv2_b,
                                              woff4, whi, wlo,
                                              koff4, whi1, wlo1, x2);
    k_lin12_svd<<<NB / 32, 256, 0, stream>>>(x2, lin1_wp, lin1_b,
                                             lin2_w, lin2_b, code, proj);
    k_decoder  <<<NB / 32, 256, 0, stream>>>(proj, dec1_w, dec1_b,
                                             wbf, dec2_b, out_img);
}

// Round 14
// 169.126 us; speedup vs baseline: 1.5421x; 1.1131x over previous
//
#include <hip/hip_runtime.h>
#include <hip/hip_bf16.h>
#include <math.h>

#define NB 16384

typedef __bf16 bf16x8 __attribute__((ext_vector_type(8)));
typedef __fp16 f16x8  __attribute__((ext_vector_type(8)));
typedef float  f32x4  __attribute__((ext_vector_type(4)));
typedef unsigned short ushort4v __attribute__((ext_vector_type(4)));
typedef unsigned int   uint4v  __attribute__((ext_vector_type(4)));

__device__ __forceinline__ float selu_f(float x) {
    const float kScale = 1.0507009873554805f;
    const float kAlphaScale = 1.7580993408473766f;   // scale*alpha
    return x > 0.0f ? kScale * x : kAlphaScale * (__expf(x) - 1.0f);
}

__device__ __forceinline__ unsigned short f2bf(float x) {   // RNE
    unsigned int u = __float_as_uint(x);
    unsigned int r = (u + 0x7FFFu + ((u >> 16) & 1u)) >> 16;
    return (unsigned short)r;
}

// split v into fp16 hi + fp16 lo, packed into one u32 (lo16=hi, hi16=lo)
__device__ __forceinline__ unsigned int packsplit(float v) {
    const __fp16 h = (__fp16)v;
    const __fp16 l = (__fp16)(v - (float)h);
    const unsigned int hb = (unsigned int)__builtin_bit_cast(unsigned short, h);
    const unsigned int lb = (unsigned int)__builtin_bit_cast(unsigned short, l);
    return hb | (lb << 16);
}

// extract packed pairs: AH u32 = hi fp16s, AL u32 = lo fp16s
#define PERM_AH 0x05040100u
#define PERM_AL 0x07060302u

union F16x8Cast { uint4v u; f16x8 f; };

#define CH1 145          // x1 channel stride (u32)
#define X1SZ (CH1 * 10)  // 1450 u32 per image
#define IMS 37           // sImgP row stride
#define IMSZ 1064        // per image

// ---------------------------------------------------------------------------
// K-permutations for pairwise (ds_read2-mergeable) A-gathers (r13, proven).
// ---------------------------------------------------------------------------
__device__ __forceinline__ int c2_elem(int s, int g, int j) {
    const int o = s * 4 + g, jp = j >> 1, hl = j & 1;
    if (jp < 3) {
        const int p = o * 3 + jp;
        int ch, idx;
        if (p < 60) { ch = p / 10; idx = p - ch * 10; }
        else        { ch = 6 + (p - 60) / 9; idx = (p - 60) % 9; }
        int tap;
        if (ch < 6)        tap = 5 * (idx >> 1) + 2 * (idx & 1);
        else if (idx == 0) tap = 0;
        else { const int r = ((idx - 1) >> 1) + 1; tap = 5 * r + 2 * ((idx - 1) & 1); }
        return ch * 25 + tap + hl;
    } else {
        const int q = o;
        if (q >= 29) return -1;
        int chp, tap;
        if (q < 15) { chp = q / 5; const int ts = q - chp * 5; tap = 5 * ts + 4; }
        else { const int q2 = q - 15; chp = 3 + q2 / 7; const int ts = q2 % 7;
               tap = (ts < 2) ? (2 + ts) : (5 * (ts - 2) + 4); }
        return (2 * chp + hl) * 25 + tap;
    }
}
__device__ __forceinline__ int c1_elem(int g, int j) {
    const int p = g * 4 + (j >> 1), hl = j & 1;
    if (p < 10) return 5 * (p >> 1) + 2 * (p & 1) + hl;
    if (p < 15) return hl ? -1 : (5 * (p - 10) + 4);
    return -1;
}

// ---------------------------------------------------------------------------
// Kernel P (prep): builds all weight-derived tables in ws. (r13, unchanged)
// ---------------------------------------------------------------------------
__global__ __launch_bounds__(256) void k_prep(
    const float* __restrict__ dec2_w,  unsigned short* __restrict__ wbf,
    const float* __restrict__ lin1_w,  float* __restrict__ lin1_wp,
    const float* __restrict__ conv2_w, unsigned short* __restrict__ woff4,
    __fp16* __restrict__ whi, __fp16* __restrict__ wlo,
    const float* __restrict__ conv1_w, unsigned short* __restrict__ koff4,
    __fp16* __restrict__ whi1, __fp16* __restrict__ wlo1)
{
    int i = blockIdx.x * 256 + threadIdx.x;
    if (i < 125440) { wbf[i] = f2bf(dec2_w[i]); return; }
    i -= 125440;
    if (i < 16000) {                       // lin1 permute
        const int row = i / 320, cn = i - row * 320;
        const int q = cn / 20, oc = cn - q * 20;
        lin1_wp[row * 320 + cn] = lin1_w[row * 320 + oc * 16 + q];
        return;
    }
    i -= 16000;
    if (i < 128) {                         // conv2 pair-base offsets
        const int s = i >> 4, g = (i >> 2) & 3, jp = i & 3;
        const int e = c2_elem(s, g, jp * 2);
        unsigned short off = 0;
        if (e >= 0) {
            const int ic = e / 25, tap = e - ic * 25;
            off = (unsigned short)(ic * CH1 + (tap / 5) * 12 + tap % 5);
        }
        woff4[i] = off;
        return;
    }
    i -= 128;
    if (i < 16384) {                       // conv2 weight split tables
        const int v = i >> 13;             // 0 = hi, 1 = lo
        const int r = i & 8191;
        const int j = r & 7, lane = (r >> 3) & 63, s = (r >> 9) & 7, nt = r >> 12;
        const int oc = nt * 16 + (lane & 15);
        const int e = c2_elem(s, lane >> 4, j);
        float w = 0.f;
        if (e >= 0 && oc < 20) {
            const int ic = e / 25, tap = e - ic * 25;
            w = conv2_w[(oc * 10 + ic) * 25 + tap];
        }
        const __fp16 hi = (__fp16)w;
        if (v == 0) whi[r] = hi;
        else        wlo[r] = (__fp16)(w - (float)hi);
        return;
    }
    i -= 16384;
    if (i < 16) {                          // conv1 pair-base offsets
        const int e = c1_elem(i >> 2, (i & 3) * 2);
        koff4[i] = (unsigned short)(e < 0 ? 0 : (e / 5) * IMS + e % 5);
        return;
    }
    i -= 16;
    if (i < 1024) {                        // conv1 weight split tables
        const int v = i >> 9;
        const int r = i & 511;
        const int j = r & 7, lane = r >> 3;
        const int c = lane & 15, g = lane >> 4;
        const int e = c1_elem(g, j);
        const float w = (e >= 0 && c < 10) ? conv1_w[c * 25 + e] : 0.f;
        const __fp16 hi = (__fp16)w;
        if (v == 0) whi1[r] = hi;
        else        wlo1[r] = (__fp16)(w - (float)hi);
    }
}

// ---------------------------------------------------------------------------
// Kernel A (r13 body + setprio around MFMA clusters + float4 phase-0 loads).
// Lessons pinned: (256,4) only (r4), unroll-1 outer + small live sets (r6),
// no conv2 K-padding (r9), phase-1 patches from LDS not global (r11).
// Waves are independent (no barrier after phase 0's) -> setprio is in the
// m191 "independent waves" regime where it measured +4-7%.
// ---------------------------------------------------------------------------
__global__ __launch_bounds__(256, 4) void k_conv_fused(
    const float* __restrict__ images,
    const float* __restrict__ conv1_b, const float* __restrict__ conv2_b,
    const unsigned short* __restrict__ woff4,
    const __fp16* __restrict__ whi,  const __fp16* __restrict__ wlo,
    const unsigned short* __restrict__ koff4,
    const __fp16* __restrict__ whi1, const __fp16* __restrict__ wlo1,
    float* __restrict__ x2)
{
    __shared__ unsigned int sImgP[4 * IMSZ];   // 17.0 KB
    __shared__ unsigned int sX1P[4 * X1SZ];    // 23.2 KB

    const int t  = threadIdx.x;
    const int b0 = blockIdx.x * 4;

    // ---- phase 0: images -> split-packed LDS (float4 loads; 28 = 7x4) ----
    for (int k = t; k < 4 * 196; k += 256) {
        const int img = k / 196;
        const int r4  = k - img * 196;
        const int row = r4 / 7;
        const int col = (r4 - row * 7) * 4;
        const float4 v = reinterpret_cast<const float4*>(
                             images + (size_t)(b0 + img) * 784)[r4];
        unsigned int* d = sImgP + img * IMSZ + row * IMS + col;
        d[0] = packsplit(v.x); d[1] = packsplit(v.y);
        d[2] = packsplit(v.z); d[3] = packsplit(v.w);
    }
    // zero col 28 (read by dummy pair-partners of col-4 taps; must be finite)
    for (int i = t; i < 112; i += 256) {
        const int img = i / 28, row = i - img * 28;
        sImgP[img * IMSZ + row * IMS + 28] = 0u;
    }
    __syncthreads();

    const int lane = t & 63;
    const int wv   = t >> 6;
    const int g    = lane >> 4;          // k-group
    const int c0   = lane & 15;          // A-row (phase1/2) / D-col

    // ---- phase 1: conv1 via MFMA -> sX1P[wv][c*CH1 + q] ----
    {
        const unsigned int* imgP = sImgP + wv * IMSZ;
        unsigned int* x1P = sX1P + wv * X1SZ;

        const int sub = c0 & 3, qq = c0 >> 2;
        const int base_lane = (sub >> 1) * IMS + 2 * qq + (sub & 1);
        const ushort4v k4 = *reinterpret_cast<const ushort4v*>(koff4 + g * 4);
        int ab[4];
        #pragma unroll
        for (int jp = 0; jp < 4; ++jp) ab[jp] = base_lane + (int)k4[jp];

        const f16x8 bh1 = *reinterpret_cast<const f16x8*>(whi1 + lane * 8);
        const f16x8 bl1 = *reinterpret_cast<const f16x8*>(wlo1 + lane * 8);
        const float bias = (c0 < 10) ? conv1_b[c0] : 0.f;

        #pragma unroll 1
        for (int a = 0; a < 12; ++a) {
            const int abase = a * (2 * IMS);
            #pragma unroll
            for (int b = 0; b < 3; ++b) {
                const unsigned int* pb_ = imgP + abase + b * 8;
                unsigned int w[8];
                const unsigned int* r0 = pb_ + ab[0]; w[0] = r0[0]; w[1] = r0[1];
                const unsigned int* r1 = pb_ + ab[1]; w[2] = r1[0]; w[3] = r1[1];
                const unsigned int* r2 = pb_ + ab[2]; w[4] = r2[0]; w[5] = r2[1];
                const unsigned int* r3 = pb_ + ab[3]; w[6] = r3[0]; w[7] = r3[1];
                F16x8Cast AH, AL;
                AH.u = (uint4v){ __builtin_amdgcn_perm(w[1], w[0], PERM_AH),
                                 __builtin_amdgcn_perm(w[3], w[2], PERM_AH),
                                 __builtin_amdgcn_perm(w[5], w[4], PERM_AH),
                                 __builtin_amdgcn_perm(w[7], w[6], PERM_AH) };
                AL.u = (uint4v){ __builtin_amdgcn_perm(w[1], w[0], PERM_AL),
                                 __builtin_amdgcn_perm(w[3], w[2], PERM_AL),
                                 __builtin_amdgcn_perm(w[5], w[4], PERM_AL),
                                 __builtin_amdgcn_perm(w[7], w[6], PERM_AL) };
                f32x4 acc = {0.f, 0.f, 0.f, 0.f};
                __builtin_amdgcn_s_setprio(1);
                acc = __builtin_amdgcn_mfma_f32_16x16x32_f16(AH.f, bh1, acc, 0, 0, 0);
                acc = __builtin_amdgcn_mfma_f32_16x16x32_f16(AL.f, bh1, acc, 0, 0, 0);
                acc = __builtin_amdgcn_mfma_f32_16x16x32_f16(AH.f, bl1, acc, 0, 0, 0);
                __builtin_amdgcn_s_setprio(0);
                const float m = fmaxf(fmaxf(acc[0], acc[1]), fmaxf(acc[2], acc[3]));
                if (c0 < 10)
                    x1P[c0 * CH1 + 12 * a + 4 * b + g] = packsplit(selu_f(m + bias));
            }
        }
    }
    __syncthreads();

    // ---- phase 2: conv2 via MFMA (perm extraction, paired gathers) ----
    {
        const unsigned int* x1P = sX1P + wv * X1SZ;

        int rowbase[4];
        #pragma unroll
        for (int mi = 0; mi < 4; ++mi) {
            const int r64 = mi * 16 + c0;
            const int qi  = r64 >> 2;
            const int sb  = r64 & 3;
            rowbase[mi] = (2 * (qi >> 2) + (sb >> 1)) * 12
                        + 2 * (qi & 3) + (sb & 1);
        }

        f32x4 acc[4][2];
        #pragma unroll
        for (int mi = 0; mi < 4; ++mi) {
            acc[mi][0] = (f32x4){0.f, 0.f, 0.f, 0.f};
            acc[mi][1] = (f32x4){0.f, 0.f, 0.f, 0.f};
        }

        // double-buffered per-s data (named regs; no runtime indexing)
        ushort4v of = *reinterpret_cast<const ushort4v*>(woff4 + g * 4);
        f16x8 bh0 = *reinterpret_cast<const f16x8*>(whi + (size_t)(0 * 64 + lane) * 8);
        f16x8 bl0 = *reinterpret_cast<const f16x8*>(wlo + (size_t)(0 * 64 + lane) * 8);
        f16x8 bh1 = *reinterpret_cast<const f16x8*>(whi + (size_t)(8 * 64 + lane) * 8);
        f16x8 bl1 = *reinterpret_cast<const f16x8*>(wlo + (size_t)(8 * 64 + lane) * 8);

        #pragma unroll 1
        for (int s = 0; s < 8; ++s) {
            const int sn = (s + 1) & 7;    // wraps harmlessly at s=7
            const ushort4v ofn = *reinterpret_cast<const ushort4v*>(woff4 + sn * 16 + g * 4);
            const f16x8 nbh0 = *reinterpret_cast<const f16x8*>(whi + (size_t)((0 + sn) * 64 + lane) * 8);
            const f16x8 nbl0 = *reinterpret_cast<const f16x8*>(wlo + (size_t)((0 + sn) * 64 + lane) * 8);
            const f16x8 nbh1 = *reinterpret_cast<const f16x8*>(whi + (size_t)((8 + sn) * 64 + lane) * 8);
            const f16x8 nbl1 = *reinterpret_cast<const f16x8*>(wlo + (size_t)((8 + sn) * 64 + lane) * 8);

            #pragma unroll
            for (int mi = 0; mi < 4; ++mi) {
                const unsigned int* pp = x1P + rowbase[mi];
                unsigned int w[8];
                const unsigned int* q0 = pp + (int)of[0]; w[0] = q0[0]; w[1] = q0[1];
                const unsigned int* q1 = pp + (int)of[1]; w[2] = q1[0]; w[3] = q1[1];
                const unsigned int* q2 = pp + (int)of[2]; w[4] = q2[0]; w[5] = q2[1];
                const unsigned int* q3 = pp + (int)of[3]; w[6] = q3[0]; w[7] = q3[145];
                F16x8Cast AH, AL;
                AH.u = (uint4v){ __builtin_amdgcn_perm(w[1], w[0], PERM_AH),
                                 __builtin_amdgcn_perm(w[3], w[2], PERM_AH),
                                 __builtin_amdgcn_perm(w[5], w[4], PERM_AH),
                                 __builtin_amdgcn_perm(w[7], w[6], PERM_AH) };
                AL.u = (uint4v){ __builtin_amdgcn_perm(w[1], w[0], PERM_AL),
                                 __builtin_amdgcn_perm(w[3], w[2], PERM_AL),
                                 __builtin_amdgcn_perm(w[5], w[4], PERM_AL),
                                 __builtin_amdgcn_perm(w[7], w[6], PERM_AL) };
                __builtin_amdgcn_s_setprio(1);
                acc[mi][0] = __builtin_amdgcn_mfma_f32_16x16x32_f16(AH.f, bh0, acc[mi][0], 0, 0, 0);
                acc[mi][0] = __builtin_amdgcn_mfma_f32_16x16x32_f16(AL.f, bh0, acc[mi][0], 0, 0, 0);
                acc[mi][0] = __builtin_amdgcn_mfma_f32_16x16x32_f16(AH.f, bl0, acc[mi][0], 0, 0, 0);
                acc[mi][1] = __builtin_amdgcn_mfma_f32_16x16x32_f16(AH.f, bh1, acc[mi][1], 0, 0, 0);
                acc[mi][1] = __builtin_amdgcn_mfma_f32_16x16x32_f16(AL.f, bh1, acc[mi][1], 0, 0, 0);
                acc[mi][1] = __builtin_amdgcn_mfma_f32_16x16x32_f16(AH.f, bl1, acc[mi][1], 0, 0, 0);
                __builtin_amdgcn_s_setprio(0);
            }
            of = ofn; bh0 = nbh0; bl0 = nbl0; bh1 = nbh1; bl1 = nbl1;
        }

        // epilogue: the 4 D-regs are one pool quad; qq = pooled pos
        const float bias0 = conv2_b[c0];
        const float bias1 = (c0 < 4) ? conv2_b[16 + c0] : 0.f;
        #pragma unroll
        for (int mi = 0; mi < 4; ++mi) {
            const int qq = mi * 4 + g;
            float* orow = x2 + (size_t)(b0 + wv) * 320 + qq * 20;
            const float v0 = fmaxf(fmaxf(acc[mi][0][0], acc[mi][0][1]),
                                   fmaxf(acc[mi][0][2], acc[mi][0][3]));
            orow[c0] = selu_f(v0 + bias0);
            if (c0 < 4) {
                const float v1 = fmaxf(fmaxf(acc[mi][1][0], acc[mi][1][1]),
                                       fmaxf(acc[mi][1][2], acc[mi][1][3]));
                orow[16 + c0] = selu_f(v1 + bias1);
            }
        }
    }
}

// ---------------------------------------------------------------------------
// Kernel T (tail, fused): lin1+selu -> lin2 -> code, fp32-Jacobi SVD
// projector (t<32, code rows in LDS) -> proj in LDS -> dec1+selu (bf16 h in
// LDS, overlaid on sIn) -> dec2 via MFMA + sigmoid -> out.
// Removes one launch + the proj global round-trip (was k_lin12_svd+k_decoder).
// ---------------------------------------------------------------------------
#define HS 168   // padded h row stride in ushorts

__global__ __launch_bounds__(256) void k_tail(
    const float* __restrict__ x2,
    const float* __restrict__ lin1_wp, const float* __restrict__ lin1_b,
    const float* __restrict__ lin2_w,  const float* __restrict__ lin2_b,
    const float* __restrict__ dec1_w,  const float* __restrict__ dec1_b,
    const unsigned short* __restrict__ dec2_wb, const float* __restrict__ dec2_b,
    float* __restrict__ code, float* __restrict__ out)
{
    __shared__ float sIn[32][324];   // 41.5 KB; reused as sHd (bf16 h) later
    __shared__ float sH[32][51];
    __shared__ float sC[32][28];
    __shared__ float sP[32][26];     // proj (SVD output)
    unsigned short* sHd = reinterpret_cast<unsigned short*>(&sIn[0][0]);

    const int t  = threadIdx.x;
    const int b0 = blockIdx.x * 32;

    {   // float4-vectorized x2 staging
        const float* g = x2 + (size_t)b0 * 320;
        for (int k = t; k < 2560; k += 256) {
            const int r  = k / 80;
            const int c4 = k - r * 80;
            reinterpret_cast<float4*>(&sIn[r][0])[c4] =
                reinterpret_cast<const float4*>(g + r * 320)[c4];
        }
    }
    __syncthreads();

    for (int idx = t; idx < 1600; idx += 256) {        // lin1: 32 x 50
        const int bi = idx & 31;
        const int j  = idx >> 5;
        float s = lin1_b[j];
        const float4* w  = reinterpret_cast<const float4*>(lin1_wp + j * 320);
        const float4* xi = reinterpret_cast<const float4*>(&sIn[bi][0]);
        #pragma unroll 4
        for (int k4 = 0; k4 < 80; ++k4) {
            const float4 a = xi[k4];
            const float4 wq = w[k4];
            s = fmaf(a.x, wq.x, s); s = fmaf(a.y, wq.y, s);
            s = fmaf(a.z, wq.z, s); s = fmaf(a.w, wq.w, s);
        }
        sH[bi][j] = selu_f(s);
    }
    __syncthreads();
    for (int idx = t; idx < 800; idx += 256) {         // lin2: 32 x 25
        const int bi = idx & 31;
        const int j  = idx >> 5;
        float s = lin2_b[j];
        const float* w = lin2_w + j * 50;
        #pragma unroll
        for (int k = 0; k < 50; ++k) s = fmaf(sH[bi][k], w[k], s);
        code[(size_t)(b0 + bi) * 25 + j] = s;
        sC[bi][j] = s;
    }
    __syncthreads();

    // ---- fp32 Jacobi SVD projector: thread t<32 handles sample b0+t ----
    if (t < 32) {
        float M[5][5];
        #pragma unroll
        for (int i = 0; i < 5; ++i)
            #pragma unroll
            for (int j = 0; j < 5; ++j) M[i][j] = sC[t][i * 5 + j];

        float A[5][5], V[5][5];
        #pragma unroll
        for (int i = 0; i < 5; ++i) {
            #pragma unroll
            for (int j = 0; j < 5; ++j) {
                float s = 0.f;
                #pragma unroll
                for (int k = 0; k < 5; ++k) s = fmaf(M[i][k], M[j][k], s);
                A[i][j] = s;
                V[i][j] = (i == j) ? 1.f : 0.f;
            }
        }
        for (int sweep = 0; sweep < 6; ++sweep) {
            #pragma unroll
            for (int p = 0; p < 4; ++p) {
                #pragma unroll
                for (int q = p + 1; q < 5; ++q) {
                    const float apq = A[p][q];
                    if (fabsf(apq) > 1e-30f) {
                        const float app = A[p][p], aqq = A[q][q];
                        const float tau = (aqq - app) / (2.f * apq);
                        const float tt  = (tau >= 0.f ? 1.f : -1.f) /
                                          (fabsf(tau) + sqrtf(1.f + tau * tau));
                        const float cc  = 1.f / sqrtf(1.f + tt * tt);
                        const float ss  = tt * cc;
                        #pragma unroll
                        for (int i = 0; i < 5; ++i) {
                            if (i == p || i == q) continue;
                            const float aip = A[i][p], aiq = A[i][q];
                            A[i][p] = A[p][i] = cc * aip - ss * aiq;
                            A[i][q] = A[q][i] = ss * aip + cc * aiq;
                        }
                        A[p][p] = app - tt * apq;
                        A[q][q] = aqq + tt * apq;
                        A[p][q] = A[q][p] = 0.f;
                        #pragma unroll
                        for (int i = 0; i < 5; ++i) {
                            const float vip = V[i][p], viq = V[i][q];
                            V[i][p] = cc * vip - ss * viq;
                            V[i][q] = ss * vip + cc * viq;
                        }
                    }
                }
            }
        }
        float d[5];
        #pragma unroll
        for (int i = 0; i < 5; ++i) d[i] = A[i][i];
        float sel[5];
        #pragma unroll
        for (int c1 = 0; c1 < 5; ++c1) {
            int cnt = 0;
            #pragma unroll
            for (int c2 = 0; c2 < 5; ++c2) {
                if (c2 == c1) continue;
                if (d[c2] > d[c1] || (d[c2] == d[c1] && c2 < c1)) ++cnt;
            }
            sel[c1] = (cnt < 2) ? 1.f : 0.f;
        }
        #pragma unroll
        for (int i = 0; i < 5; ++i) {
            #pragma unroll
            for (int j = 0; j < 5; ++j) {
                float s = 0.f;
                #pragma unroll
                for (int k = 0; k < 5; ++k) s = fmaf(sel[k] * V[i][k], V[j][k], s);
                sP[t][i * 5 + j] = s;
            }
        }
    }
    __syncthreads();

    // ---- dec1: h[bi][j] = selu(sP row @ dec1_w) -> sHd (overlays sIn) ----
    const int bi = t & 31;
    const int j0 = t >> 5;
    {
        float p[25];
        #pragma unroll
        for (int k = 0; k < 25; ++k) p[k] = sP[bi][k];
        #pragma unroll 4
        for (int i = 0; i < 20; ++i) {
            const int j = j0 + i * 8;
            const float* w = dec1_w + j * 25;
            float s = dec1_b[j];
            #pragma unroll
            for (int k = 0; k < 25; ++k) s = fmaf(p[k], w[k], s);
            sHd[bi * HS + j] = f2bf(selu_f(s));
        }
    }
    __syncthreads();

    // ---- dec2: out[32][784] = sigmoid(h @ W^T + b) via MFMA ----
    const int wv   = t >> 6;      // 0..3
    const int lane = t & 63;
    const int arow = lane & 15;   // A row / B col within tile
    const int kgrp = lane >> 4;   // 0..3

    bf16x8 afr[2][5];             // hoisted A fragments: 2 row-tiles x 5 k-steps
    #pragma unroll
    for (int rt = 0; rt < 2; ++rt)
        #pragma unroll
        for (int ks = 0; ks < 5; ++ks)
            afr[rt][ks] = *reinterpret_cast<const bf16x8*>(
                &sHd[(rt * 16 + arow) * HS + ks * 32 + kgrp * 8]);

    for (int ct = wv; ct < 49; ct += 4) {
        const int col = ct * 16 + arow;
        bf16x8 bfr[5];
        const unsigned short* wp = dec2_wb + (size_t)col * 160 + kgrp * 8;
        #pragma unroll
        for (int ks = 0; ks < 5; ++ks)
            bfr[ks] = *reinterpret_cast<const bf16x8*>(wp + ks * 32);

        f32x4 acc0 = {0.f, 0.f, 0.f, 0.f};
        f32x4 acc1 = {0.f, 0.f, 0.f, 0.f};
        #pragma unroll
        for (int ks = 0; ks < 5; ++ks) {
            acc0 = __builtin_amdgcn_mfma_f32_16x16x32_bf16(afr[0][ks], bfr[ks], acc0, 0, 0, 0);
            acc1 = __builtin_amdgcn_mfma_f32_16x16x32_bf16(afr[1][ks], bfr[ks], acc1, 0, 0, 0);
        }
        const float bb = dec2_b[col];
        #pragma unroll
        for (int r = 0; r < 4; ++r) {
            const int row = kgrp * 4 + r;          // D: row=(lane>>4)*4+reg
            const float v0 = acc0[r] + bb;
            const float v1 = acc1[r] + bb;
            out[(size_t)(b0 + row) * 784 + col]      = 1.0f / (1.0f + __expf(-v0));
            out[(size_t)(b0 + 16 + row) * 784 + col] = 1.0f / (1.0f + __expf(-v1));
        }
    }
}

// ---------------------------------------------------------------------------
extern "C" void kernel_launch(void* const* d_in, const int* in_sizes, int n_in,
                              void* d_out, int out_size, void* d_ws, size_t ws_size,
                              hipStream_t stream) {
    const float* images  = (const float*)d_in[0];
    const float* conv1_w = (const float*)d_in[1];
    const float* conv1_b = (const float*)d_in[2];
    const float* conv2_w = (const float*)d_in[3];
    const float* conv2_b = (const float*)d_in[4];
    const float* lin1_w  = (const float*)d_in[5];
    const float* lin1_b  = (const float*)d_in[6];
    const float* lin2_w  = (const float*)d_in[7];
    const float* lin2_b  = (const float*)d_in[8];
    const float* dec1_w  = (const float*)d_in[9];
    const float* dec1_b  = (const float*)d_in[10];
    const float* dec2_w  = (const float*)d_in[11];
    const float* dec2_b  = (const float*)d_in[12];

    float* out_img = (float*)d_out;                    // NB*784 fp32
    float* code    = (float*)d_out + (size_t)NB * 784; // NB*25  fp32

    // workspace layout (bytes, all 16-aligned):
    char* ws = (char*)d_ws;
    float*          x2      = (float*)ws;                                  // NB*320 f
    unsigned short* wbf     = (unsigned short*)(ws + (size_t)NB * 345 * 4);// 125440 us
    char*           pB      = ws + (size_t)NB * 345 * 4 + 250880;
    float*          lin1_wp = (float*)pB;                                  // 16000 f
    unsigned short* woff4   = (unsigned short*)(pB + 64000);               // 128 us
    __fp16*         whi     = (__fp16*)(pB + 64512);                       // 8192 h
    __fp16*         wlo     = (__fp16*)(pB + 80896);                       // 8192 h
    unsigned short* koff4   = (unsigned short*)(pB + 97280);               // 16 us
    __fp16*         whi1    = (__fp16*)(pB + 97344);                       // 512 h
    __fp16*         wlo1    = (__fp16*)(pB + 98368);                       // 512 h

    k_prep     <<<622,      256, 0, stream>>>(dec2_w, wbf, lin1_w, lin1_wp,
                                              conv2_w, woff4, whi, wlo,
                                              conv1_w, koff4, whi1, wlo1);
    k_conv_fused<<<NB / 4,  256, 0, stream>>>(images, conv1_b, conv2_b,
                                              woff4, whi, wlo,
                                              koff4, whi1, wlo1, x2);
    k_tail     <<<NB / 32, 256, 0, stream>>>(x2, lin1_wp, lin1_b,
                                             lin2_w, lin2_b,
                                             dec1_w, dec1_b,
                                             wbf, dec2_b,
                                             code, out_img);
}

// Round 15
// 166.743 us; speedup vs baseline: 1.5641x; 1.0143x over previous
//
#include <hip/hip_runtime.h>
#include <hip/hip_bf16.h>
#include <math.h>

#define NB 16384

typedef __bf16 bf16x8 __attribute__((ext_vector_type(8)));
typedef __fp16 f16x8  __attribute__((ext_vector_type(8)));
typedef float  f32x4  __attribute__((ext_vector_type(4)));
typedef unsigned short ushort4v __attribute__((ext_vector_type(4)));
typedef unsigned int   uint4v  __attribute__((ext_vector_type(4)));

__device__ __forceinline__ float selu_f(float x) {
    const float kScale = 1.0507009873554805f;
    const float kAlphaScale = 1.7580993408473766f;   // scale*alpha
    return x > 0.0f ? kScale * x : kAlphaScale * (__expf(x) - 1.0f);
}

__device__ __forceinline__ unsigned short f2bf(float x) {   // RNE
    unsigned int u = __float_as_uint(x);
    unsigned int r = (u + 0x7FFFu + ((u >> 16) & 1u)) >> 16;
    return (unsigned short)r;
}

// split v into fp16 hi + fp16 lo, packed into one u32 (lo16=hi, hi16=lo)
__device__ __forceinline__ unsigned int packsplit(float v) {
    const __fp16 h = (__fp16)v;
    const __fp16 l = (__fp16)(v - (float)h);
    const unsigned int hb = (unsigned int)__builtin_bit_cast(unsigned short, h);
    const unsigned int lb = (unsigned int)__builtin_bit_cast(unsigned short, l);
    return hb | (lb << 16);
}

// extract packed pairs: AH u32 = hi fp16s, AL u32 = lo fp16s
#define PERM_AH 0x05040100u
#define PERM_AL 0x07060302u

union F16x8Cast { uint4v u; f16x8 f; };

#define CH1 145          // x1 channel stride (u32)
#define X1SZ (CH1 * 10)  // 1450 u32 per image
#define IMS 37           // sImgP row stride
#define IMSZ 1064        // per image

// ---------------------------------------------------------------------------
// K-permutations for pairwise (ds_read2-mergeable) A-gathers (r13, proven).
// ---------------------------------------------------------------------------
__device__ __forceinline__ int c2_elem(int s, int g, int j) {
    const int o = s * 4 + g, jp = j >> 1, hl = j & 1;
    if (jp < 3) {
        const int p = o * 3 + jp;
        int ch, idx;
        if (p < 60) { ch = p / 10; idx = p - ch * 10; }
        else        { ch = 6 + (p - 60) / 9; idx = (p - 60) % 9; }
        int tap;
        if (ch < 6)        tap = 5 * (idx >> 1) + 2 * (idx & 1);
        else if (idx == 0) tap = 0;
        else { const int r = ((idx - 1) >> 1) + 1; tap = 5 * r + 2 * ((idx - 1) & 1); }
        return ch * 25 + tap + hl;
    } else {
        const int q = o;
        if (q >= 29) return -1;
        int chp, tap;
        if (q < 15) { chp = q / 5; const int ts = q - chp * 5; tap = 5 * ts + 4; }
        else { const int q2 = q - 15; chp = 3 + q2 / 7; const int ts = q2 % 7;
               tap = (ts < 2) ? (2 + ts) : (5 * (ts - 2) + 4); }
        return (2 * chp + hl) * 25 + tap;
    }
}
__device__ __forceinline__ int c1_elem(int g, int j) {
    const int p = g * 4 + (j >> 1), hl = j & 1;
    if (p < 10) return 5 * (p >> 1) + 2 * (p & 1) + hl;
    if (p < 15) return hl ? -1 : (5 * (p - 10) + 4);
    return -1;
}

// ---------------------------------------------------------------------------
// Kernel P (prep): builds all weight-derived tables in ws. (r13, unchanged)
// ---------------------------------------------------------------------------
__global__ __launch_bounds__(256) void k_prep(
    const float* __restrict__ dec2_w,  unsigned short* __restrict__ wbf,
    const float* __restrict__ lin1_w,  float* __restrict__ lin1_wp,
    const float* __restrict__ conv2_w, unsigned short* __restrict__ woff4,
    __fp16* __restrict__ whi, __fp16* __restrict__ wlo,
    const float* __restrict__ conv1_w, unsigned short* __restrict__ koff4,
    __fp16* __restrict__ whi1, __fp16* __restrict__ wlo1)
{
    int i = blockIdx.x * 256 + threadIdx.x;
    if (i < 125440) { wbf[i] = f2bf(dec2_w[i]); return; }
    i -= 125440;
    if (i < 16000) {                       // lin1 permute
        const int row = i / 320, cn = i - row * 320;
        const int q = cn / 20, oc = cn - q * 20;
        lin1_wp[row * 320 + cn] = lin1_w[row * 320 + oc * 16 + q];
        return;
    }
    i -= 16000;
    if (i < 128) {                         // conv2 pair-base offsets
        const int s = i >> 4, g = (i >> 2) & 3, jp = i & 3;
        const int e = c2_elem(s, g, jp * 2);
        unsigned short off = 0;
        if (e >= 0) {
            const int ic = e / 25, tap = e - ic * 25;
            off = (unsigned short)(ic * CH1 + (tap / 5) * 12 + tap % 5);
        }
        woff4[i] = off;
        return;
    }
    i -= 128;
    if (i < 16384) {                       // conv2 weight split tables
        const int v = i >> 13;             // 0 = hi, 1 = lo
        const int r = i & 8191;
        const int j = r & 7, lane = (r >> 3) & 63, s = (r >> 9) & 7, nt = r >> 12;
        const int oc = nt * 16 + (lane & 15);
        const int e = c2_elem(s, lane >> 4, j);
        float w = 0.f;
        if (e >= 0 && oc < 20) {
            const int ic = e / 25, tap = e - ic * 25;
            w = conv2_w[(oc * 10 + ic) * 25 + tap];
        }
        const __fp16 hi = (__fp16)w;
        if (v == 0) whi[r] = hi;
        else        wlo[r] = (__fp16)(w - (float)hi);
        return;
    }
    i -= 16384;
    if (i < 16) {                          // conv1 pair-base offsets
        const int e = c1_elem(i >> 2, (i & 3) * 2);
        koff4[i] = (unsigned short)(e < 0 ? 0 : (e / 5) * IMS + e % 5);
        return;
    }
    i -= 16;
    if (i < 1024) {                        // conv1 weight split tables
        const int v = i >> 9;
        const int r = i & 511;
        const int j = r & 7, lane = r >> 3;
        const int c = lane & 15, g = lane >> 4;
        const int e = c1_elem(g, j);
        const float w = (e >= 0 && c < 10) ? conv1_w[c * 25 + e] : 0.f;
        const __fp16 hi = (__fp16)w;
        if (v == 0) whi1[r] = hi;
        else        wlo1[r] = (__fp16)(w - (float)hi);
    }
}

// ---------------------------------------------------------------------------
// Kernel A (r14, byte-identical — proven 97us): conv1+conv2 split-fp16 MFMA
// with setprio MFMA clusters + float4 phase-0. Lessons pinned: (256,4) only
// (r4), unroll-1 outer + small live sets (r6), no conv2 K-padding (r9),
// phase-1 patches from LDS not global (r11).
// ---------------------------------------------------------------------------
__global__ __launch_bounds__(256, 4) void k_conv_fused(
    const float* __restrict__ images,
    const float* __restrict__ conv1_b, const float* __restrict__ conv2_b,
    const unsigned short* __restrict__ woff4,
    const __fp16* __restrict__ whi,  const __fp16* __restrict__ wlo,
    const unsigned short* __restrict__ koff4,
    const __fp16* __restrict__ whi1, const __fp16* __restrict__ wlo1,
    float* __restrict__ x2)
{
    __shared__ unsigned int sImgP[4 * IMSZ];   // 17.0 KB
    __shared__ unsigned int sX1P[4 * X1SZ];    // 23.2 KB

    const int t  = threadIdx.x;
    const int b0 = blockIdx.x * 4;

    // ---- phase 0: images -> split-packed LDS (float4 loads; 28 = 7x4) ----
    for (int k = t; k < 4 * 196; k += 256) {
        const int img = k / 196;
        const int r4  = k - img * 196;
        const int row = r4 / 7;
        const int col = (r4 - row * 7) * 4;
        const float4 v = reinterpret_cast<const float4*>(
                             images + (size_t)(b0 + img) * 784)[r4];
        unsigned int* d = sImgP + img * IMSZ + row * IMS + col;
        d[0] = packsplit(v.x); d[1] = packsplit(v.y);
        d[2] = packsplit(v.z); d[3] = packsplit(v.w);
    }
    // zero col 28 (read by dummy pair-partners of col-4 taps; must be finite)
    for (int i = t; i < 112; i += 256) {
        const int img = i / 28, row = i - img * 28;
        sImgP[img * IMSZ + row * IMS + 28] = 0u;
    }
    __syncthreads();

    const int lane = t & 63;
    const int wv   = t >> 6;
    const int g    = lane >> 4;          // k-group
    const int c0   = lane & 15;          // A-row (phase1/2) / D-col

    // ---- phase 1: conv1 via MFMA -> sX1P[wv][c*CH1 + q] ----
    {
        const unsigned int* imgP = sImgP + wv * IMSZ;
        unsigned int* x1P = sX1P + wv * X1SZ;

        const int sub = c0 & 3, qq = c0 >> 2;
        const int base_lane = (sub >> 1) * IMS + 2 * qq + (sub & 1);
        const ushort4v k4 = *reinterpret_cast<const ushort4v*>(koff4 + g * 4);
        int ab[4];
        #pragma unroll
        for (int jp = 0; jp < 4; ++jp) ab[jp] = base_lane + (int)k4[jp];

        const f16x8 bh1 = *reinterpret_cast<const f16x8*>(whi1 + lane * 8);
        const f16x8 bl1 = *reinterpret_cast<const f16x8*>(wlo1 + lane * 8);
        const float bias = (c0 < 10) ? conv1_b[c0] : 0.f;

        #pragma unroll 1
        for (int a = 0; a < 12; ++a) {
            const int abase = a * (2 * IMS);
            #pragma unroll
            for (int b = 0; b < 3; ++b) {
                const unsigned int* pb_ = imgP + abase + b * 8;
                unsigned int w[8];
                const unsigned int* r0 = pb_ + ab[0]; w[0] = r0[0]; w[1] = r0[1];
                const unsigned int* r1 = pb_ + ab[1]; w[2] = r1[0]; w[3] = r1[1];
                const unsigned int* r2 = pb_ + ab[2]; w[4] = r2[0]; w[5] = r2[1];
                const unsigned int* r3 = pb_ + ab[3]; w[6] = r3[0]; w[7] = r3[1];
                F16x8Cast AH, AL;
                AH.u = (uint4v){ __builtin_amdgcn_perm(w[1], w[0], PERM_AH),
                                 __builtin_amdgcn_perm(w[3], w[2], PERM_AH),
                                 __builtin_amdgcn_perm(w[5], w[4], PERM_AH),
                                 __builtin_amdgcn_perm(w[7], w[6], PERM_AH) };
                AL.u = (uint4v){ __builtin_amdgcn_perm(w[1], w[0], PERM_AL),
                                 __builtin_amdgcn_perm(w[3], w[2], PERM_AL),
                                 __builtin_amdgcn_perm(w[5], w[4], PERM_AL),
                                 __builtin_amdgcn_perm(w[7], w[6], PERM_AL) };
                f32x4 acc = {0.f, 0.f, 0.f, 0.f};
                __builtin_amdgcn_s_setprio(1);
                acc = __builtin_amdgcn_mfma_f32_16x16x32_f16(AH.f, bh1, acc, 0, 0, 0);
                acc = __builtin_amdgcn_mfma_f32_16x16x32_f16(AL.f, bh1, acc, 0, 0, 0);
                acc = __builtin_amdgcn_mfma_f32_16x16x32_f16(AH.f, bl1, acc, 0, 0, 0);
                __builtin_amdgcn_s_setprio(0);
                const float m = fmaxf(fmaxf(acc[0], acc[1]), fmaxf(acc[2], acc[3]));
                if (c0 < 10)
                    x1P[c0 * CH1 + 12 * a + 4 * b + g] = packsplit(selu_f(m + bias));
            }
        }
    }
    __syncthreads();

    // ---- phase 2: conv2 via MFMA (perm extraction, paired gathers) ----
    {
        const unsigned int* x1P = sX1P + wv * X1SZ;

        int rowbase[4];
        #pragma unroll
        for (int mi = 0; mi < 4; ++mi) {
            const int r64 = mi * 16 + c0;
            const int qi  = r64 >> 2;
            const int sb  = r64 & 3;
            rowbase[mi] = (2 * (qi >> 2) + (sb >> 1)) * 12
                        + 2 * (qi & 3) + (sb & 1);
        }

        f32x4 acc[4][2];
        #pragma unroll
        for (int mi = 0; mi < 4; ++mi) {
            acc[mi][0] = (f32x4){0.f, 0.f, 0.f, 0.f};
            acc[mi][1] = (f32x4){0.f, 0.f, 0.f, 0.f};
        }

        // double-buffered per-s data (named regs; no runtime indexing)
        ushort4v of = *reinterpret_cast<const ushort4v*>(woff4 + g * 4);
        f16x8 bh0 = *reinterpret_cast<const f16x8*>(whi + (size_t)(0 * 64 + lane) * 8);
        f16x8 bl0 = *reinterpret_cast<const f16x8*>(wlo + (size_t)(0 * 64 + lane) * 8);
        f16x8 bh1 = *reinterpret_cast<const f16x8*>(whi + (size_t)(8 * 64 + lane) * 8);
        f16x8 bl1 = *reinterpret_cast<const f16x8*>(wlo + (size_t)(8 * 64 + lane) * 8);

        #pragma unroll 1
        for (int s = 0; s < 8; ++s) {
            const int sn = (s + 1) & 7;    // wraps harmlessly at s=7
            const ushort4v ofn = *reinterpret_cast<const ushort4v*>(woff4 + sn * 16 + g * 4);
            const f16x8 nbh0 = *reinterpret_cast<const f16x8*>(whi + (size_t)((0 + sn) * 64 + lane) * 8);
            const f16x8 nbl0 = *reinterpret_cast<const f16x8*>(wlo + (size_t)((0 + sn) * 64 + lane) * 8);
            const f16x8 nbh1 = *reinterpret_cast<const f16x8*>(whi + (size_t)((8 + sn) * 64 + lane) * 8);
            const f16x8 nbl1 = *reinterpret_cast<const f16x8*>(wlo + (size_t)((8 + sn) * 64 + lane) * 8);

            #pragma unroll
            for (int mi = 0; mi < 4; ++mi) {
                const unsigned int* pp = x1P + rowbase[mi];
                unsigned int w[8];
                const unsigned int* q0 = pp + (int)of[0]; w[0] = q0[0]; w[1] = q0[1];
                const unsigned int* q1 = pp + (int)of[1]; w[2] = q1[0]; w[3] = q1[1];
                const unsigned int* q2 = pp + (int)of[2]; w[4] = q2[0]; w[5] = q2[1];
                const unsigned int* q3 = pp + (int)of[3]; w[6] = q3[0]; w[7] = q3[145];
                F16x8Cast AH, AL;
                AH.u = (uint4v){ __builtin_amdgcn_perm(w[1], w[0], PERM_AH),
                                 __builtin_amdgcn_perm(w[3], w[2], PERM_AH),
                                 __builtin_amdgcn_perm(w[5], w[4], PERM_AH),
                                 __builtin_amdgcn_perm(w[7], w[6], PERM_AH) };
                AL.u = (uint4v){ __builtin_amdgcn_perm(w[1], w[0], PERM_AL),
                                 __builtin_amdgcn_perm(w[3], w[2], PERM_AL),
                                 __builtin_amdgcn_perm(w[5], w[4], PERM_AL),
                                 __builtin_amdgcn_perm(w[7], w[6], PERM_AL) };
                __builtin_amdgcn_s_setprio(1);
                acc[mi][0] = __builtin_amdgcn_mfma_f32_16x16x32_f16(AH.f, bh0, acc[mi][0], 0, 0, 0);
                acc[mi][0] = __builtin_amdgcn_mfma_f32_16x16x32_f16(AL.f, bh0, acc[mi][0], 0, 0, 0);
                acc[mi][0] = __builtin_amdgcn_mfma_f32_16x16x32_f16(AH.f, bl0, acc[mi][0], 0, 0, 0);
                acc[mi][1] = __builtin_amdgcn_mfma_f32_16x16x32_f16(AH.f, bh1, acc[mi][1], 0, 0, 0);
                acc[mi][1] = __builtin_amdgcn_mfma_f32_16x16x32_f16(AL.f, bh1, acc[mi][1], 0, 0, 0);
                acc[mi][1] = __builtin_amdgcn_mfma_f32_16x16x32_f16(AH.f, bl1, acc[mi][1], 0, 0, 0);
                __builtin_amdgcn_s_setprio(0);
            }
            of = ofn; bh0 = nbh0; bl0 = nbl0; bh1 = nbh1; bl1 = nbl1;
        }

        // epilogue: the 4 D-regs are one pool quad; qq = pooled pos
        const float bias0 = conv2_b[c0];
        const float bias1 = (c0 < 4) ? conv2_b[16 + c0] : 0.f;
        #pragma unroll
        for (int mi = 0; mi < 4; ++mi) {
            const int qq = mi * 4 + g;
            float* orow = x2 + (size_t)(b0 + wv) * 320 + qq * 20;
            const float v0 = fmaxf(fmaxf(acc[mi][0][0], acc[mi][0][1]),
                                   fmaxf(acc[mi][0][2], acc[mi][0][3]));
            orow[c0] = selu_f(v0 + bias0);
            if (c0 < 4) {
                const float v1 = fmaxf(fmaxf(acc[mi][1][0], acc[mi][1][1]),
                                       fmaxf(acc[mi][1][2], acc[mi][1][3]));
                orow[16 + c0] = selu_f(v1 + bias1);
            }
        }
    }
}

// ---------------------------------------------------------------------------
// Kernel T (tail): NS=16 samples/block (was 32) -> LDS 27.6KB -> 5 blocks/CU
// (was 2 at 55KB). The tail is a chain of barrier-separated phases (staging,
// lin1, lin2, SVD-serial, dec1, dec2); more resident blocks interleave phases
// across blocks and hide the serial-SVD + barrier latency.
// ---------------------------------------------------------------------------
#define NS 16    // samples per tail block
#define HS 168   // padded h row stride in ushorts

__global__ __launch_bounds__(256) void k_tail(
    const float* __restrict__ x2,
    const float* __restrict__ lin1_wp, const float* __restrict__ lin1_b,
    const float* __restrict__ lin2_w,  const float* __restrict__ lin2_b,
    const float* __restrict__ dec1_w,  const float* __restrict__ dec1_b,
    const unsigned short* __restrict__ dec2_wb, const float* __restrict__ dec2_b,
    float* __restrict__ code, float* __restrict__ out)
{
    __shared__ float sIn[NS][324];   // 20.7 KB; reused as sHd (bf16 h) later
    __shared__ float sH[NS][51];
    __shared__ float sC[NS][28];
    __shared__ float sP[NS][26];     // proj (SVD output)
    unsigned short* sHd = reinterpret_cast<unsigned short*>(&sIn[0][0]);

    const int t  = threadIdx.x;
    const int b0 = blockIdx.x * NS;

    {   // float4-vectorized x2 staging: NS x 80 float4
        const float* g = x2 + (size_t)b0 * 320;
        for (int k = t; k < NS * 80; k += 256) {
            const int r  = k / 80;
            const int c4 = k - r * 80;
            reinterpret_cast<float4*>(&sIn[r][0])[c4] =
                reinterpret_cast<const float4*>(g + r * 320)[c4];
        }
    }
    __syncthreads();

    for (int idx = t; idx < NS * 50; idx += 256) {     // lin1: NS x 50
        const int bi = idx & (NS - 1);
        const int j  = idx / NS;
        float s = lin1_b[j];
        const float4* w  = reinterpret_cast<const float4*>(lin1_wp + j * 320);
        const float4* xi = reinterpret_cast<const float4*>(&sIn[bi][0]);
        #pragma unroll 4
        for (int k4 = 0; k4 < 80; ++k4) {
            const float4 a = xi[k4];
            const float4 wq = w[k4];
            s = fmaf(a.x, wq.x, s); s = fmaf(a.y, wq.y, s);
            s = fmaf(a.z, wq.z, s); s = fmaf(a.w, wq.w, s);
        }
        sH[bi][j] = selu_f(s);
    }
    __syncthreads();
    for (int idx = t; idx < NS * 25; idx += 256) {     // lin2: NS x 25
        const int bi = idx & (NS - 1);
        const int j  = idx / NS;
        float s = lin2_b[j];
        const float* w = lin2_w + j * 50;
        #pragma unroll
        for (int k = 0; k < 50; ++k) s = fmaf(sH[bi][k], w[k], s);
        code[(size_t)(b0 + bi) * 25 + j] = s;
        sC[bi][j] = s;
    }
    __syncthreads();

    // ---- fp32 Jacobi SVD projector: thread t<NS handles sample b0+t ----
    if (t < NS) {
        float M[5][5];
        #pragma unroll
        for (int i = 0; i < 5; ++i)
            #pragma unroll
            for (int j = 0; j < 5; ++j) M[i][j] = sC[t][i * 5 + j];

        float A[5][5], V[5][5];
        #pragma unroll
        for (int i = 0; i < 5; ++i) {
            #pragma unroll
            for (int j = 0; j < 5; ++j) {
                float s = 0.f;
                #pragma unroll
                for (int k = 0; k < 5; ++k) s = fmaf(M[i][k], M[j][k], s);
                A[i][j] = s;
                V[i][j] = (i == j) ? 1.f : 0.f;
            }
        }
        for (int sweep = 0; sweep < 6; ++sweep) {
            #pragma unroll
            for (int p = 0; p < 4; ++p) {
                #pragma unroll
                for (int q = p + 1; q < 5; ++q) {
                    const float apq = A[p][q];
                    if (fabsf(apq) > 1e-30f) {
                        const float app = A[p][p], aqq = A[q][q];
                        const float tau = (aqq - app) / (2.f * apq);
                        const float tt  = (tau >= 0.f ? 1.f : -1.f) /
                                          (fabsf(tau) + sqrtf(1.f + tau * tau));
                        const float cc  = 1.f / sqrtf(1.f + tt * tt);
                        const float ss  = tt * cc;
                        #pragma unroll
                        for (int i = 0; i < 5; ++i) {
                            if (i == p || i == q) continue;
                            const float aip = A[i][p], aiq = A[i][q];
                            A[i][p] = A[p][i] = cc * aip - ss * aiq;
                            A[i][q] = A[q][i] = ss * aip + cc * aiq;
                        }
                        A[p][p] = app - tt * apq;
                        A[q][q] = aqq + tt * apq;
                        A[p][q] = A[q][p] = 0.f;
                        #pragma unroll
                        for (int i = 0; i < 5; ++i) {
                            const float vip = V[i][p], viq = V[i][q];
                            V[i][p] = cc * vip - ss * viq;
                            V[i][q] = ss * vip + cc * viq;
                        }
                    }
                }
            }
        }
        float d[5];
        #pragma unroll
        for (int i = 0; i < 5; ++i) d[i] = A[i][i];
        float sel[5];
        #pragma unroll
        for (int c1 = 0; c1 < 5; ++c1) {
            int cnt = 0;
            #pragma unroll
            for (int c2 = 0; c2 < 5; ++c2) {
                if (c2 == c1) continue;
                if (d[c2] > d[c1] || (d[c2] == d[c1] && c2 < c1)) ++cnt;
            }
            sel[c1] = (cnt < 2) ? 1.f : 0.f;
        }
        #pragma unroll
        for (int i = 0; i < 5; ++i) {
            #pragma unroll
            for (int j = 0; j < 5; ++j) {
                float s = 0.f;
                #pragma unroll
                for (int k = 0; k < 5; ++k) s = fmaf(sel[k] * V[i][k], V[j][k], s);
                sP[t][i * 5 + j] = s;
            }
        }
    }
    __syncthreads();

    // ---- dec1: h[bi][j] = selu(sP row @ dec1_w) -> sHd (overlays sIn) ----
    const int bi = t & (NS - 1);
    const int j0 = t / NS;               // 0..15
    {
        float p[25];
        #pragma unroll
        for (int k = 0; k < 25; ++k) p[k] = sP[bi][k];
        #pragma unroll 2
        for (int i = 0; i < 10; ++i) {   // j = j0 + 16*i covers 0..159
            const int j = j0 + i * 16;
            const float* w = dec1_w + j * 25;
            float s = dec1_b[j];
            #pragma unroll
            for (int k = 0; k < 25; ++k) s = fmaf(p[k], w[k], s);
            sHd[bi * HS + j] = f2bf(selu_f(s));
        }
    }
    __syncthreads();

    // ---- dec2: out[NS][784] = sigmoid(h @ W^T + b) via MFMA (1 row-tile) --
    const int wv   = t >> 6;      // 0..3
    const int lane = t & 63;
    const int arow = lane & 15;   // A row (sample) / B col within tile
    const int kgrp = lane >> 4;   // 0..3

    bf16x8 afr[5];                // hoisted A fragments: 5 k-steps
    #pragma unroll
    for (int ks = 0; ks < 5; ++ks)
        afr[ks] = *reinterpret_cast<const bf16x8*>(
            &sHd[arow * HS + ks * 32 + kgrp * 8]);

    for (int ct = wv; ct < 49; ct += 4) {
        const int col = ct * 16 + arow;
        bf16x8 bfr[5];
        const unsigned short* wp = dec2_wb + (size_t)col * 160 + kgrp * 8;
        #pragma unroll
        for (int ks = 0; ks < 5; ++ks)
            bfr[ks] = *reinterpret_cast<const bf16x8*>(wp + ks * 32);

        f32x4 acc0 = {0.f, 0.f, 0.f, 0.f};
        #pragma unroll
        for (int ks = 0; ks < 5; ++ks)
            acc0 = __builtin_amdgcn_mfma_f32_16x16x32_bf16(afr[ks], bfr[ks], acc0, 0, 0, 0);
        const float bb = dec2_b[col];
        #pragma unroll
        for (int r = 0; r < 4; ++r) {
            const int row = kgrp * 4 + r;          // D: row=(lane>>4)*4+reg
            const float v0 = acc0[r] + bb;
            out[(size_t)(b0 + row) * 784 + col] = 1.0f / (1.0f + __expf(-v0));
        }
    }
}

// ---------------------------------------------------------------------------
extern "C" void kernel_launch(void* const* d_in, const int* in_sizes, int n_in,
                              void* d_out, int out_size, void* d_ws, size_t ws_size,
                              hipStream_t stream) {
    const float* images  = (const float*)d_in[0];
    const float* conv1_w = (const float*)d_in[1];
    const float* conv1_b = (const float*)d_in[2];
    const float* conv2_w = (const float*)d_in[3];
    const float* conv2_b = (const float*)d_in[4];
    const float* lin1_w  = (const float*)d_in[5];
    const float* lin1_b  = (const float*)d_in[6];
    const float* lin2_w  = (const float*)d_in[7];
    const float* lin2_b  = (const float*)d_in[8];
    const float* dec1_w  = (const float*)d_in[9];
    const float* dec1_b  = (const float*)d_in[10];
    const float* dec2_w  = (const float*)d_in[11];
    const float* dec2_b  = (const float*)d_in[12];

    float* out_img = (float*)d_out;                    // NB*784 fp32
    float* code    = (float*)d_out + (size_t)NB * 784; // NB*25  fp32

    // workspace layout (bytes, all 16-aligned):
    char* ws = (char*)d_ws;
    float*          x2      = (float*)ws;                                  // NB*320 f
    unsigned short* wbf     = (unsigned short*)(ws + (size_t)NB * 345 * 4);// 125440 us
    char*           pB      = ws + (size_t)NB * 345 * 4 + 250880;
    float*          lin1_wp = (float*)pB;                                  // 16000 f
    unsigned short* woff4   = (unsigned short*)(pB + 64000);               // 128 us
    __fp16*         whi     = (__fp16*)(pB + 64512);                       // 8192 h
    __fp16*         wlo     = (__fp16*)(pB + 80896);                       // 8192 h
    unsigned short* koff4   = (unsigned short*)(pB + 97280);               // 16 us
    __fp16*         whi1    = (__fp16*)(pB + 97344);                       // 512 h
    __fp16*         wlo1    = (__fp16*)(pB + 98368);                       // 512 h

    k_prep     <<<622,      256, 0, stream>>>(dec2_w, wbf, lin1_w, lin1_wp,
                                              conv2_w, woff4, whi, wlo,
                                              conv1_w, koff4, whi1, wlo1);
    k_conv_fused<<<NB / 4,  256, 0, stream>>>(images, conv1_b, conv2_b,
                                              woff4, whi, wlo,
                                              koff4, whi1, wlo1, x2);
    k_tail     <<<NB / NS, 256, 0, stream>>>(x2, lin1_wp, lin1_b,
                                             lin2_w, lin2_b,
                                             dec1_w, dec1_b,
                                             wbf, dec2_b,
                                             code, out_img);
}

// Round 16
// 139.086 us; speedup vs baseline: 1.8752x; 1.1988x over previous
//
#include <hip/hip_runtime.h>
#include <hip/hip_bf16.h>
#include <math.h>

#define NB 16384

typedef __bf16 bf16x8 __attribute__((ext_vector_type(8)));
typedef __fp16 f16x8  __attribute__((ext_vector_type(8)));
typedef float  f32x4  __attribute__((ext_vector_type(4)));
typedef unsigned short ushort4v __attribute__((ext_vector_type(4)));
typedef unsigned int   uint4v  __attribute__((ext_vector_type(4)));

__device__ __forceinline__ float selu_f(float x) {
    const float kScale = 1.0507009873554805f;
    const float kAlphaScale = 1.7580993408473766f;   // scale*alpha
    return x > 0.0f ? kScale * x : kAlphaScale * (__expf(x) - 1.0f);
}

__device__ __forceinline__ unsigned short f2bf(float x) {   // RNE
    unsigned int u = __float_as_uint(x);
    unsigned int r = (u + 0x7FFFu + ((u >> 16) & 1u)) >> 16;
    return (unsigned short)r;
}

// split v into fp16 hi + fp16 lo, packed into one u32 (lo16=hi, hi16=lo)
__device__ __forceinline__ unsigned int packsplit(float v) {
    const __fp16 h = (__fp16)v;
    const __fp16 l = (__fp16)(v - (float)h);
    const unsigned int hb = (unsigned int)__builtin_bit_cast(unsigned short, h);
    const unsigned int lb = (unsigned int)__builtin_bit_cast(unsigned short, l);
    return hb | (lb << 16);
}

// extract packed pairs: AH u32 = hi fp16s, AL u32 = lo fp16s
#define PERM_AH 0x05040100u
#define PERM_AL 0x07060302u

union F16x8Cast { uint4v u; f16x8 f; };

#define CH1 145          // x1 channel stride (u32)
#define X1SZ (CH1 * 10)  // 1450 u32 per image
#define IMS 37           // sImgP row stride
#define IMSZ 1064        // per image

// ---------------------------------------------------------------------------
// K-permutations for pairwise (ds_read2-mergeable) A-gathers (r13, proven).
// ---------------------------------------------------------------------------
__device__ __forceinline__ int c2_elem(int s, int g, int j) {
    const int o = s * 4 + g, jp = j >> 1, hl = j & 1;
    if (jp < 3) {
        const int p = o * 3 + jp;
        int ch, idx;
        if (p < 60) { ch = p / 10; idx = p - ch * 10; }
        else        { ch = 6 + (p - 60) / 9; idx = (p - 60) % 9; }
        int tap;
        if (ch < 6)        tap = 5 * (idx >> 1) + 2 * (idx & 1);
        else if (idx == 0) tap = 0;
        else { const int r = ((idx - 1) >> 1) + 1; tap = 5 * r + 2 * ((idx - 1) & 1); }
        return ch * 25 + tap + hl;
    } else {
        const int q = o;
        if (q >= 29) return -1;
        int chp, tap;
        if (q < 15) { chp = q / 5; const int ts = q - chp * 5; tap = 5 * ts + 4; }
        else { const int q2 = q - 15; chp = 3 + q2 / 7; const int ts = q2 % 7;
               tap = (ts < 2) ? (2 + ts) : (5 * (ts - 2) + 4); }
        return (2 * chp + hl) * 25 + tap;
    }
}
__device__ __forceinline__ int c1_elem(int g, int j) {
    const int p = g * 4 + (j >> 1), hl = j & 1;
    if (p < 10) return 5 * (p >> 1) + 2 * (p & 1) + hl;
    if (p < 15) return hl ? -1 : (5 * (p - 10) + 4);
    return -1;
}

// ---------------------------------------------------------------------------
// Kernel P (prep): builds all weight-derived tables in ws.
//  1. dec2_w -> bf16 wbf                                   (125440)
//  2. lin1_w -> whiL/wloL split, MFMA B-fragment order     (20480 slots)
//     slot ((nt*10+ks)*64+lane)*8+j: k=ks*32+(lane>>4&3)*8+j, ocol=nt*16+
//     (lane&15); input index k is in x2's [q*20+oc] permuted space ->
//     original lin1 col = (k%20)*16 + (k/20). Replaces lin1_wp.
//  3. woff4 / conv2 whi,wlo / koff4 / conv1 whi1,wlo1 (r13, proven)
// ---------------------------------------------------------------------------
__global__ __launch_bounds__(256) void k_prep(
    const float* __restrict__ dec2_w,  unsigned short* __restrict__ wbf,
    const float* __restrict__ lin1_w,  __fp16* __restrict__ whiL,
    __fp16* __restrict__ wloL,
    const float* __restrict__ conv2_w, unsigned short* __restrict__ woff4,
    __fp16* __restrict__ whi, __fp16* __restrict__ wlo,
    const float* __restrict__ conv1_w, unsigned short* __restrict__ koff4,
    __fp16* __restrict__ whi1, __fp16* __restrict__ wlo1)
{
    int i = blockIdx.x * 256 + threadIdx.x;
    if (i < 125440) { wbf[i] = f2bf(dec2_w[i]); return; }
    i -= 125440;
    if (i < 20480) {                       // lin1 split fragment tables
        const int j = i & 7, lane = (i >> 3) & 63, rest = i >> 9;  // 0..39
        const int nt = rest / 10, ks = rest - nt * 10;
        const int k    = ks * 32 + ((lane >> 4) & 3) * 8 + j;      // 0..319
        const int ocol = nt * 16 + (lane & 15);
        float w = 0.f;
        if (ocol < 50)
            w = lin1_w[ocol * 320 + (k % 20) * 16 + (k / 20)];
        const __fp16 hi = (__fp16)w;
        whiL[i] = hi;
        wloL[i] = (__fp16)(w - (float)hi);
        return;
    }
    i -= 20480;
    if (i < 128) {                         // conv2 pair-base offsets
        const int s = i >> 4, g = (i >> 2) & 3, jp = i & 3;
        const int e = c2_elem(s, g, jp * 2);
        unsigned short off = 0;
        if (e >= 0) {
            const int ic = e / 25, tap = e - ic * 25;
            off = (unsigned short)(ic * CH1 + (tap / 5) * 12 + tap % 5);
        }
        woff4[i] = off;
        return;
    }
    i -= 128;
    if (i < 16384) {                       // conv2 weight split tables
        const int v = i >> 13;             // 0 = hi, 1 = lo
        const int r = i & 8191;
        const int j = r & 7, lane = (r >> 3) & 63, s = (r >> 9) & 7, nt = r >> 12;
        const int oc = nt * 16 + (lane & 15);
        const int e = c2_elem(s, lane >> 4, j);
        float w = 0.f;
        if (e >= 0 && oc < 20) {
            const int ic = e / 25, tap = e - ic * 25;
            w = conv2_w[(oc * 10 + ic) * 25 + tap];
        }
        const __fp16 hi = (__fp16)w;
        if (v == 0) whi[r] = hi;
        else        wlo[r] = (__fp16)(w - (float)hi);
        return;
    }
    i -= 16384;
    if (i < 16) {                          // conv1 pair-base offsets
        const int e = c1_elem(i >> 2, (i & 3) * 2);
        koff4[i] = (unsigned short)(e < 0 ? 0 : (e / 5) * IMS + e % 5);
        return;
    }
    i -= 16;
    if (i < 1024) {                        // conv1 weight split tables
        const int v = i >> 9;
        const int r = i & 511;
        const int j = r & 7, lane = r >> 3;
        const int c = lane & 15, g = lane >> 4;
        const int e = c1_elem(g, j);
        const float w = (e >= 0 && c < 10) ? conv1_w[c * 25 + e] : 0.f;
        const __fp16 hi = (__fp16)w;
        if (v == 0) whi1[r] = hi;
        else        wlo1[r] = (__fp16)(w - (float)hi);
    }
}

// ---------------------------------------------------------------------------
// Kernel A (r14 body, proven 97us; epilogue now writes SPLIT-PACKED x2 so the
// tail's lin1-MFMA can consume it directly). Lessons pinned: (256,4) only
// (r4), unroll-1 outer + small live sets (r6), no conv2 K-padding (r9),
// phase-1 patches from LDS not global (r11).
// ---------------------------------------------------------------------------
__global__ __launch_bounds__(256, 4) void k_conv_fused(
    const float* __restrict__ images,
    const float* __restrict__ conv1_b, const float* __restrict__ conv2_b,
    const unsigned short* __restrict__ woff4,
    const __fp16* __restrict__ whi,  const __fp16* __restrict__ wlo,
    const unsigned short* __restrict__ koff4,
    const __fp16* __restrict__ whi1, const __fp16* __restrict__ wlo1,
    unsigned int* __restrict__ x2p)
{
    __shared__ unsigned int sImgP[4 * IMSZ];   // 17.0 KB
    __shared__ unsigned int sX1P[4 * X1SZ];    // 23.2 KB

    const int t  = threadIdx.x;
    const int b0 = blockIdx.x * 4;

    // ---- phase 0: images -> split-packed LDS (float4 loads; 28 = 7x4) ----
    for (int k = t; k < 4 * 196; k += 256) {
        const int img = k / 196;
        const int r4  = k - img * 196;
        const int row = r4 / 7;
        const int col = (r4 - row * 7) * 4;
        const float4 v = reinterpret_cast<const float4*>(
                             images + (size_t)(b0 + img) * 784)[r4];
        unsigned int* d = sImgP + img * IMSZ + row * IMS + col;
        d[0] = packsplit(v.x); d[1] = packsplit(v.y);
        d[2] = packsplit(v.z); d[3] = packsplit(v.w);
    }
    // zero col 28 (read by dummy pair-partners of col-4 taps; must be finite)
    for (int i = t; i < 112; i += 256) {
        const int img = i / 28, row = i - img * 28;
        sImgP[img * IMSZ + row * IMS + 28] = 0u;
    }
    __syncthreads();

    const int lane = t & 63;
    const int wv   = t >> 6;
    const int g    = lane >> 4;          // k-group
    const int c0   = lane & 15;          // A-row (phase1/2) / D-col

    // ---- phase 1: conv1 via MFMA -> sX1P[wv][c*CH1 + q] ----
    {
        const unsigned int* imgP = sImgP + wv * IMSZ;
        unsigned int* x1P = sX1P + wv * X1SZ;

        const int sub = c0 & 3, qq = c0 >> 2;
        const int base_lane = (sub >> 1) * IMS + 2 * qq + (sub & 1);
        const ushort4v k4 = *reinterpret_cast<const ushort4v*>(koff4 + g * 4);
        int ab[4];
        #pragma unroll
        for (int jp = 0; jp < 4; ++jp) ab[jp] = base_lane + (int)k4[jp];

        const f16x8 bh1 = *reinterpret_cast<const f16x8*>(whi1 + lane * 8);
        const f16x8 bl1 = *reinterpret_cast<const f16x8*>(wlo1 + lane * 8);
        const float bias = (c0 < 10) ? conv1_b[c0] : 0.f;

        #pragma unroll 1
        for (int a = 0; a < 12; ++a) {
            const int abase = a * (2 * IMS);
            #pragma unroll
            for (int b = 0; b < 3; ++b) {
                const unsigned int* pb_ = imgP + abase + b * 8;
                unsigned int w[8];
                const unsigned int* r0 = pb_ + ab[0]; w[0] = r0[0]; w[1] = r0[1];
                const unsigned int* r1 = pb_ + ab[1]; w[2] = r1[0]; w[3] = r1[1];
                const unsigned int* r2 = pb_ + ab[2]; w[4] = r2[0]; w[5] = r2[1];
                const unsigned int* r3 = pb_ + ab[3]; w[6] = r3[0]; w[7] = r3[1];
                F16x8Cast AH, AL;
                AH.u = (uint4v){ __builtin_amdgcn_perm(w[1], w[0], PERM_AH),
                                 __builtin_amdgcn_perm(w[3], w[2], PERM_AH),
                                 __builtin_amdgcn_perm(w[5], w[4], PERM_AH),
                                 __builtin_amdgcn_perm(w[7], w[6], PERM_AH) };
                AL.u = (uint4v){ __builtin_amdgcn_perm(w[1], w[0], PERM_AL),
                                 __builtin_amdgcn_perm(w[3], w[2], PERM_AL),
                                 __builtin_amdgcn_perm(w[5], w[4], PERM_AL),
                                 __builtin_amdgcn_perm(w[7], w[6], PERM_AL) };
                f32x4 acc = {0.f, 0.f, 0.f, 0.f};
                __builtin_amdgcn_s_setprio(1);
                acc = __builtin_amdgcn_mfma_f32_16x16x32_f16(AH.f, bh1, acc, 0, 0, 0);
                acc = __builtin_amdgcn_mfma_f32_16x16x32_f16(AL.f, bh1, acc, 0, 0, 0);
                acc = __builtin_amdgcn_mfma_f32_16x16x32_f16(AH.f, bl1, acc, 0, 0, 0);
                __builtin_amdgcn_s_setprio(0);
                const float m = fmaxf(fmaxf(acc[0], acc[1]), fmaxf(acc[2], acc[3]));
                if (c0 < 10)
                    x1P[c0 * CH1 + 12 * a + 4 * b + g] = packsplit(selu_f(m + bias));
            }
        }
    }
    __syncthreads();

    // ---- phase 2: conv2 via MFMA (perm extraction, paired gathers) ----
    {
        const unsigned int* x1P = sX1P + wv * X1SZ;

        int rowbase[4];
        #pragma unroll
        for (int mi = 0; mi < 4; ++mi) {
            const int r64 = mi * 16 + c0;
            const int qi  = r64 >> 2;
            const int sb  = r64 & 3;
            rowbase[mi] = (2 * (qi >> 2) + (sb >> 1)) * 12
                        + 2 * (qi & 3) + (sb & 1);
        }

        f32x4 acc[4][2];
        #pragma unroll
        for (int mi = 0; mi < 4; ++mi) {
            acc[mi][0] = (f32x4){0.f, 0.f, 0.f, 0.f};
            acc[mi][1] = (f32x4){0.f, 0.f, 0.f, 0.f};
        }

        // double-buffered per-s data (named regs; no runtime indexing)
        ushort4v of = *reinterpret_cast<const ushort4v*>(woff4 + g * 4);
        f16x8 bh0 = *reinterpret_cast<const f16x8*>(whi + (size_t)(0 * 64 + lane) * 8);
        f16x8 bl0 = *reinterpret_cast<const f16x8*>(wlo + (size_t)(0 * 64 + lane) * 8);
        f16x8 bh1 = *reinterpret_cast<const f16x8*>(whi + (size_t)(8 * 64 + lane) * 8);
        f16x8 bl1 = *reinterpret_cast<const f16x8*>(wlo + (size_t)(8 * 64 + lane) * 8);

        #pragma unroll 1
        for (int s = 0; s < 8; ++s) {
            const int sn = (s + 1) & 7;    // wraps harmlessly at s=7
            const ushort4v ofn = *reinterpret_cast<const ushort4v*>(woff4 + sn * 16 + g * 4);
            const f16x8 nbh0 = *reinterpret_cast<const f16x8*>(whi + (size_t)((0 + sn) * 64 + lane) * 8);
            const f16x8 nbl0 = *reinterpret_cast<const f16x8*>(wlo + (size_t)((0 + sn) * 64 + lane) * 8);
            const f16x8 nbh1 = *reinterpret_cast<const f16x8*>(whi + (size_t)((8 + sn) * 64 + lane) * 8);
            const f16x8 nbl1 = *reinterpret_cast<const f16x8*>(wlo + (size_t)((8 + sn) * 64 + lane) * 8);

            #pragma unroll
            for (int mi = 0; mi < 4; ++mi) {
                const unsigned int* pp = x1P + rowbase[mi];
                unsigned int w[8];
                const unsigned int* q0 = pp + (int)of[0]; w[0] = q0[0]; w[1] = q0[1];
                const unsigned int* q1 = pp + (int)of[1]; w[2] = q1[0]; w[3] = q1[1];
                const unsigned int* q2 = pp + (int)of[2]; w[4] = q2[0]; w[5] = q2[1];
                const unsigned int* q3 = pp + (int)of[3]; w[6] = q3[0]; w[7] = q3[145];
                F16x8Cast AH, AL;
                AH.u = (uint4v){ __builtin_amdgcn_perm(w[1], w[0], PERM_AH),
                                 __builtin_amdgcn_perm(w[3], w[2], PERM_AH),
                                 __builtin_amdgcn_perm(w[5], w[4], PERM_AH),
                                 __builtin_amdgcn_perm(w[7], w[6], PERM_AH) };
                AL.u = (uint4v){ __builtin_amdgcn_perm(w[1], w[0], PERM_AL),
                                 __builtin_amdgcn_perm(w[3], w[2], PERM_AL),
                                 __builtin_amdgcn_perm(w[5], w[4], PERM_AL),
                                 __builtin_amdgcn_perm(w[7], w[6], PERM_AL) };
                __builtin_amdgcn_s_setprio(1);
                acc[mi][0] = __builtin_amdgcn_mfma_f32_16x16x32_f16(AH.f, bh0, acc[mi][0], 0, 0, 0);
                acc[mi][0] = __builtin_amdgcn_mfma_f32_16x16x32_f16(AL.f, bh0, acc[mi][0], 0, 0, 0);
                acc[mi][0] = __builtin_amdgcn_mfma_f32_16x16x32_f16(AH.f, bl0, acc[mi][0], 0, 0, 0);
                acc[mi][1] = __builtin_amdgcn_mfma_f32_16x16x32_f16(AH.f, bh1, acc[mi][1], 0, 0, 0);
                acc[mi][1] = __builtin_amdgcn_mfma_f32_16x16x32_f16(AL.f, bh1, acc[mi][1], 0, 0, 0);
                acc[mi][1] = __builtin_amdgcn_mfma_f32_16x16x32_f16(AH.f, bl1, acc[mi][1], 0, 0, 0);
                __builtin_amdgcn_s_setprio(0);
            }
            of = ofn; bh0 = nbh0; bl0 = nbl0; bh1 = nbh1; bl1 = nbl1;
        }

        // epilogue: pool quad in D-regs; write SPLIT-PACKED x2
        const float bias0 = conv2_b[c0];
        const float bias1 = (c0 < 4) ? conv2_b[16 + c0] : 0.f;
        #pragma unroll
        for (int mi = 0; mi < 4; ++mi) {
            const int qq = mi * 4 + g;
            unsigned int* orow = x2p + (size_t)(b0 + wv) * 320 + qq * 20;
            const float v0 = fmaxf(fmaxf(acc[mi][0][0], acc[mi][0][1]),
                                   fmaxf(acc[mi][0][2], acc[mi][0][3]));
            orow[c0] = packsplit(selu_f(v0 + bias0));
            if (c0 < 4) {
                const float v1 = fmaxf(fmaxf(acc[mi][1][0], acc[mi][1][1]),
                                       fmaxf(acc[mi][1][2], acc[mi][1][3]));
                orow[16 + c0] = packsplit(selu_f(v1 + bias1));
            }
        }
    }
}

// ---------------------------------------------------------------------------
// Kernel T (tail): lin1 as split-fp16 MFMA (M=16 samples, N=4x16 tiles one
// per wave, K=320; A = packed x2 rows, consecutive -> b128 + perm, no gather)
// -> lin2 (VALU, tiny) -> code; fp32 Jacobi SVD w/ convergence skip -> proj
// in LDS -> dec1 -> dec2 MFMA + sigmoid -> out.
// ---------------------------------------------------------------------------
#define NS 16    // samples per tail block
#define HS 168   // padded h row stride in ushorts
#define SIS 324  // sInP row stride in u32 (324 mod 32 = 4 -> 2-way max)

__global__ __launch_bounds__(256) void k_tail(
    const unsigned int* __restrict__ x2p,
    const __fp16* __restrict__ whiL, const __fp16* __restrict__ wloL,
    const float* __restrict__ lin1_b,
    const float* __restrict__ lin2_w,  const float* __restrict__ lin2_b,
    const float* __restrict__ dec1_w,  const float* __restrict__ dec1_b,
    const unsigned short* __restrict__ dec2_wb, const float* __restrict__ dec2_b,
    float* __restrict__ code, float* __restrict__ out)
{
    __shared__ unsigned int sInP[NS][SIS];   // 20.25 KB; reused as sHd later
    __shared__ float sH[NS][51];
    __shared__ float sC[NS][28];
    __shared__ float sP[NS][26];             // proj (SVD output)
    unsigned short* sHd = reinterpret_cast<unsigned short*>(&sInP[0][0]);

    const int t  = threadIdx.x;
    const int b0 = blockIdx.x * NS;
    const int lane = t & 63;
    const int wv   = t >> 6;

    {   // uint4-vectorized packed-x2 staging (rows contiguous in global)
        const uint4v* g = reinterpret_cast<const uint4v*>(x2p + (size_t)b0 * 320);
        for (int k = t; k < NS * 80; k += 256) {
            const int r  = k / 80;
            const int c4 = k - r * 80;
            *reinterpret_cast<uint4v*>(&sInP[r][c4 * 4]) = g[k];
        }
    }
    __syncthreads();

    // ---- lin1 via split-fp16 MFMA: wave wv owns output cols wv*16..+15 ----
    const int arow = lane & 15;   // A row (sample) / D col (output j)
    const int kgrp = lane >> 4;
    {
        f32x4 accL = {0.f, 0.f, 0.f, 0.f};
        #pragma unroll 1
        for (int ks = 0; ks < 10; ++ks) {
            const unsigned int* pa = &sInP[arow][ks * 32 + kgrp * 8];
            const uint4v w0 = *reinterpret_cast<const uint4v*>(pa);
            const uint4v w1 = *reinterpret_cast<const uint4v*>(pa + 4);
            F16x8Cast AH, AL;
            AH.u = (uint4v){ __builtin_amdgcn_perm(w0[1], w0[0], PERM_AH),
                             __builtin_amdgcn_perm(w0[3], w0[2], PERM_AH),
                             __builtin_amdgcn_perm(w1[1], w1[0], PERM_AH),
                             __builtin_amdgcn_perm(w1[3], w1[2], PERM_AH) };
            AL.u = (uint4v){ __builtin_amdgcn_perm(w0[1], w0[0], PERM_AL),
                             __builtin_amdgcn_perm(w0[3], w0[2], PERM_AL),
                             __builtin_amdgcn_perm(w1[1], w1[0], PERM_AL),
                             __builtin_amdgcn_perm(w1[3], w1[2], PERM_AL) };
            const f16x8 bh = *reinterpret_cast<const f16x8*>(
                whiL + ((size_t)(wv * 10 + ks) * 64 + lane) * 8);
            const f16x8 bl = *reinterpret_cast<const f16x8*>(
                wloL + ((size_t)(wv * 10 + ks) * 64 + lane) * 8);
            accL = __builtin_amdgcn_mfma_f32_16x16x32_f16(AH.f, bh, accL, 0, 0, 0);
            accL = __builtin_amdgcn_mfma_f32_16x16x32_f16(AL.f, bh, accL, 0, 0, 0);
            accL = __builtin_amdgcn_mfma_f32_16x16x32_f16(AH.f, bl, accL, 0, 0, 0);
        }
        const int ocol = wv * 16 + arow;     // lin1 output index
        if (ocol < 50) {
            const float bb = lin1_b[ocol];
            #pragma unroll
            for (int r = 0; r < 4; ++r)      // D row = sample = kgrp*4+r
                sH[kgrp * 4 + r][ocol] = selu_f(accL[r] + bb);
        }
    }
    __syncthreads();

    for (int idx = t; idx < NS * 25; idx += 256) {     // lin2: NS x 25
        const int bi = idx & (NS - 1);
        const int j  = idx / NS;
        float s = lin2_b[j];
        const float* w = lin2_w + j * 50;
        #pragma unroll
        for (int k = 0; k < 50; ++k) s = fmaf(sH[bi][k], w[k], s);
        code[(size_t)(b0 + bi) * 25 + j] = s;
        sC[bi][j] = s;
    }
    __syncthreads();

    // ---- fp32 Jacobi SVD projector (convergence-skip guard) ----
    if (t < NS) {
        float M[5][5];
        #pragma unroll
        for (int i = 0; i < 5; ++i)
            #pragma unroll
            for (int j = 0; j < 5; ++j) M[i][j] = sC[t][i * 5 + j];

        float A[5][5], V[5][5];
        #pragma unroll
        for (int i = 0; i < 5; ++i) {
            #pragma unroll
            for (int j = 0; j < 5; ++j) {
                float s = 0.f;
                #pragma unroll
                for (int k = 0; k < 5; ++k) s = fmaf(M[i][k], M[j][k], s);
                A[i][j] = s;
                V[i][j] = (i == j) ? 1.f : 0.f;
            }
        }
        for (int sweep = 0; sweep < 6; ++sweep) {
            #pragma unroll
            for (int p = 0; p < 4; ++p) {
                #pragma unroll
                for (int q = p + 1; q < 5; ++q) {
                    const float apq = A[p][q];
                    const float app = A[p][p], aqq = A[q][q];
                    // skip converged rotations (angle < ~3e-7)
                    if (apq * apq > 1e-13f * fmaxf(app * aqq, 1e-30f)) {
                        const float tau = (aqq - app) / (2.f * apq);
                        const float tt  = (tau >= 0.f ? 1.f : -1.f) /
                                          (fabsf(tau) + sqrtf(1.f + tau * tau));
                        const float cc  = 1.f / sqrtf(1.f + tt * tt);
                        const float ss  = tt * cc;
                        #pragma unroll
                        for (int i = 0; i < 5; ++i) {
                            if (i == p || i == q) continue;
                            const float aip = A[i][p], aiq = A[i][q];
                            A[i][p] = A[p][i] = cc * aip - ss * aiq;
                            A[i][q] = A[q][i] = ss * aip + cc * aiq;
                        }
                        A[p][p] = app - tt * apq;
                        A[q][q] = aqq + tt * apq;
                        A[p][q] = A[q][p] = 0.f;
                        #pragma unroll
                        for (int i = 0; i < 5; ++i) {
                            const float vip = V[i][p], viq = V[i][q];
                            V[i][p] = cc * vip - ss * viq;
                            V[i][q] = ss * vip + cc * viq;
                        }
                    }
                }
            }
        }
        float d[5];
        #pragma unroll
        for (int i = 0; i < 5; ++i) d[i] = A[i][i];
        float sel[5];
        #pragma unroll
        for (int c1 = 0; c1 < 5; ++c1) {
            int cnt = 0;
            #pragma unroll
            for (int c2 = 0; c2 < 5; ++c2) {
                if (c2 == c1) continue;
                if (d[c2] > d[c1] || (d[c2] == d[c1] && c2 < c1)) ++cnt;
            }
            sel[c1] = (cnt < 2) ? 1.f : 0.f;
        }
        #pragma unroll
        for (int i = 0; i < 5; ++i) {
            #pragma unroll
            for (int j = 0; j < 5; ++j) {
                float s = 0.f;
                #pragma unroll
                for (int k = 0; k < 5; ++k) s = fmaf(sel[k] * V[i][k], V[j][k], s);
                sP[t][i * 5 + j] = s;
            }
        }
    }
    __syncthreads();

    // ---- dec1: h[bi][j] = selu(sP row @ dec1_w) -> sHd (overlays sInP) ----
    const int bi = t & (NS - 1);
    const int j0 = t / NS;               // 0..15
    {
        float p[25];
        #pragma unroll
        for (int k = 0; k < 25; ++k) p[k] = sP[bi][k];
        #pragma unroll 2
        for (int i = 0; i < 10; ++i) {   // j = j0 + 16*i covers 0..159
            const int j = j0 + i * 16;
            const float* w = dec1_w + j * 25;
            float s = dec1_b[j];
            #pragma unroll
            for (int k = 0; k < 25; ++k) s = fmaf(p[k], w[k], s);
            sHd[bi * HS + j] = f2bf(selu_f(s));
        }
    }
    __syncthreads();

    // ---- dec2: out[NS][784] = sigmoid(h @ W^T + b) via MFMA (1 row-tile) --
    bf16x8 afr[5];                // hoisted A fragments: 5 k-steps
    #pragma unroll
    for (int ks = 0; ks < 5; ++ks)
        afr[ks] = *reinterpret_cast<const bf16x8*>(
            &sHd[arow * HS + ks * 32 + kgrp * 8]);

    for (int ct = wv; ct < 49; ct += 4) {
        const int col = ct * 16 + arow;
        bf16x8 bfr[5];
        const unsigned short* wp = dec2_wb + (size_t)col * 160 + kgrp * 8;
        #pragma unroll
        for (int ks = 0; ks < 5; ++ks)
            bfr[ks] = *reinterpret_cast<const bf16x8*>(wp + ks * 32);

        f32x4 acc0 = {0.f, 0.f, 0.f, 0.f};
        #pragma unroll
        for (int ks = 0; ks < 5; ++ks)
            acc0 = __builtin_amdgcn_mfma_f32_16x16x32_bf16(afr[ks], bfr[ks], acc0, 0, 0, 0);
        const float bb = dec2_b[col];
        #pragma unroll
        for (int r = 0; r < 4; ++r) {
            const int row = kgrp * 4 + r;          // D: row=(lane>>4)*4+reg
            const float v0 = acc0[r] + bb;
            out[(size_t)(b0 + row) * 784 + col] = 1.0f / (1.0f + __expf(-v0));
        }
    }
}

// ---------------------------------------------------------------------------
extern "C" void kernel_launch(void* const* d_in, const int* in_sizes, int n_in,
                              void* d_out, int out_size, void* d_ws, size_t ws_size,
                              hipStream_t stream) {
    const float* images  = (const float*)d_in[0];
    const float* conv1_w = (const float*)d_in[1];
    const float* conv1_b = (const float*)d_in[2];
    const float* conv2_w = (const float*)d_in[3];
    const float* conv2_b = (const float*)d_in[4];
    const float* lin1_w  = (const float*)d_in[5];
    const float* lin1_b  = (const float*)d_in[6];
    const float* lin2_w  = (const float*)d_in[7];
    const float* lin2_b  = (const float*)d_in[8];
    const float* dec1_w  = (const float*)d_in[9];
    const float* dec1_b  = (const float*)d_in[10];
    const float* dec2_w  = (const float*)d_in[11];
    const float* dec2_b  = (const float*)d_in[12];

    float* out_img = (float*)d_out;                    // NB*784 fp32
    float* code    = (float*)d_out + (size_t)NB * 784; // NB*25  fp32

    // workspace layout (bytes, 64-aligned offsets):
    char* ws = (char*)d_ws;
    unsigned int*   x2p     = (unsigned int*)ws;                           // NB*320 u32
    unsigned short* wbf     = (unsigned short*)(ws + (size_t)NB * 320 * 4);// 125440 us
    char*           pB      = ws + (size_t)NB * 320 * 4 + 250880;
    __fp16*         whiL    = (__fp16*)pB;                                 // 20480 h
    __fp16*         wloL    = (__fp16*)(pB + 40960);                       // 20480 h
    unsigned short* woff4   = (unsigned short*)(pB + 81920);               // 128 us
    __fp16*         whi     = (__fp16*)(pB + 82432);                       // 8192 h
    __fp16*         wlo     = (__fp16*)(pB + 98816);                       // 8192 h
    unsigned short* koff4   = (unsigned short*)(pB + 115200);              // 16 us
    __fp16*         whi1    = (__fp16*)(pB + 115264);                      // 512 h
    __fp16*         wlo1    = (__fp16*)(pB + 116288);                      // 512 h

    k_prep     <<<639,      256, 0, stream>>>(dec2_w, wbf, lin1_w, whiL, wloL,
                                              conv2_w, woff4, whi, wlo,
                                              conv1_w, koff4, whi1, wlo1);
    k_conv_fused<<<NB / 4,  256, 0, stream>>>(images, conv1_b, conv2_b,
                                              woff4, whi, wlo,
                                              koff4, whi1, wlo1, x2p);
    k_tail     <<<NB / NS, 256, 0, stream>>>(x2p, whiL, wloL, lin1_b,
                                             lin2_w, lin2_b,
                                             dec1_w, dec1_b,
                                             wbf, dec2_b,
                                             code, out_img);
}

// Round 17
// 139.070 us; speedup vs baseline: 1.8754x; 1.0001x over previous
//
#include <hip/hip_runtime.h>
#include <hip/hip_bf16.h>
#include <math.h>

#define NB 16384

typedef __bf16 bf16x8 __attribute__((ext_vector_type(8)));
typedef __fp16 f16x8  __attribute__((ext_vector_type(8)));
typedef float  f32x4  __attribute__((ext_vector_type(4)));
typedef unsigned short ushort4v __attribute__((ext_vector_type(4)));
typedef unsigned int   uint4v  __attribute__((ext_vector_type(4)));

__device__ __forceinline__ float selu_f(float x) {
    const float kScale = 1.0507009873554805f;
    const float kAlphaScale = 1.7580993408473766f;   // scale*alpha
    return x > 0.0f ? kScale * x : kAlphaScale * (__expf(x) - 1.0f);
}

__device__ __forceinline__ unsigned short f2bf(float x) {   // RNE
    unsigned int u = __float_as_uint(x);
    unsigned int r = (u + 0x7FFFu + ((u >> 16) & 1u)) >> 16;
    return (unsigned short)r;
}

// split v into fp16 hi + fp16 lo, packed into one u32 (lo16=hi, hi16=lo)
__device__ __forceinline__ unsigned int packsplit(float v) {
    const __fp16 h = (__fp16)v;
    const __fp16 l = (__fp16)(v - (float)h);
    const unsigned int hb = (unsigned int)__builtin_bit_cast(unsigned short, h);
    const unsigned int lb = (unsigned int)__builtin_bit_cast(unsigned short, l);
    return hb | (lb << 16);
}

// extract packed pairs: AH u32 = hi fp16s, AL u32 = lo fp16s
#define PERM_AH 0x05040100u
#define PERM_AL 0x07060302u

union F16x8Cast { uint4v u; f16x8 f; };

#define CH1 145          // x1 channel stride (u32)
#define X1SZ (CH1 * 10)  // 1450 u32 per image
// parity-split image layout: even row y at 29*(y/2), odd row y at 432+29*(y/2)
// -> the two rows of any read pair differ by 432 == 16 (mod 32): disjoint banks
#define IMSZ 840         // per image (max addr 837)
__device__ __forceinline__ int rowoff29(int y) {
    return 29 * (y >> 1) + 432 * (y & 1);
}

// ---------------------------------------------------------------------------
// K-permutations for pairwise (ds_read2-mergeable) A-gathers (r13, proven).
// ---------------------------------------------------------------------------
__device__ __forceinline__ int c2_elem(int s, int g, int j) {
    const int o = s * 4 + g, jp = j >> 1, hl = j & 1;
    if (jp < 3) {
        const int p = o * 3 + jp;
        int ch, idx;
        if (p < 60) { ch = p / 10; idx = p - ch * 10; }
        else        { ch = 6 + (p - 60) / 9; idx = (p - 60) % 9; }
        int tap;
        if (ch < 6)        tap = 5 * (idx >> 1) + 2 * (idx & 1);
        else if (idx == 0) tap = 0;
        else { const int r = ((idx - 1) >> 1) + 1; tap = 5 * r + 2 * ((idx - 1) & 1); }
        return ch * 25 + tap + hl;
    } else {
        const int q = o;
        if (q >= 29) return -1;
        int chp, tap;
        if (q < 15) { chp = q / 5; const int ts = q - chp * 5; tap = 5 * ts + 4; }
        else { const int q2 = q - 15; chp = 3 + q2 / 7; const int ts = q2 % 7;
               tap = (ts < 2) ? (2 + ts) : (5 * (ts - 2) + 4); }
        return (2 * chp + hl) * 25 + tap;
    }
}
__device__ __forceinline__ int c1_elem(int g, int j) {
    const int p = g * 4 + (j >> 1), hl = j & 1;
    if (p < 10) return 5 * (p >> 1) + 2 * (p & 1) + hl;
    if (p < 15) return hl ? -1 : (5 * (p - 10) + 4);
    return -1;
}

// ---------------------------------------------------------------------------
// Kernel P (prep): builds all weight-derived tables in ws.
// koff4 is now 32 entries: [parity p][g][jp] -> parity-aware offset
//   29*((p+ky)>>1) + 432*((p+ky)&1) + kx   (relative to 29a base).
// ---------------------------------------------------------------------------
__global__ __launch_bounds__(256) void k_prep(
    const float* __restrict__ dec2_w,  unsigned short* __restrict__ wbf,
    const float* __restrict__ lin1_w,  __fp16* __restrict__ whiL,
    __fp16* __restrict__ wloL,
    const float* __restrict__ conv2_w, unsigned short* __restrict__ woff4,
    __fp16* __restrict__ whi, __fp16* __restrict__ wlo,
    const float* __restrict__ conv1_w, unsigned short* __restrict__ koff4,
    __fp16* __restrict__ whi1, __fp16* __restrict__ wlo1)
{
    int i = blockIdx.x * 256 + threadIdx.x;
    if (i < 125440) { wbf[i] = f2bf(dec2_w[i]); return; }
    i -= 125440;
    if (i < 20480) {                       // lin1 split fragment tables
        const int j = i & 7, lane = (i >> 3) & 63, rest = i >> 9;  // 0..39
        const int nt = rest / 10, ks = rest - nt * 10;
        const int k    = ks * 32 + ((lane >> 4) & 3) * 8 + j;      // 0..319
        const int ocol = nt * 16 + (lane & 15);
        float w = 0.f;
        if (ocol < 50)
            w = lin1_w[ocol * 320 + (k % 20) * 16 + (k / 20)];
        const __fp16 hi = (__fp16)w;
        whiL[i] = hi;
        wloL[i] = (__fp16)(w - (float)hi);
        return;
    }
    i -= 20480;
    if (i < 128) {                         // conv2 pair-base offsets
        const int s = i >> 4, g = (i >> 2) & 3, jp = i & 3;
        const int e = c2_elem(s, g, jp * 2);
        unsigned short off = 0;
        if (e >= 0) {
            const int ic = e / 25, tap = e - ic * 25;
            off = (unsigned short)(ic * CH1 + (tap / 5) * 12 + tap % 5);
        }
        woff4[i] = off;
        return;
    }
    i -= 128;
    if (i < 16384) {                       // conv2 weight split tables
        const int v = i >> 13;             // 0 = hi, 1 = lo
        const int r = i & 8191;
        const int j = r & 7, lane = (r >> 3) & 63, s = (r >> 9) & 7, nt = r >> 12;
        const int oc = nt * 16 + (lane & 15);
        const int e = c2_elem(s, lane >> 4, j);
        float w = 0.f;
        if (e >= 0 && oc < 20) {
            const int ic = e / 25, tap = e - ic * 25;
            w = conv2_w[(oc * 10 + ic) * 25 + tap];
        }
        const __fp16 hi = (__fp16)w;
        if (v == 0) whi[r] = hi;
        else        wlo[r] = (__fp16)(w - (float)hi);
        return;
    }
    i -= 16384;
    if (i < 32) {                          // conv1 pair-base offsets (parity-split)
        const int p = i >> 4, g = (i >> 2) & 3, jp = i & 3;
        const int e = c1_elem(g, jp * 2);
        unsigned short off = 0;
        if (e >= 0) {
            const int ky = e / 5, kx = e % 5;
            const int t0 = p + ky;
            off = (unsigned short)(29 * (t0 >> 1) + 432 * (t0 & 1) + kx);
        }
        koff4[i] = off;
        return;
    }
    i -= 32;
    if (i < 1024) {                        // conv1 weight split tables
        const int v = i >> 9;
        const int r = i & 511;
        const int j = r & 7, lane = r >> 3;
        const int c = lane & 15, g = lane >> 4;
        const int e = c1_elem(g, j);
        const float w = (e >= 0 && c < 10) ? conv1_w[c * 25 + e] : 0.f;
        const __fp16 hi = (__fp16)w;
        if (v == 0) whi1[r] = hi;
        else        wlo1[r] = (__fp16)(w - (float)hi);
    }
}

// ---------------------------------------------------------------------------
// Kernel A (r16 body; sImgP now parity-split so every phase-1 read pair's two
// rows land 16 banks apart -> conflict-free within k-group). Lessons pinned:
// (256,4) only (r4), unroll-1 outer + small live sets (r6), no conv2
// K-padding (r9), phase-1 patches from LDS not global (r11).
// ---------------------------------------------------------------------------
__global__ __launch_bounds__(256, 4) void k_conv_fused(
    const float* __restrict__ images,
    const float* __restrict__ conv1_b, const float* __restrict__ conv2_b,
    const unsigned short* __restrict__ woff4,
    const __fp16* __restrict__ whi,  const __fp16* __restrict__ wlo,
    const unsigned short* __restrict__ koff4,
    const __fp16* __restrict__ whi1, const __fp16* __restrict__ wlo1,
    unsigned int* __restrict__ x2p)
{
    __shared__ unsigned int sImgP[4 * IMSZ];   // 13.4 KB (parity-split rows)
    __shared__ unsigned int sX1P[4 * X1SZ];    // 23.2 KB

    const int t  = threadIdx.x;
    const int b0 = blockIdx.x * 4;

    // ---- phase 0: images -> split-packed LDS (float4 loads; 28 = 7x4) ----
    for (int k = t; k < 4 * 196; k += 256) {
        const int img = k / 196;
        const int r4  = k - img * 196;
        const int row = r4 / 7;
        const int col = (r4 - row * 7) * 4;
        const float4 v = reinterpret_cast<const float4*>(
                             images + (size_t)(b0 + img) * 784)[r4];
        unsigned int* d = sImgP + img * IMSZ + rowoff29(row) + col;
        d[0] = packsplit(v.x); d[1] = packsplit(v.y);
        d[2] = packsplit(v.z); d[3] = packsplit(v.w);
    }
    // zero col 28 (read by dummy pair-partners of col-4 taps; must be finite)
    for (int i = t; i < 112; i += 256) {
        const int img = i / 28, row = i - img * 28;
        sImgP[img * IMSZ + rowoff29(row) + 28] = 0u;
    }
    __syncthreads();

    const int lane = t & 63;
    const int wv   = t >> 6;
    const int g    = lane >> 4;          // k-group
    const int c0   = lane & 15;          // A-row (phase1/2) / D-col

    // ---- phase 1: conv1 via MFMA -> sX1P[wv][c*CH1 + q] ----
    {
        const unsigned int* imgP = sImgP + wv * IMSZ;
        unsigned int* x1P = sX1P + wv * X1SZ;

        const int p1 = (c0 >> 1) & 1;            // sub>>1 (row parity of y0)
        const int base_lane = 2 * (c0 >> 2) + (c0 & 1);
        const ushort4v k4 = *reinterpret_cast<const ushort4v*>(
            koff4 + p1 * 16 + g * 4);
        int ab[4];
        #pragma unroll
        for (int jp = 0; jp < 4; ++jp) ab[jp] = base_lane + (int)k4[jp];

        const f16x8 bh1 = *reinterpret_cast<const f16x8*>(whi1 + lane * 8);
        const f16x8 bl1 = *reinterpret_cast<const f16x8*>(wlo1 + lane * 8);
        const float bias = (c0 < 10) ? conv1_b[c0] : 0.f;

        #pragma unroll 1
        for (int a = 0; a < 12; ++a) {
            const int abase = a * 29;
            #pragma unroll
            for (int b = 0; b < 3; ++b) {
                const unsigned int* pb_ = imgP + abase + b * 8;
                unsigned int w[8];
                const unsigned int* r0 = pb_ + ab[0]; w[0] = r0[0]; w[1] = r0[1];
                const unsigned int* r1 = pb_ + ab[1]; w[2] = r1[0]; w[3] = r1[1];
                const unsigned int* r2 = pb_ + ab[2]; w[4] = r2[0]; w[5] = r2[1];
                const unsigned int* r3 = pb_ + ab[3]; w[6] = r3[0]; w[7] = r3[1];
                F16x8Cast AH, AL;
                AH.u = (uint4v){ __builtin_amdgcn_perm(w[1], w[0], PERM_AH),
                                 __builtin_amdgcn_perm(w[3], w[2], PERM_AH),
                                 __builtin_amdgcn_perm(w[5], w[4], PERM_AH),
                                 __builtin_amdgcn_perm(w[7], w[6], PERM_AH) };
                AL.u = (uint4v){ __builtin_amdgcn_perm(w[1], w[0], PERM_AL),
                                 __builtin_amdgcn_perm(w[3], w[2], PERM_AL),
                                 __builtin_amdgcn_perm(w[5], w[4], PERM_AL),
                                 __builtin_amdgcn_perm(w[7], w[6], PERM_AL) };
                f32x4 acc = {0.f, 0.f, 0.f, 0.f};
                __builtin_amdgcn_s_setprio(1);
                acc = __builtin_amdgcn_mfma_f32_16x16x32_f16(AH.f, bh1, acc, 0, 0, 0);
                acc = __builtin_amdgcn_mfma_f32_16x16x32_f16(AL.f, bh1, acc, 0, 0, 0);
                acc = __builtin_amdgcn_mfma_f32_16x16x32_f16(AH.f, bl1, acc, 0, 0, 0);
                __builtin_amdgcn_s_setprio(0);
                const float m = fmaxf(fmaxf(acc[0], acc[1]), fmaxf(acc[2], acc[3]));
                if (c0 < 10)
                    x1P[c0 * CH1 + 12 * a + 4 * b + g] = packsplit(selu_f(m + bias));
            }
        }
    }
    __syncthreads();

    // ---- phase 2: conv2 via MFMA (perm extraction, paired gathers) ----
    {
        const unsigned int* x1P = sX1P + wv * X1SZ;

        int rowbase[4];
        #pragma unroll
        for (int mi = 0; mi < 4; ++mi) {
            const int r64 = mi * 16 + c0;
            const int qi  = r64 >> 2;
            const int sb  = r64 & 3;
            rowbase[mi] = (2 * (qi >> 2) + (sb >> 1)) * 12
                        + 2 * (qi & 3) + (sb & 1);
        }

        f32x4 acc[4][2];
        #pragma unroll
        for (int mi = 0; mi < 4; ++mi) {
            acc[mi][0] = (f32x4){0.f, 0.f, 0.f, 0.f};
            acc[mi][1] = (f32x4){0.f, 0.f, 0.f, 0.f};
        }

        // double-buffered per-s data (named regs; no runtime indexing)
        ushort4v of = *reinterpret_cast<const ushort4v*>(woff4 + g * 4);
        f16x8 bh0 = *reinterpret_cast<const f16x8*>(whi + (size_t)(0 * 64 + lane) * 8);
        f16x8 bl0 = *reinterpret_cast<const f16x8*>(wlo + (size_t)(0 * 64 + lane) * 8);
        f16x8 bh1 = *reinterpret_cast<const f16x8*>(whi + (size_t)(8 * 64 + lane) * 8);
        f16x8 bl1 = *reinterpret_cast<const f16x8*>(wlo + (size_t)(8 * 64 + lane) * 8);

        #pragma unroll 1
        for (int s = 0; s < 8; ++s) {
            const int sn = (s + 1) & 7;    // wraps harmlessly at s=7
            const ushort4v ofn = *reinterpret_cast<const ushort4v*>(woff4 + sn * 16 + g * 4);
            const f16x8 nbh0 = *reinterpret_cast<const f16x8*>(whi + (size_t)((0 + sn) * 64 + lane) * 8);
            const f16x8 nbl0 = *reinterpret_cast<const f16x8*>(wlo + (size_t)((0 + sn) * 64 + lane) * 8);
            const f16x8 nbh1 = *reinterpret_cast<const f16x8*>(whi + (size_t)((8 + sn) * 64 + lane) * 8);
            const f16x8 nbl1 = *reinterpret_cast<const f16x8*>(wlo + (size_t)((8 + sn) * 64 + lane) * 8);

            #pragma unroll
            for (int mi = 0; mi < 4; ++mi) {
                const unsigned int* pp = x1P + rowbase[mi];
                unsigned int w[8];
                const unsigned int* q0 = pp + (int)of[0]; w[0] = q0[0]; w[1] = q0[1];
                const unsigned int* q1 = pp + (int)of[1]; w[2] = q1[0]; w[3] = q1[1];
                const unsigned int* q2 = pp + (int)of[2]; w[4] = q2[0]; w[5] = q2[1];
                const unsigned int* q3 = pp + (int)of[3]; w[6] = q3[0]; w[7] = q3[145];
                F16x8Cast AH, AL;
                AH.u = (uint4v){ __builtin_amdgcn_perm(w[1], w[0], PERM_AH),
                                 __builtin_amdgcn_perm(w[3], w[2], PERM_AH),
                                 __builtin_amdgcn_perm(w[5], w[4], PERM_AH),
                                 __builtin_amdgcn_perm(w[7], w[6], PERM_AH) };
                AL.u = (uint4v){ __builtin_amdgcn_perm(w[1], w[0], PERM_AL),
                                 __builtin_amdgcn_perm(w[3], w[2], PERM_AL),
                                 __builtin_amdgcn_perm(w[5], w[4], PERM_AL),
                                 __builtin_amdgcn_perm(w[7], w[6], PERM_AL) };
                __builtin_amdgcn_s_setprio(1);
                acc[mi][0] = __builtin_amdgcn_mfma_f32_16x16x32_f16(AH.f, bh0, acc[mi][0], 0, 0, 0);
                acc[mi][0] = __builtin_amdgcn_mfma_f32_16x16x32_f16(AL.f, bh0, acc[mi][0], 0, 0, 0);
                acc[mi][0] = __builtin_amdgcn_mfma_f32_16x16x32_f16(AH.f, bl0, acc[mi][0], 0, 0, 0);
                acc[mi][1] = __builtin_amdgcn_mfma_f32_16x16x32_f16(AH.f, bh1, acc[mi][1], 0, 0, 0);
                acc[mi][1] = __builtin_amdgcn_mfma_f32_16x16x32_f16(AL.f, bh1, acc[mi][1], 0, 0, 0);
                acc[mi][1] = __builtin_amdgcn_mfma_f32_16x16x32_f16(AH.f, bl1, acc[mi][1], 0, 0, 0);
                __builtin_amdgcn_s_setprio(0);
            }
            of = ofn; bh0 = nbh0; bl0 = nbl0; bh1 = nbh1; bl1 = nbl1;
        }

        // epilogue: pool quad in D-regs; write SPLIT-PACKED x2
        const float bias0 = conv2_b[c0];
        const float bias1 = (c0 < 4) ? conv2_b[16 + c0] : 0.f;
        #pragma unroll
        for (int mi = 0; mi < 4; ++mi) {
            const int qq = mi * 4 + g;
            unsigned int* orow = x2p + (size_t)(b0 + wv) * 320 + qq * 20;
            const float v0 = fmaxf(fmaxf(acc[mi][0][0], acc[mi][0][1]),
                                   fmaxf(acc[mi][0][2], acc[mi][0][3]));
            orow[c0] = packsplit(selu_f(v0 + bias0));
            if (c0 < 4) {
                const float v1 = fmaxf(fmaxf(acc[mi][1][0], acc[mi][1][1]),
                                       fmaxf(acc[mi][1][2], acc[mi][1][3]));
                orow[16 + c0] = packsplit(selu_f(v1 + bias1));
            }
        }
    }
}

// ---------------------------------------------------------------------------
// Kernel T (tail, r16 proven): lin1 as split-fp16 MFMA -> lin2 -> code;
// fp32 Jacobi SVD w/ convergence skip -> proj in LDS -> dec1 -> dec2 MFMA
// + sigmoid -> out.
// ---------------------------------------------------------------------------
#define NS 16    // samples per tail block
#define HS 168   // padded h row stride in ushorts
#define SIS 324  // sInP row stride in u32

__global__ __launch_bounds__(256) void k_tail(
    const unsigned int* __restrict__ x2p,
    const __fp16* __restrict__ whiL, const __fp16* __restrict__ wloL,
    const float* __restrict__ lin1_b,
    const float* __restrict__ lin2_w,  const float* __restrict__ lin2_b,
    const float* __restrict__ dec1_w,  const float* __restrict__ dec1_b,
    const unsigned short* __restrict__ dec2_wb, const float* __restrict__ dec2_b,
    float* __restrict__ code, float* __restrict__ out)
{
    __shared__ unsigned int sInP[NS][SIS];   // 20.25 KB; reused as sHd later
    __shared__ float sH[NS][51];
    __shared__ float sC[NS][28];
    __shared__ float sP[NS][26];             // proj (SVD output)
    unsigned short* sHd = reinterpret_cast<unsigned short*>(&sInP[0][0]);

    const int t  = threadIdx.x;
    const int b0 = blockIdx.x * NS;
    const int lane = t & 63;
    const int wv   = t >> 6;

    {   // uint4-vectorized packed-x2 staging (rows contiguous in global)
        const uint4v* g = reinterpret_cast<const uint4v*>(x2p + (size_t)b0 * 320);
        for (int k = t; k < NS * 80; k += 256) {
            const int r  = k / 80;
            const int c4 = k - r * 80;
            *reinterpret_cast<uint4v*>(&sInP[r][c4 * 4]) = g[k];
        }
    }
    __syncthreads();

    // ---- lin1 via split-fp16 MFMA: wave wv owns output cols wv*16..+15 ----
    const int arow = lane & 15;   // A row (sample) / D col (output j)
    const int kgrp = lane >> 4;
    {
        f32x4 accL = {0.f, 0.f, 0.f, 0.f};
        #pragma unroll 1
        for (int ks = 0; ks < 10; ++ks) {
            const unsigned int* pa = &sInP[arow][ks * 32 + kgrp * 8];
            const uint4v w0 = *reinterpret_cast<const uint4v*>(pa);
            const uint4v w1 = *reinterpret_cast<const uint4v*>(pa + 4);
            F16x8Cast AH, AL;
            AH.u = (uint4v){ __builtin_amdgcn_perm(w0[1], w0[0], PERM_AH),
                             __builtin_amdgcn_perm(w0[3], w0[2], PERM_AH),
                             __builtin_amdgcn_perm(w1[1], w1[0], PERM_AH),
                             __builtin_amdgcn_perm(w1[3], w1[2], PERM_AH) };
            AL.u = (uint4v){ __builtin_amdgcn_perm(w0[1], w0[0], PERM_AL),
                             __builtin_amdgcn_perm(w0[3], w0[2], PERM_AL),
                             __builtin_amdgcn_perm(w1[1], w1[0], PERM_AL),
                             __builtin_amdgcn_perm(w1[3], w1[2], PERM_AL) };
            const f16x8 bh = *reinterpret_cast<const f16x8*>(
                whiL + ((size_t)(wv * 10 + ks) * 64 + lane) * 8);
            const f16x8 bl = *reinterpret_cast<const f16x8*>(
                wloL + ((size_t)(wv * 10 + ks) * 64 + lane) * 8);
            accL = __builtin_amdgcn_mfma_f32_16x16x32_f16(AH.f, bh, accL, 0, 0, 0);
            accL = __builtin_amdgcn_mfma_f32_16x16x32_f16(AL.f, bh, accL, 0, 0, 0);
            accL = __builtin_amdgcn_mfma_f32_16x16x32_f16(AH.f, bl, accL, 0, 0, 0);
        }
        const int ocol = wv * 16 + arow;     // lin1 output index
        if (ocol < 50) {
            const float bb = lin1_b[ocol];
            #pragma unroll
            for (int r = 0; r < 4; ++r)      // D row = sample = kgrp*4+r
                sH[kgrp * 4 + r][ocol] = selu_f(accL[r] + bb);
        }
    }
    __syncthreads();

    for (int idx = t; idx < NS * 25; idx += 256) {     // lin2: NS x 25
        const int bi = idx & (NS - 1);
        const int j  = idx / NS;
        float s = lin2_b[j];
        const float* w = lin2_w + j * 50;
        #pragma unroll
        for (int k = 0; k < 50; ++k) s = fmaf(sH[bi][k], w[k], s);
        code[(size_t)(b0 + bi) * 25 + j] = s;
        sC[bi][j] = s;
    }
    __syncthreads();

    // ---- fp32 Jacobi SVD projector (convergence-skip guard) ----
    if (t < NS) {
        float M[5][5];
        #pragma unroll
        for (int i = 0; i < 5; ++i)
            #pragma unroll
            for (int j = 0; j < 5; ++j) M[i][j] = sC[t][i * 5 + j];

        float A[5][5], V[5][5];
        #pragma unroll
        for (int i = 0; i < 5; ++i) {
            #pragma unroll
            for (int j = 0; j < 5; ++j) {
                float s = 0.f;
                #pragma unroll
                for (int k = 0; k < 5; ++k) s = fmaf(M[i][k], M[j][k], s);
                A[i][j] = s;
                V[i][j] = (i == j) ? 1.f : 0.f;
            }
        }
        for (int sweep = 0; sweep < 6; ++sweep) {
            #pragma unroll
            for (int p = 0; p < 4; ++p) {
                #pragma unroll
                for (int q = p + 1; q < 5; ++q) {
                    const float apq = A[p][q];
                    const float app = A[p][p], aqq = A[q][q];
                    // skip converged rotations (angle < ~3e-7)
                    if (apq * apq > 1e-13f * fmaxf(app * aqq, 1e-30f)) {
                        const float tau = (aqq - app) / (2.f * apq);
                        const float tt  = (tau >= 0.f ? 1.f : -1.f) /
                                          (fabsf(tau) + sqrtf(1.f + tau * tau));
                        const float cc  = 1.f / sqrtf(1.f + tt * tt);
                        const float ss  = tt * cc;
                        #pragma unroll
                        for (int i = 0; i < 5; ++i) {
                            if (i == p || i == q) continue;
                            const float aip = A[i][p], aiq = A[i][q];
                            A[i][p] = A[p][i] = cc * aip - ss * aiq;
                            A[i][q] = A[q][i] = ss * aip + cc * aiq;
                        }
                        A[p][p] = app - tt * apq;
                        A[q][q] = aqq + tt * apq;
                        A[p][q] = A[q][p] = 0.f;
                        #pragma unroll
                        for (int i = 0; i < 5; ++i) {
                            const float vip = V[i][p], viq = V[i][q];
                            V[i][p] = cc * vip - ss * viq;
                            V[i][q] = ss * vip + cc * viq;
                        }
                    }
                }
            }
        }
        float d[5];
        #pragma unroll
        for (int i = 0; i < 5; ++i) d[i] = A[i][i];
        float sel[5];
        #pragma unroll
        for (int c1 = 0; c1 < 5; ++c1) {
            int cnt = 0;
            #pragma unroll
            for (int c2 = 0; c2 < 5; ++c2) {
                if (c2 == c1) continue;
                if (d[c2] > d[c1] || (d[c2] == d[c1] && c2 < c1)) ++cnt;
            }
            sel[c1] = (cnt < 2) ? 1.f : 0.f;
        }
        #pragma unroll
        for (int i = 0; i < 5; ++i) {
            #pragma unroll
            for (int j = 0; j < 5; ++j) {
                float s = 0.f;
                #pragma unroll
                for (int k = 0; k < 5; ++k) s = fmaf(sel[k] * V[i][k], V[j][k], s);
                sP[t][i * 5 + j] = s;
            }
        }
    }
    __syncthreads();

    // ---- dec1: h[bi][j] = selu(sP row @ dec1_w) -> sHd (overlays sInP) ----
    const int bi = t & (NS - 1);
    const int j0 = t / NS;               // 0..15
    {
        float p[25];
        #pragma unroll
        for (int k = 0; k < 25; ++k) p[k] = sP[bi][k];
        #pragma unroll 2
        for (int i = 0; i < 10; ++i) {   // j = j0 + 16*i covers 0..159
            const int j = j0 + i * 16;
            const float* w = dec1_w + j * 25;
            float s = dec1_b[j];
            #pragma unroll
            for (int k = 0; k < 25; ++k) s = fmaf(p[k], w[k], s);
            sHd[bi * HS + j] = f2bf(selu_f(s));
        }
    }
    __syncthreads();

    // ---- dec2: out[NS][784] = sigmoid(h @ W^T + b) via MFMA (1 row-tile) --
    bf16x8 afr[5];                // hoisted A fragments: 5 k-steps
    #pragma unroll
    for (int ks = 0; ks < 5; ++ks)
        afr[ks] = *reinterpret_cast<const bf16x8*>(
            &sHd[arow * HS + ks * 32 + kgrp * 8]);

    for (int ct = wv; ct < 49; ct += 4) {
        const int col = ct * 16 + arow;
        bf16x8 bfr[5];
        const unsigned short* wp = dec2_wb + (size_t)col * 160 + kgrp * 8;
        #pragma unroll
        for (int ks = 0; ks < 5; ++ks)
            bfr[ks] = *reinterpret_cast<const bf16x8*>(wp + ks * 32);

        f32x4 acc0 = {0.f, 0.f, 0.f, 0.f};
        #pragma unroll
        for (int ks = 0; ks < 5; ++ks)
            acc0 = __builtin_amdgcn_mfma_f32_16x16x32_bf16(afr[ks], bfr[ks], acc0, 0, 0, 0);
        const float bb = dec2_b[col];
        #pragma unroll
        for (int r = 0; r < 4; ++r) {
            const int row = kgrp * 4 + r;          // D: row=(lane>>4)*4+reg
            const float v0 = acc0[r] + bb;
            out[(size_t)(b0 + row) * 784 + col] = 1.0f / (1.0f + __expf(-v0));
        }
    }
}

// ---------------------------------------------------------------------------
extern "C" void kernel_launch(void* const* d_in, const int* in_sizes, int n_in,
                              void* d_out, int out_size, void* d_ws, size_t ws_size,
                              hipStream_t stream) {
    const float* images  = (const float*)d_in[0];
    const float* conv1_w = (const float*)d_in[1];
    const float* conv1_b = (const float*)d_in[2];
    const float* conv2_w = (const float*)d_in[3];
    const float* conv2_b = (const float*)d_in[4];
    const float* lin1_w  = (const float*)d_in[5];
    const float* lin1_b  = (const float*)d_in[6];
    const float* lin2_w  = (const float*)d_in[7];
    const float* lin2_b  = (const float*)d_in[8];
    const float* dec1_w  = (const float*)d_in[9];
    const float* dec1_b  = (const float*)d_in[10];
    const float* dec2_w  = (const float*)d_in[11];
    const float* dec2_b  = (const float*)d_in[12];

    float* out_img = (float*)d_out;                    // NB*784 fp32
    float* code    = (float*)d_out + (size_t)NB * 784; // NB*25  fp32

    // workspace layout (bytes, 64-aligned offsets):
    char* ws = (char*)d_ws;
    unsigned int*   x2p     = (unsigned int*)ws;                           // NB*320 u32
    unsigned short* wbf     = (unsigned short*)(ws + (size_t)NB * 320 * 4);// 125440 us
    char*           pB      = ws + (size_t)NB * 320 * 4 + 250880;
    __fp16*         whiL    = (__fp16*)pB;                                 // 20480 h
    __fp16*         wloL    = (__fp16*)(pB + 40960);                       // 20480 h
    unsigned short* woff4   = (unsigned short*)(pB + 81920);               // 128 us
    __fp16*         whi     = (__fp16*)(pB + 82432);                       // 8192 h
    __fp16*         wlo     = (__fp16*)(pB + 98816);                       // 8192 h
    unsigned short* koff4   = (unsigned short*)(pB + 115200);              // 32 us
    __fp16*         whi1    = (__fp16*)(pB + 115264);                      // 512 h
    __fp16*         wlo1    = (__fp16*)(pB + 116288);                      // 512 h

    k_prep     <<<639,      256, 0, stream>>>(dec2_w, wbf, lin1_w, whiL, wloL,
                                              conv2_w, woff4, whi, wlo,
                                              conv1_w, koff4, whi1, wlo1);
    k_conv_fused<<<NB / 4,  256, 0, stream>>>(images, conv1_b, conv2_b,
                                              woff4, whi, wlo,
                                              koff4, whi1, wlo1, x2p);
    k_tail     <<<NB / NS, 256, 0, stream>>>(x2p, whiL, wloL, lin1_b,
                                             lin2_w, lin2_b,
                                             dec1_w, dec1_b,
                                             wbf, dec2_b,
                                             code, out_img);
}